// Round 10
// baseline (328.305 us; speedup 1.0000x reference)
//
#include <hip/hip_runtime.h>
#include <hip/hip_bf16.h>

// Problem constants
#define B   256
#define P   100
#define N1  101
#define E   256
#define HD  256          // H*D
#define H   16
#define D   16
#define NE  8
#define NTOK (B*P)       // 25600
#define NKV  (B*N1)      // 25856

typedef __attribute__((ext_vector_type(8))) short short8;
typedef __attribute__((ext_vector_type(4))) float f32x4;
typedef unsigned short ushort_t;

__device__ __forceinline__ unsigned short f2bf(float f) {
  unsigned int u = __float_as_uint(f);
  unsigned int r = (u + 0x7fffu + ((u >> 16) & 1u)) >> 16;
  return (unsigned short)r;
}
__device__ __forceinline__ float bf2f(unsigned short b) {
  return __uint_as_float(((unsigned int)b) << 16);
}
// HW packed f32->bf16 (1 instr for 2 elements); D.lo = bf16(a), D.hi = bf16(b)
__device__ __forceinline__ unsigned int cvtpk(float a, float b) {
  unsigned int r;
  asm("v_cvt_pk_bf16_f32 %0, %1, %2" : "=v"(r) : "v"(a), "v"(b));
  return r;
}
__device__ __forceinline__ float lo2f(unsigned int u) {
  return __uint_as_float(u << 16);
}
__device__ __forceinline__ float hi2f(unsigned int u) {
  return __uint_as_float(u & 0xffff0000u);
}

// ---------------------------------------------------------------------------
// Shared A-split helper: fp32 x8 -> 3-plane packed uint4s (cvt_pk fast path).
// ---------------------------------------------------------------------------
__device__ __forceinline__ void split3_pack(const float* v, uint4& uh,
                                            uint4& um, uint4& ul) {
  unsigned int hw[4], mw[4], lw[4];
#pragma unroll
  for (int jj = 0; jj < 4; ++jj) {
    float va = v[2 * jj], vb = v[2 * jj + 1];
    unsigned int h = cvtpk(va, vb);
    float ra = va - lo2f(h), rb = vb - hi2f(h);
    unsigned int m = cvtpk(ra, rb);
    float sa = ra - lo2f(m), sb = rb - hi2f(m);
    unsigned int l = cvtpk(sa, sb);
    hw[jj] = h; mw[jj] = m; lw[jj] = l;
  }
  uh.x = hw[0]; uh.y = hw[1]; uh.z = hw[2]; uh.w = hw[3];
  um.x = mw[0]; um.y = mw[1]; um.z = mw[2]; um.w = mw[3];
  ul.x = lw[0]; ul.y = lw[1]; ul.z = lw[2]; ul.w = lw[3];
}

// ---------------------------------------------------------------------------
// wsplit3: pre-pack a K x 256 fp32 weight into 3-plane bf16 fragment order.
// Layout (uint4): [((kt*16+gct)*3+p)*64 + lane].
// ---------------------------------------------------------------------------
__global__ __launch_bounds__(256) void wsplit3_kernel(
    const float* __restrict__ W, uint4* __restrict__ Wp, int Kreal) {
  const int gid = blockIdx.x * 256 + threadIdx.x;
  const int lane = gid & 63;
  const int rest = gid >> 6;          // kt*16 + gct
  const int gct = rest & 15;
  const int kt = rest >> 4;
  const int k0 = kt * 32 + (lane >> 4) * 8;
  const int c = gct * 16 + (lane & 15);
  float v[8];
#pragma unroll
  for (int j = 0; j < 8; ++j) {
    int kk = k0 + j;
    v[j] = (kk < Kreal) ? W[(size_t)kk * 256 + c] : 0.f;
  }
  uint4 uh, um, ul;
  split3_pack(v, uh, um, ul);
  Wp[(size_t)(rest * 3 + 0) * 64 + lane] = uh;
  Wp[(size_t)(rest * 3 + 1) * 64 + lane] = um;
  Wp[(size_t)(rest * 3 + 2) * 64 + lane] = ul;
}

// ---------------------------------------------------------------------------
// Fused K+V projection, 3-plane MFMA. Tile 32 rows x 256 cols, 4 waves.
// ---------------------------------------------------------------------------
__global__ __launch_bounds__(256) void kvproj3_kernel(
    const float* __restrict__ enc, const uint4* __restrict__ Wk3,
    const uint4* __restrict__ Wv3, float* __restrict__ kout,
    float* __restrict__ vout) {
  const int KT = 8;
  const int NKG = KT * 4;              // 32 k-groups of 8
  const int RSTRIDE = KT * 12 + 1;     // 97
  __shared__ uint4 als[32 * 97];       // 49.7 KB
  const int tid = threadIdx.x;
  const int row0 = blockIdx.x * 32;
  for (int i = tid; i < 32 * NKG; i += 256) {
    const int row = i >> 5;
    const int kg = i & 31;
    float v[8];
    const float4* s = (const float4*)(enc + (size_t)(row0 + row) * 256 + kg * 8);
    float4 x0 = s[0], x1 = s[1];
    v[0] = x0.x; v[1] = x0.y; v[2] = x0.z; v[3] = x0.w;
    v[4] = x1.x; v[5] = x1.y; v[6] = x1.z; v[7] = x1.w;
    uint4 uh, um, ul;
    split3_pack(v, uh, um, ul);
    const int slot = row * RSTRIDE + kg;
    als[slot] = uh;
    als[slot + NKG] = um;
    als[slot + 2 * NKG] = ul;
  }
  __syncthreads();
  const int w = tid >> 6;
  const int lane = tid & 63;
  const int lr = lane & 15;
  const int lg4 = lane >> 4;
  f32x4 acck[2][4], accv[2][4];
#pragma unroll
  for (int rt = 0; rt < 2; ++rt)
#pragma unroll
    for (int ct = 0; ct < 4; ++ct) {
      acck[rt][ct] = (f32x4){0.f, 0.f, 0.f, 0.f};
      accv[rt][ct] = (f32x4){0.f, 0.f, 0.f, 0.f};
    }
  for (int kt = 0; kt < KT; ++kt) {
    short8 ah[2], am[2], al[2];
#pragma unroll
    for (int rt = 0; rt < 2; ++rt) {
      const int base = (rt * 16 + lr) * RSTRIDE + kt * 4 + lg4;
      ah[rt] = __builtin_bit_cast(short8, als[base]);
      am[rt] = __builtin_bit_cast(short8, als[base + NKG]);
      al[rt] = __builtin_bit_cast(short8, als[base + 2 * NKG]);
    }
#pragma unroll
    for (int ct = 0; ct < 4; ++ct) {
      const int gct = w * 4 + ct;
      const size_t base = (size_t)((kt * 16 + gct) * 3) * 64 + lane;
      {
        short8 bh = __builtin_bit_cast(short8, Wk3[base]);
        short8 bm = __builtin_bit_cast(short8, Wk3[base + 64]);
        short8 bl = __builtin_bit_cast(short8, Wk3[base + 128]);
#pragma unroll
        for (int rt = 0; rt < 2; ++rt) {
          f32x4 a = acck[rt][ct];
          a = __builtin_amdgcn_mfma_f32_16x16x32_bf16(ah[rt], bh, a, 0, 0, 0);
          a = __builtin_amdgcn_mfma_f32_16x16x32_bf16(ah[rt], bm, a, 0, 0, 0);
          a = __builtin_amdgcn_mfma_f32_16x16x32_bf16(am[rt], bh, a, 0, 0, 0);
          a = __builtin_amdgcn_mfma_f32_16x16x32_bf16(am[rt], bm, a, 0, 0, 0);
          a = __builtin_amdgcn_mfma_f32_16x16x32_bf16(ah[rt], bl, a, 0, 0, 0);
          a = __builtin_amdgcn_mfma_f32_16x16x32_bf16(al[rt], bh, a, 0, 0, 0);
          acck[rt][ct] = a;
        }
      }
      {
        short8 bh = __builtin_bit_cast(short8, Wv3[base]);
        short8 bm = __builtin_bit_cast(short8, Wv3[base + 64]);
        short8 bl = __builtin_bit_cast(short8, Wv3[base + 128]);
#pragma unroll
        for (int rt = 0; rt < 2; ++rt) {
          f32x4 a = accv[rt][ct];
          a = __builtin_amdgcn_mfma_f32_16x16x32_bf16(ah[rt], bh, a, 0, 0, 0);
          a = __builtin_amdgcn_mfma_f32_16x16x32_bf16(ah[rt], bm, a, 0, 0, 0);
          a = __builtin_amdgcn_mfma_f32_16x16x32_bf16(am[rt], bh, a, 0, 0, 0);
          a = __builtin_amdgcn_mfma_f32_16x16x32_bf16(am[rt], bm, a, 0, 0, 0);
          a = __builtin_amdgcn_mfma_f32_16x16x32_bf16(ah[rt], bl, a, 0, 0, 0);
          a = __builtin_amdgcn_mfma_f32_16x16x32_bf16(al[rt], bh, a, 0, 0, 0);
          accv[rt][ct] = a;
        }
      }
    }
  }
#pragma unroll
  for (int rt = 0; rt < 2; ++rt) {
#pragma unroll
    for (int ct = 0; ct < 4; ++ct) {
      const int gct = w * 4 + ct;
#pragma unroll
      for (int reg = 0; reg < 4; ++reg) {
        const int row = row0 + rt * 16 + lg4 * 4 + reg;
        int bb = row / N1, nn = row - bb * N1;
        size_t o = (((size_t)bb * H + gct) * N1 + nn) * D + lr;
        kout[o] = acck[rt][ct][reg];
        vout[o] = accv[rt][ct][reg];
      }
    }
  }
}

// ---------------------------------------------------------------------------
// proj3 (Q only): MODE 1, KT=9.
// ---------------------------------------------------------------------------
template <int KT, int MODE>
__global__ __launch_bounds__(256) void proj3_kernel(
    const float* __restrict__ src, const float* __restrict__ attr,
    const uint4* __restrict__ Wp3, float* __restrict__ outp) {
  const int RSTRIDE = KT * 12 + 1;
  __shared__ uint4 als[32 * (KT * 12 + 1)];
  const int tid = threadIdx.x;
  const int row0 = blockIdx.x * 32;
  const int NKG = KT * 4;
  for (int i = tid; i < 32 * NKG; i += 256) {
    const int row = i / NKG;
    const int kg = i - row * NKG;
    float v[8];
    const int kbase = kg * 8;
    if (MODE == 0 || kbase < 256) {
      const float4* s = (const float4*)(src + (size_t)(row0 + row) * 256 + kbase);
      float4 x0 = s[0], x1 = s[1];
      v[0] = x0.x; v[1] = x0.y; v[2] = x0.z; v[3] = x0.w;
      v[4] = x1.x; v[5] = x1.y; v[6] = x1.z; v[7] = x1.w;
    } else {
#pragma unroll
      for (int j = 0; j < 8; ++j) {
        int k = kbase + j;
        v[j] = (k >= 256 && k < 260) ? attr[(size_t)(row0 + row) * 4 + (k - 256)]
                                     : 0.f;
      }
    }
    uint4 uh, um, ul;
    split3_pack(v, uh, um, ul);
    const int slot = row * RSTRIDE + kg;
    als[slot] = uh;
    als[slot + NKG] = um;
    als[slot + 2 * NKG] = ul;
  }
  __syncthreads();
  const int w = tid >> 6;
  const int lane = tid & 63;
  const int lr = lane & 15;
  const int lg4 = lane >> 4;
  f32x4 acc[2][4];
#pragma unroll
  for (int rt = 0; rt < 2; ++rt)
#pragma unroll
    for (int ct = 0; ct < 4; ++ct) acc[rt][ct] = (f32x4){0.f, 0.f, 0.f, 0.f};
  for (int kt = 0; kt < KT; ++kt) {
    short8 ah[2], am[2], al[2];
#pragma unroll
    for (int rt = 0; rt < 2; ++rt) {
      const int base = (rt * 16 + lr) * RSTRIDE + kt * 4 + lg4;
      ah[rt] = __builtin_bit_cast(short8, als[base]);
      am[rt] = __builtin_bit_cast(short8, als[base + NKG]);
      al[rt] = __builtin_bit_cast(short8, als[base + 2 * NKG]);
    }
#pragma unroll
    for (int ct = 0; ct < 4; ++ct) {
      const int gct = w * 4 + ct;
      const size_t base = (size_t)((kt * 16 + gct) * 3) * 64 + lane;
      short8 bh = __builtin_bit_cast(short8, Wp3[base]);
      short8 bm = __builtin_bit_cast(short8, Wp3[base + 64]);
      short8 bl = __builtin_bit_cast(short8, Wp3[base + 128]);
#pragma unroll
      for (int rt = 0; rt < 2; ++rt) {
        f32x4 a = acc[rt][ct];
        a = __builtin_amdgcn_mfma_f32_16x16x32_bf16(ah[rt], bh, a, 0, 0, 0);
        a = __builtin_amdgcn_mfma_f32_16x16x32_bf16(ah[rt], bm, a, 0, 0, 0);
        a = __builtin_amdgcn_mfma_f32_16x16x32_bf16(am[rt], bh, a, 0, 0, 0);
        a = __builtin_amdgcn_mfma_f32_16x16x32_bf16(am[rt], bm, a, 0, 0, 0);
        a = __builtin_amdgcn_mfma_f32_16x16x32_bf16(ah[rt], bl, a, 0, 0, 0);
        a = __builtin_amdgcn_mfma_f32_16x16x32_bf16(al[rt], bh, a, 0, 0, 0);
        acc[rt][ct] = a;
      }
    }
  }
#pragma unroll
  for (int rt = 0; rt < 2; ++rt) {
#pragma unroll
    for (int ct = 0; ct < 4; ++ct) {
      const int gct = w * 4 + ct;
#pragma unroll
      for (int reg = 0; reg < 4; ++reg) {
        const int row = row0 + rt * 16 + lg4 * 4 + reg;
        size_t o;
        if (MODE == 0) {
          int bb = row / N1, nn = row - bb * N1;
          o = (((size_t)bb * H + gct) * N1 + nn) * D + lr;
        } else {
          int bb = row / P, pp = row - bb * P;
          o = (((size_t)bb * H + gct) * P + pp) * D + lr;
        }
        outp[o] = acc[rt][ct][reg];
      }
    }
  }
}

// ---------------------------------------------------------------------------
// Attention v4: grid B*8 (head pairs). 256 threads = 4 waves.
// wave w: head = h0 + (w>>1); row = (w&1)*64 + lane (1 row/lane).
// K AND V both in LDS, single chunk of all 101 keys: 25.9 KB -> 6 blocks/CU.
// exp2-domain online softmax; masks prefetched; single staging barrier.
// ---------------------------------------------------------------------------
__device__ __forceinline__ float dot16f(
    const float4& a0, const float4& a1, const float4& a2, const float4& a3,
    const float4& b0, const float4& b1, const float4& b2, const float4& b3) {
  float s = a0.x * b0.x;
  s = fmaf(a0.y, b0.y, s); s = fmaf(a0.z, b0.z, s); s = fmaf(a0.w, b0.w, s);
  s = fmaf(a1.x, b1.x, s); s = fmaf(a1.y, b1.y, s); s = fmaf(a1.z, b1.z, s);
  s = fmaf(a1.w, b1.w, s);
  s = fmaf(a2.x, b2.x, s); s = fmaf(a2.y, b2.y, s); s = fmaf(a2.z, b2.z, s);
  s = fmaf(a2.w, b2.w, s);
  s = fmaf(a3.x, b3.x, s); s = fmaf(a3.y, b3.y, s); s = fmaf(a3.z, b3.z, s);
  s = fmaf(a3.w, b3.w, s);
  return s;
}

__global__ __launch_bounds__(256) void attn_kernel(
    const float* __restrict__ q, const float* __restrict__ k,
    const float* __restrict__ v, const float* __restrict__ ninf,
    float* __restrict__ x) {
  const int b = blockIdx.x >> 3;
  const int h0 = (blockIdx.x & 7) * 2;
  __shared__ float4 kl4[2 * N1 * 4];   // 808 float4 = 12.9 KB
  __shared__ float4 vl4[2 * N1 * 4];
  const int tid = threadIdx.x;
  {
    // 2 adjacent heads are contiguous in (B,H,N1,D): one linear copy.
    const float4* ks = (const float4*)(k + ((size_t)b * H + h0) * N1 * D);
    const float4* vs = (const float4*)(v + ((size_t)b * H + h0) * N1 * D);
    for (int i = tid; i < 2 * N1 * 4; i += 256) {
      kl4[i] = ks[i];
      vl4[i] = vs[i];
    }
  }
  const int w = tid >> 6;
  const int lane = tid & 63;
  const int hh = w >> 1;
  const int h = h0 + hh;
  const int prow = (w & 1) * 64 + lane;
  const bool act = (prow < P);
  const int p = act ? prow : (P - 1);
  const float LOG2E = 1.4426950408889634f;
  const float c1 = 0.25f * LOG2E;
  const float* qb = q + (((size_t)b * H + h) * P + p) * D;
  float4 qa0 = *(const float4*)&qb[0];
  float4 qa1 = *(const float4*)&qb[4];
  float4 qa2 = *(const float4*)&qb[8];
  float4 qa3 = *(const float4*)&qb[12];
  qa0.x *= c1; qa0.y *= c1; qa0.z *= c1; qa0.w *= c1;
  qa1.x *= c1; qa1.y *= c1; qa1.z *= c1; qa1.w *= c1;
  qa2.x *= c1; qa2.y *= c1; qa2.z *= c1; qa2.w *= c1;
  qa3.x *= c1; qa3.y *= c1; qa3.z *= c1; qa3.w *= c1;
  const float* mrow = ninf + ((size_t)b * P + p) * N1;
  const float* kw = (const float*)(kl4 + hh * N1 * 4);
  const float* vw = (const float*)(vl4 + hh * N1 * 4);
  __syncthreads();

  float m2 = -1e30f, l = 0.f;
  float o[16];
#pragma unroll
  for (int d = 0; d < 16; ++d) o[d] = 0.f;
  float4 mk = *(const float4*)&mrow[0];
  const float tmask = mrow[100];

  for (int it = 0; it < 25; ++it) {
    const int j = it * 4;
    const int nn = (it < 24) ? (j + 4) : 0;
    float4 nx = *(const float4*)&mrow[nn];
    const float4* kr0 = (const float4*)&kw[(j + 0) * D];
    const float4* kr1 = (const float4*)&kw[(j + 1) * D];
    const float4* kr2 = (const float4*)&kw[(j + 2) * D];
    const float4* kr3 = (const float4*)&kw[(j + 3) * D];
    float4 k00 = kr0[0], k01 = kr0[1], k02 = kr0[2], k03 = kr0[3];
    float4 k10 = kr1[0], k11 = kr1[1], k12 = kr1[2], k13 = kr1[3];
    float4 k20 = kr2[0], k21 = kr2[1], k22 = kr2[2], k23 = kr2[3];
    float4 k30 = kr3[0], k31 = kr3[1], k32 = kr3[2], k33 = kr3[3];
    float s0 = fmaf(mk.x, LOG2E, dot16f(qa0, qa1, qa2, qa3, k00, k01, k02, k03));
    float s1 = fmaf(mk.y, LOG2E, dot16f(qa0, qa1, qa2, qa3, k10, k11, k12, k13));
    float s2 = fmaf(mk.z, LOG2E, dot16f(qa0, qa1, qa2, qa3, k20, k21, k22, k23));
    float s3 = fmaf(mk.w, LOG2E, dot16f(qa0, qa1, qa2, qa3, k30, k31, k32, k33));
    float mn = fmaxf(fmaxf(fmaxf(s0, s1), fmaxf(s2, s3)), m2);
    float sc = exp2f(m2 - mn);
    float p0 = exp2f(s0 - mn), p1 = exp2f(s1 - mn);
    float p2 = exp2f(s2 - mn), p3 = exp2f(s3 - mn);
    l = fmaf(l, sc, (p0 + p1) + (p2 + p3));
    const float4* vr0 = (const float4*)&vw[(j + 0) * D];
    const float4* vr1 = (const float4*)&vw[(j + 1) * D];
    const float4* vr2 = (const float4*)&vw[(j + 2) * D];
    const float4* vr3 = (const float4*)&vw[(j + 3) * D];
#pragma unroll
    for (int dq = 0; dq < 4; ++dq) {
      float4 v0 = vr0[dq], v1 = vr1[dq], v2 = vr2[dq], v3 = vr3[dq];
      o[4 * dq + 0] = fmaf(o[4 * dq + 0], sc,
          fmaf(p0, v0.x, fmaf(p1, v1.x, fmaf(p2, v2.x, p3 * v3.x))));
      o[4 * dq + 1] = fmaf(o[4 * dq + 1], sc,
          fmaf(p0, v0.y, fmaf(p1, v1.y, fmaf(p2, v2.y, p3 * v3.y))));
      o[4 * dq + 2] = fmaf(o[4 * dq + 2], sc,
          fmaf(p0, v0.z, fmaf(p1, v1.z, fmaf(p2, v2.z, p3 * v3.z))));
      o[4 * dq + 3] = fmaf(o[4 * dq + 3], sc,
          fmaf(p0, v0.w, fmaf(p1, v1.w, fmaf(p2, v2.w, p3 * v3.w))));
    }
    m2 = mn;
    mk = nx;
  }
  // tail key 100
  {
    const float4* kr = (const float4*)&kw[100 * D];
    float4 k0 = kr[0], k1 = kr[1], k2 = kr[2], k3 = kr[3];
    float s = fmaf(tmask, LOG2E, dot16f(qa0, qa1, qa2, qa3, k0, k1, k2, k3));
    float mn = fmaxf(m2, s);
    float sc = exp2f(m2 - mn);
    float pp = exp2f(s - mn);
    l = fmaf(l, sc, pp);
    const float4* vr = (const float4*)&vw[100 * D];
#pragma unroll
    for (int dq = 0; dq < 4; ++dq) {
      float4 v0 = vr[dq];
      o[4 * dq + 0] = fmaf(o[4 * dq + 0], sc, pp * v0.x);
      o[4 * dq + 1] = fmaf(o[4 * dq + 1], sc, pp * v0.y);
      o[4 * dq + 2] = fmaf(o[4 * dq + 2], sc, pp * v0.z);
      o[4 * dq + 3] = fmaf(o[4 * dq + 3], sc, pp * v0.w);
    }
  }
  if (act) {
    const float inv = 1.f / l;
    float* xr = &x[((size_t)b * P + p) * HD + h * D];
#pragma unroll
    for (int dq = 0; dq < 4; ++dq) {
      float4 t;
      t.x = o[4 * dq + 0] * inv; t.y = o[4 * dq + 1] * inv;
      t.z = o[4 * dq + 2] * inv; t.w = o[4 * dq + 3] * inv;
      *(float4*)&xr[4 * dq] = t;
    }
  }
}

// ---------------------------------------------------------------------------
// Kernel 4: router logits (fp32) + top2 + gates; emits xsplit (2-plane).
// ---------------------------------------------------------------------------
__global__ __launch_bounds__(256) void logits_top2_kernel(
    const float* __restrict__ x, const float* __restrict__ Wg,
    int* __restrict__ topi, float* __restrict__ topg,
    ushort_t* __restrict__ xsplit) {
  __shared__ float xl[32][260];
  __shared__ float wg[E * NE];
  __shared__ float lg[32][9];
  const int tid = threadIdx.x;
  const int t0 = blockIdx.x * 32;
  for (int r = 0; r < 32; ++r) {
    float val = x[(size_t)(t0 + r) * HD + tid];
    xl[r][tid] = val;
    unsigned short hi = f2bf(val);
    unsigned short lo = f2bf(val - bf2f(hi));
    xsplit[(size_t)(t0 + r) * 512 + tid] = hi;
    xsplit[(size_t)(t0 + r) * 512 + 256 + tid] = lo;
  }
  for (int i = tid; i < E * NE; i += 256) wg[i] = Wg[i];
  __syncthreads();
  const int r = tid >> 3, e = tid & 7;
  float acc = 0.f;
  for (int f = 0; f < E; ++f) acc += xl[r][f] * wg[f * NE + e];
  lg[r][e] = acc;
  __syncthreads();
  if (tid < 32) {
    float v[8];
#pragma unroll
    for (int j = 0; j < 8; ++j) v[j] = lg[tid][j];
    int i1 = 0; float v1 = v[0];
#pragma unroll
    for (int j = 1; j < 8; ++j) if (v[j] > v1) { v1 = v[j]; i1 = j; }
    int i2 = -1; float v2 = -1e30f;
#pragma unroll
    for (int j = 0; j < 8; ++j)
      if (j != i1 && v[j] > v2) { v2 = v[j]; i2 = j; }
    float ex = __expf(v2 - v1);
    float g1 = 1.f / (1.f + ex);
    float g2 = ex / (1.f + ex);
    int t = t0 + tid;
    topi[t * 2 + 0] = i1; topi[t * 2 + 1] = i2;
    topg[t * 2 + 0] = g1; topg[t * 2 + 1] = g2;
  }
}

// ---------------------------------------------------------------------------
// Kernel 5: build per-expert token lists. UNCHANGED.
// ---------------------------------------------------------------------------
__global__ __launch_bounds__(1024) void build_lists_kernel(
    const int* __restrict__ topi, const float* __restrict__ topg,
    int* __restrict__ list_tok, float* __restrict__ list_gate,
    int* __restrict__ counts) {
  const int e = blockIdx.x;
  const int tid = threadIdx.x;
  const int lane = tid & 63, w = tid >> 6;
  __shared__ int wsum[16];
  int running = 0;
  for (int c = 0; c < NTOK; c += 1024) {
    int t = c + tid;
    int ia = topi[t * 2 + 0], ib = topi[t * 2 + 1];
    int slot = (ia == e) ? 0 : ((ib == e) ? 1 : -1);
    int f = (slot >= 0) ? 1 : 0;
    unsigned long long m = __ballot(f);
    if (lane == 0) wsum[w] = __popcll(m);
    __syncthreads();
    int wbase = 0, total = 0;
#pragma unroll
    for (int i = 0; i < 16; ++i) {
      int s = wsum[i];
      if (i < w) wbase += s;
      total += s;
    }
    if (f) {
      int prefix = __popcll(m & ((1ull << lane) - 1ull));
      int pos = running + wbase + prefix;
      list_tok[e * NTOK + pos] = (t << 1) | slot;
      list_gate[e * NTOK + pos] = topg[t * 2 + slot];
    }
    running += total;
    __syncthreads();
  }
  if (tid == 0) counts[e] = running;
}

// ---------------------------------------------------------------------------
// Kernel 5b: expert weight 2-plane prepack (cvt_pk fast path).
// ---------------------------------------------------------------------------
__global__ __launch_bounds__(256) void wsplit_kernel(
    const float* __restrict__ eW, uint4* __restrict__ Wp) {
  const int gid = blockIdx.x * 256 + threadIdx.x;
  const int lane = gid & 63;
  const int rest = gid >> 6;
  const int gct = rest & 15;
  const int kt = (rest >> 4) & 7;
  const int e = rest >> 7;
  const int kbase = kt * 32 + (lane >> 4) * 8;
  const int c = gct * 16 + (lane & 15);
  unsigned int hi[4], lo[4];
#pragma unroll
  for (int jj = 0; jj < 4; ++jj) {
    float v0 = eW[((size_t)e * HD + (kbase + 2 * jj)) * E + c];
    float v1 = eW[((size_t)e * HD + (kbase + 2 * jj + 1)) * E + c];
    unsigned int h = cvtpk(v0, v1);
    float r0 = v0 - lo2f(h), r1 = v1 - hi2f(h);
    unsigned int l = cvtpk(r0, r1);
    hi[jj] = h; lo[jj] = l;
  }
  uint4 uh, ul;
  uh.x = hi[0]; uh.y = hi[1]; uh.z = hi[2]; uh.w = hi[3];
  ul.x = lo[0]; ul.y = lo[1]; ul.z = lo[2]; ul.w = lo[3];
  Wp[(size_t)(rest * 2 + 0) * 64 + lane] = uh;
  Wp[(size_t)(rest * 2 + 1) * 64 + lane] = ul;
}

// ---------------------------------------------------------------------------
// Kernel 6: sparse expert GEMM via split-bf16 MFMA. UNCHANGED.
// ---------------------------------------------------------------------------
__global__ __launch_bounds__(256) void expert_gemm_kernel(
    const ushort_t* __restrict__ xsplit, const uint4* __restrict__ Wp,
    const float* __restrict__ eb, const int* __restrict__ list_tok,
    const float* __restrict__ list_gate, const int* __restrict__ counts,
    float* __restrict__ p0, float* __restrict__ p1) {
  int e = 0, t0 = -1;
  {
    int rem = blockIdx.x;
    for (int i = 0; i < NE; ++i) {
      int nt = (counts[i] + 31) >> 5;
      if (rem < nt) { e = i; t0 = rem * 32; break; }
      rem -= nt;
    }
  }
  if (t0 < 0) return;
  const int cnt = counts[e];
  const int nr = min(32, cnt - t0);
  __shared__ uint4 xls[32 * 65];
  __shared__ int stok[32];
  __shared__ float sg[32];
  const int tid = threadIdx.x;
  if (tid < 32) {
    int src = e * NTOK + t0 + ((tid < nr) ? tid : 0);
    stok[tid] = list_tok[src];
    sg[tid] = (tid < nr) ? list_gate[e * NTOK + t0 + tid] : 0.f;
  }
  __syncthreads();
  for (int i = tid; i < 32 * 64; i += 256) {
    int r = i >> 6, ch = i & 63;
    const uint4* src = (const uint4*)(xsplit + (size_t)(stok[r] >> 1) * 512);
    xls[r * 65 + ch] = src[ch];
  }
  __syncthreads();
  const int w = tid >> 6;
  const int lane = tid & 63;
  const int lr = lane & 15;
  const int lg4 = lane >> 4;
  f32x4 acc[2][4];
#pragma unroll
  for (int rt = 0; rt < 2; ++rt)
#pragma unroll
    for (int ct = 0; ct < 4; ++ct) acc[rt][ct] = (f32x4){0.f, 0.f, 0.f, 0.f};

  for (int kt = 0; kt < 8; ++kt) {
    short8 afrag[2][2];
#pragma unroll
    for (int rt = 0; rt < 2; ++rt)
#pragma unroll
      for (int pl = 0; pl < 2; ++pl) {
        uint4 u = xls[(rt * 16 + lr) * 65 + pl * 32 + kt * 4 + lg4];
        afrag[rt][pl] = __builtin_bit_cast(short8, u);
      }
#pragma unroll
    for (int ct = 0; ct < 4; ++ct) {
      const int gct = w * 4 + ct;
      const size_t base = (size_t)(((e * 8 + kt) * 16 + gct) * 2) * 64 + lane;
      short8 bh = __builtin_bit_cast(short8, Wp[base]);
      short8 bl = __builtin_bit_cast(short8, Wp[base + 64]);
#pragma unroll
      for (int rt = 0; rt < 2; ++rt) {
        acc[rt][ct] = __builtin_amdgcn_mfma_f32_16x16x32_bf16(
            afrag[rt][0], bh, acc[rt][ct], 0, 0, 0);
        acc[rt][ct] = __builtin_amdgcn_mfma_f32_16x16x32_bf16(
            afrag[rt][0], bl, acc[rt][ct], 0, 0, 0);
        acc[rt][ct] = __builtin_amdgcn_mfma_f32_16x16x32_bf16(
            afrag[rt][1], bh, acc[rt][ct], 0, 0, 0);
      }
    }
  }
#pragma unroll
  for (int rt = 0; rt < 2; ++rt) {
#pragma unroll
    for (int ct = 0; ct < 4; ++ct) {
      const int col = (w * 4 + ct) * 16 + lr;
      const float bias = eb[e * E + col];
#pragma unroll
      for (int reg = 0; reg < 4; ++reg) {
        const int ridx = rt * 16 + lg4 * 4 + reg;
        if (ridx < nr) {
          const int tokw = stok[ridx];
          const float g = sg[ridx];
          float* dst = ((tokw & 1) ? p1 : p0) + (size_t)(tokw >> 1) * E + col;
          *dst = g * (acc[rt][ct][reg] + bias);
        }
      }
    }
  }
}

// ---------------------------------------------------------------------------
// Kernel 7: score2 = mh @ enc^T, per batch. grid (4, 256), block 128.
// ---------------------------------------------------------------------------
__global__ __launch_bounds__(128) void score2_kernel(
    const float* __restrict__ p0, const float* __restrict__ p1,
    const float* __restrict__ enc, float* __restrict__ out) {
  const int b = blockIdx.y;
  const int pt = blockIdx.x * 25;
  __shared__ float mh[25][E];
  const int tid = threadIdx.x;
  for (int i = tid; i < 25 * E; i += 128) {
    int r = i >> 8, c = i & 255;
    int t = b * P + pt + r;
    mh[r][c] = p0[(size_t)t * E + c] + p1[(size_t)t * E + c];
  }
  __syncthreads();
  const int n = tid;
  if (n >= N1) return;
  float acc[25];
#pragma unroll
  for (int r = 0; r < 25; ++r) acc[r] = 0.f;
  const float* er = enc + ((size_t)b * N1 + n) * E;
  for (int ee = 0; ee < E; ee += 4) {
    float4 ev = *(const float4*)&er[ee];
#pragma unroll
    for (int r = 0; r < 25; ++r) {
      float4 mv = *(const float4*)&mh[r][ee];
      acc[r] += mv.x * ev.x + mv.y * ev.y + mv.z * ev.z + mv.w * ev.w;
    }
  }
#pragma unroll
  for (int r = 0; r < 25; ++r) out[((size_t)b * P + pt + r) * N1 + n] = acc[r];
}

// ---------------------------------------------------------------------------
// Kernel 8: add biases, tanh clip, + ninf, row softmax.  In-place on d_out.
// ---------------------------------------------------------------------------
__global__ __launch_bounds__(256) void softmax2_kernel(
    float* __restrict__ sc, const float* __restrict__ ab,
    const float* __restrict__ ab1, const float* __restrict__ ninf) {
  const int row = blockIdx.x * 4 + (threadIdx.x >> 6);
  const int lane = threadIdx.x & 63;
  float* srow = sc + (size_t)row * N1;
  const float* a = ab + (size_t)row * N1;
  const float* a1 = ab1 + (size_t)row * N1;
  const float* nf = ninf + (size_t)row * N1;
  float s0 = -1e30f, s1 = -1e30f;
  {
    int i = lane;
    float s = srow[i] + a[i] + a1[i];
    float e2 = __expf(s * 0.125f);
    float th = 1.f - 2.f / (e2 + 1.f);
    s0 = 10.f * th + nf[i];
  }
  if (lane < N1 - 64) {
    int i = lane + 64;
    float s = srow[i] + a[i] + a1[i];
    float e2 = __expf(s * 0.125f);
    float th = 1.f - 2.f / (e2 + 1.f);
    s1 = 10.f * th + nf[i];
  }
  float mx = fmaxf(s0, s1);
#pragma unroll
  for (int off = 32; off > 0; off >>= 1) mx = fmaxf(mx, __shfl_xor(mx, off, 64));
  float p0 = __expf(s0 - mx);
  float p1 = (lane < N1 - 64) ? __expf(s1 - mx) : 0.f;
  float sum = p0 + p1;
#pragma unroll
  for (int off = 32; off > 0; off >>= 1) sum += __shfl_xor(sum, off, 64);
  float inv = 1.f / sum;
  srow[lane] = p0 * inv;
  if (lane < N1 - 64) srow[lane + 64] = p1 * inv;
}

// ---------------------------------------------------------------------------
extern "C" void kernel_launch(void* const* d_in, const int* in_sizes, int n_in,
                              void* d_out, int out_size, void* d_ws,
                              size_t ws_size, hipStream_t stream) {
  const float* eln  = (const float*)d_in[0];
  const float* attr = (const float*)d_in[1];
  const float* enc  = (const float*)d_in[2];
  const float* ninf = (const float*)d_in[3];
  const float* ab   = (const float*)d_in[4];
  const float* ab1  = (const float*)d_in[5];
  const float* Wq   = (const float*)d_in[6];
  const float* Wk   = (const float*)d_in[7];
  const float* Wv   = (const float*)d_in[8];
  const float* Wg   = (const float*)d_in[9];
  const float* eW   = (const float*)d_in[10];
  const float* eb   = (const float*)d_in[11];
  float* out = (float*)d_out;

  char* ws = (char*)d_ws;
  size_t off = 0;
  auto carve = [&](size_t bytes) {
    char* p = ws + off;
    off += (bytes + 255) & ~size_t(255);
    return p;
  };
  float* kbuf = (float*)carve(sizeof(float) * NKV * HD);
  float* vbuf = (float*)carve(sizeof(float) * NKV * HD);
  float* qbuf = (float*)carve(sizeof(float) * NTOK * HD);
  float* xbuf = (float*)carve(sizeof(float) * NTOK * HD);
  int*   topi = (int*)carve(sizeof(int) * NTOK * 2);
  float* topg = (float*)carve(sizeof(float) * NTOK * 2);
  int*   counts = (int*)carve(sizeof(int) * 16);
  int*   list_tok = (int*)carve(sizeof(int) * NE * NTOK);
  float* list_gate = (float*)carve(sizeof(float) * NE * NTOK);
  uint4* Wp  = (uint4*)carve(sizeof(ushort_t) * NE * HD * E * 2);  // 2 MB
  uint4* Wk3 = (uint4*)carve((size_t)8 * 16 * 3 * 64 * 16);        // 393 KB
  uint4* Wv3 = (uint4*)carve((size_t)8 * 16 * 3 * 64 * 16);
  uint4* Wq3 = (uint4*)carve((size_t)9 * 16 * 3 * 64 * 16);        // 442 KB
  float* pp0 = kbuf;
  float* pp1 = vbuf;
  ushort_t* xsplit = (ushort_t*)qbuf;

  wsplit_kernel<<<256, 256, 0, stream>>>(eW, Wp);
  wsplit3_kernel<<<32, 256, 0, stream>>>(Wk, Wk3, 256);
  wsplit3_kernel<<<32, 256, 0, stream>>>(Wv, Wv3, 256);
  wsplit3_kernel<<<36, 256, 0, stream>>>(Wq, Wq3, 260);
  kvproj3_kernel<<<NKV / 32, 256, 0, stream>>>(enc, Wk3, Wv3, kbuf, vbuf);
  proj3_kernel<9, 1><<<NTOK / 32, 256, 0, stream>>>(eln, attr, Wq3, qbuf);
  attn_kernel<<<B * 8, 256, 0, stream>>>(qbuf, kbuf, vbuf, ninf, xbuf);
  logits_top2_kernel<<<NTOK / 32, 256, 0, stream>>>(xbuf, Wg, topi, topg,
                                                    xsplit);
  build_lists_kernel<<<NE, 1024, 0, stream>>>(topi, topg, list_tok, list_gate,
                                              counts);
  expert_gemm_kernel<<<1608, 256, 0, stream>>>(xsplit, Wp, eb, list_tok,
                                               list_gate, counts, pp0, pp1);
  dim3 s2(4, B);
  score2_kernel<<<s2, 128, 0, stream>>>(pp0, pp1, enc, out);
  softmax2_kernel<<<NTOK / 4, 256, 0, stream>>>(out, ab, ab1, ninf);
}

// Round 11
// 318.997 us; speedup vs baseline: 1.0292x; 1.0292x over previous
//
#include <hip/hip_runtime.h>
#include <hip/hip_bf16.h>

// Problem constants
#define B   256
#define P   100
#define N1  101
#define E   256
#define HD  256          // H*D
#define H   16
#define D   16
#define NE  8
#define NTOK (B*P)       // 25600
#define NKV  (B*N1)      // 25856

typedef __attribute__((ext_vector_type(8))) short short8;
typedef __attribute__((ext_vector_type(4))) float f32x4;
typedef unsigned short ushort_t;

__device__ __forceinline__ unsigned short f2bf(float f) {
  unsigned int u = __float_as_uint(f);
  unsigned int r = (u + 0x7fffu + ((u >> 16) & 1u)) >> 16;
  return (unsigned short)r;
}
__device__ __forceinline__ float bf2f(unsigned short b) {
  return __uint_as_float(((unsigned int)b) << 16);
}
// HW packed f32->bf16 (1 instr for 2 elements); D.lo = bf16(a), D.hi = bf16(b)
__device__ __forceinline__ unsigned int cvtpk(float a, float b) {
  unsigned int r;
  asm("v_cvt_pk_bf16_f32 %0, %1, %2" : "=v"(r) : "v"(a), "v"(b));
  return r;
}
__device__ __forceinline__ float lo2f(unsigned int u) {
  return __uint_as_float(u << 16);
}
__device__ __forceinline__ float hi2f(unsigned int u) {
  return __uint_as_float(u & 0xffff0000u);
}

// ---------------------------------------------------------------------------
// Shared A-split helper: fp32 x8 -> 3-plane packed uint4s (cvt_pk fast path).
// ---------------------------------------------------------------------------
__device__ __forceinline__ void split3_pack(const float* v, uint4& uh,
                                            uint4& um, uint4& ul) {
  unsigned int hw[4], mw[4], lw[4];
#pragma unroll
  for (int jj = 0; jj < 4; ++jj) {
    float va = v[2 * jj], vb = v[2 * jj + 1];
    unsigned int h = cvtpk(va, vb);
    float ra = va - lo2f(h), rb = vb - hi2f(h);
    unsigned int m = cvtpk(ra, rb);
    float sa = ra - lo2f(m), sb = rb - hi2f(m);
    unsigned int l = cvtpk(sa, sb);
    hw[jj] = h; mw[jj] = m; lw[jj] = l;
  }
  uh.x = hw[0]; uh.y = hw[1]; uh.z = hw[2]; uh.w = hw[3];
  um.x = mw[0]; um.y = mw[1]; um.z = mw[2]; um.w = mw[3];
  ul.x = lw[0]; ul.y = lw[1]; ul.z = lw[2]; ul.w = lw[3];
}

// ---------------------------------------------------------------------------
// wsplit3: pre-pack a K x 256 fp32 weight into 3-plane bf16 fragment order.
// Layout (uint4): [((kt*16+gct)*3+p)*64 + lane].
// ---------------------------------------------------------------------------
__global__ __launch_bounds__(256) void wsplit3_kernel(
    const float* __restrict__ W, uint4* __restrict__ Wp, int Kreal) {
  const int gid = blockIdx.x * 256 + threadIdx.x;
  const int lane = gid & 63;
  const int rest = gid >> 6;          // kt*16 + gct
  const int gct = rest & 15;
  const int kt = rest >> 4;
  const int k0 = kt * 32 + (lane >> 4) * 8;
  const int c = gct * 16 + (lane & 15);
  float v[8];
#pragma unroll
  for (int j = 0; j < 8; ++j) {
    int kk = k0 + j;
    v[j] = (kk < Kreal) ? W[(size_t)kk * 256 + c] : 0.f;
  }
  uint4 uh, um, ul;
  split3_pack(v, uh, um, ul);
  Wp[(size_t)(rest * 3 + 0) * 64 + lane] = uh;
  Wp[(size_t)(rest * 3 + 1) * 64 + lane] = um;
  Wp[(size_t)(rest * 3 + 2) * 64 + lane] = ul;
}

// ---------------------------------------------------------------------------
// Fused K+V projection, 3-plane MFMA. Tile 32 rows x 256 cols, 4 waves.
// ---------------------------------------------------------------------------
__global__ __launch_bounds__(256) void kvproj3_kernel(
    const float* __restrict__ enc, const uint4* __restrict__ Wk3,
    const uint4* __restrict__ Wv3, float* __restrict__ kout,
    float* __restrict__ vout) {
  const int KT = 8;
  const int NKG = KT * 4;              // 32 k-groups of 8
  const int RSTRIDE = KT * 12 + 1;     // 97
  __shared__ uint4 als[32 * 97];       // 49.7 KB
  const int tid = threadIdx.x;
  const int row0 = blockIdx.x * 32;
  for (int i = tid; i < 32 * NKG; i += 256) {
    const int row = i >> 5;
    const int kg = i & 31;
    float v[8];
    const float4* s = (const float4*)(enc + (size_t)(row0 + row) * 256 + kg * 8);
    float4 x0 = s[0], x1 = s[1];
    v[0] = x0.x; v[1] = x0.y; v[2] = x0.z; v[3] = x0.w;
    v[4] = x1.x; v[5] = x1.y; v[6] = x1.z; v[7] = x1.w;
    uint4 uh, um, ul;
    split3_pack(v, uh, um, ul);
    const int slot = row * RSTRIDE + kg;
    als[slot] = uh;
    als[slot + NKG] = um;
    als[slot + 2 * NKG] = ul;
  }
  __syncthreads();
  const int w = tid >> 6;
  const int lane = tid & 63;
  const int lr = lane & 15;
  const int lg4 = lane >> 4;
  f32x4 acck[2][4], accv[2][4];
#pragma unroll
  for (int rt = 0; rt < 2; ++rt)
#pragma unroll
    for (int ct = 0; ct < 4; ++ct) {
      acck[rt][ct] = (f32x4){0.f, 0.f, 0.f, 0.f};
      accv[rt][ct] = (f32x4){0.f, 0.f, 0.f, 0.f};
    }
  for (int kt = 0; kt < KT; ++kt) {
    short8 ah[2], am[2], al[2];
#pragma unroll
    for (int rt = 0; rt < 2; ++rt) {
      const int base = (rt * 16 + lr) * RSTRIDE + kt * 4 + lg4;
      ah[rt] = __builtin_bit_cast(short8, als[base]);
      am[rt] = __builtin_bit_cast(short8, als[base + NKG]);
      al[rt] = __builtin_bit_cast(short8, als[base + 2 * NKG]);
    }
#pragma unroll
    for (int ct = 0; ct < 4; ++ct) {
      const int gct = w * 4 + ct;
      const size_t base = (size_t)((kt * 16 + gct) * 3) * 64 + lane;
      {
        short8 bh = __builtin_bit_cast(short8, Wk3[base]);
        short8 bm = __builtin_bit_cast(short8, Wk3[base + 64]);
        short8 bl = __builtin_bit_cast(short8, Wk3[base + 128]);
#pragma unroll
        for (int rt = 0; rt < 2; ++rt) {
          f32x4 a = acck[rt][ct];
          a = __builtin_amdgcn_mfma_f32_16x16x32_bf16(ah[rt], bh, a, 0, 0, 0);
          a = __builtin_amdgcn_mfma_f32_16x16x32_bf16(ah[rt], bm, a, 0, 0, 0);
          a = __builtin_amdgcn_mfma_f32_16x16x32_bf16(am[rt], bh, a, 0, 0, 0);
          a = __builtin_amdgcn_mfma_f32_16x16x32_bf16(am[rt], bm, a, 0, 0, 0);
          a = __builtin_amdgcn_mfma_f32_16x16x32_bf16(ah[rt], bl, a, 0, 0, 0);
          a = __builtin_amdgcn_mfma_f32_16x16x32_bf16(al[rt], bh, a, 0, 0, 0);
          acck[rt][ct] = a;
        }
      }
      {
        short8 bh = __builtin_bit_cast(short8, Wv3[base]);
        short8 bm = __builtin_bit_cast(short8, Wv3[base + 64]);
        short8 bl = __builtin_bit_cast(short8, Wv3[base + 128]);
#pragma unroll
        for (int rt = 0; rt < 2; ++rt) {
          f32x4 a = accv[rt][ct];
          a = __builtin_amdgcn_mfma_f32_16x16x32_bf16(ah[rt], bh, a, 0, 0, 0);
          a = __builtin_amdgcn_mfma_f32_16x16x32_bf16(ah[rt], bm, a, 0, 0, 0);
          a = __builtin_amdgcn_mfma_f32_16x16x32_bf16(am[rt], bh, a, 0, 0, 0);
          a = __builtin_amdgcn_mfma_f32_16x16x32_bf16(am[rt], bm, a, 0, 0, 0);
          a = __builtin_amdgcn_mfma_f32_16x16x32_bf16(ah[rt], bl, a, 0, 0, 0);
          a = __builtin_amdgcn_mfma_f32_16x16x32_bf16(al[rt], bh, a, 0, 0, 0);
          accv[rt][ct] = a;
        }
      }
    }
  }
#pragma unroll
  for (int rt = 0; rt < 2; ++rt) {
#pragma unroll
    for (int ct = 0; ct < 4; ++ct) {
      const int gct = w * 4 + ct;
#pragma unroll
      for (int reg = 0; reg < 4; ++reg) {
        const int row = row0 + rt * 16 + lg4 * 4 + reg;
        int bb = row / N1, nn = row - bb * N1;
        size_t o = (((size_t)bb * H + gct) * N1 + nn) * D + lr;
        kout[o] = acck[rt][ct][reg];
        vout[o] = accv[rt][ct][reg];
      }
    }
  }
}

// ---------------------------------------------------------------------------
// proj3 (Q only): MODE 1, KT=9.
// ---------------------------------------------------------------------------
template <int KT, int MODE>
__global__ __launch_bounds__(256) void proj3_kernel(
    const float* __restrict__ src, const float* __restrict__ attr,
    const uint4* __restrict__ Wp3, float* __restrict__ outp) {
  const int RSTRIDE = KT * 12 + 1;
  __shared__ uint4 als[32 * (KT * 12 + 1)];
  const int tid = threadIdx.x;
  const int row0 = blockIdx.x * 32;
  const int NKG = KT * 4;
  for (int i = tid; i < 32 * NKG; i += 256) {
    const int row = i / NKG;
    const int kg = i - row * NKG;
    float v[8];
    const int kbase = kg * 8;
    if (MODE == 0 || kbase < 256) {
      const float4* s = (const float4*)(src + (size_t)(row0 + row) * 256 + kbase);
      float4 x0 = s[0], x1 = s[1];
      v[0] = x0.x; v[1] = x0.y; v[2] = x0.z; v[3] = x0.w;
      v[4] = x1.x; v[5] = x1.y; v[6] = x1.z; v[7] = x1.w;
    } else {
#pragma unroll
      for (int j = 0; j < 8; ++j) {
        int k = kbase + j;
        v[j] = (k >= 256 && k < 260) ? attr[(size_t)(row0 + row) * 4 + (k - 256)]
                                     : 0.f;
      }
    }
    uint4 uh, um, ul;
    split3_pack(v, uh, um, ul);
    const int slot = row * RSTRIDE + kg;
    als[slot] = uh;
    als[slot + NKG] = um;
    als[slot + 2 * NKG] = ul;
  }
  __syncthreads();
  const int w = tid >> 6;
  const int lane = tid & 63;
  const int lr = lane & 15;
  const int lg4 = lane >> 4;
  f32x4 acc[2][4];
#pragma unroll
  for (int rt = 0; rt < 2; ++rt)
#pragma unroll
    for (int ct = 0; ct < 4; ++ct) acc[rt][ct] = (f32x4){0.f, 0.f, 0.f, 0.f};
  for (int kt = 0; kt < KT; ++kt) {
    short8 ah[2], am[2], al[2];
#pragma unroll
    for (int rt = 0; rt < 2; ++rt) {
      const int base = (rt * 16 + lr) * RSTRIDE + kt * 4 + lg4;
      ah[rt] = __builtin_bit_cast(short8, als[base]);
      am[rt] = __builtin_bit_cast(short8, als[base + NKG]);
      al[rt] = __builtin_bit_cast(short8, als[base + 2 * NKG]);
    }
#pragma unroll
    for (int ct = 0; ct < 4; ++ct) {
      const int gct = w * 4 + ct;
      const size_t base = (size_t)((kt * 16 + gct) * 3) * 64 + lane;
      short8 bh = __builtin_bit_cast(short8, Wp3[base]);
      short8 bm = __builtin_bit_cast(short8, Wp3[base + 64]);
      short8 bl = __builtin_bit_cast(short8, Wp3[base + 128]);
#pragma unroll
      for (int rt = 0; rt < 2; ++rt) {
        f32x4 a = acc[rt][ct];
        a = __builtin_amdgcn_mfma_f32_16x16x32_bf16(ah[rt], bh, a, 0, 0, 0);
        a = __builtin_amdgcn_mfma_f32_16x16x32_bf16(ah[rt], bm, a, 0, 0, 0);
        a = __builtin_amdgcn_mfma_f32_16x16x32_bf16(am[rt], bh, a, 0, 0, 0);
        a = __builtin_amdgcn_mfma_f32_16x16x32_bf16(am[rt], bm, a, 0, 0, 0);
        a = __builtin_amdgcn_mfma_f32_16x16x32_bf16(ah[rt], bl, a, 0, 0, 0);
        a = __builtin_amdgcn_mfma_f32_16x16x32_bf16(al[rt], bh, a, 0, 0, 0);
        acc[rt][ct] = a;
      }
    }
  }
#pragma unroll
  for (int rt = 0; rt < 2; ++rt) {
#pragma unroll
    for (int ct = 0; ct < 4; ++ct) {
      const int gct = w * 4 + ct;
#pragma unroll
      for (int reg = 0; reg < 4; ++reg) {
        const int row = row0 + rt * 16 + lg4 * 4 + reg;
        size_t o;
        if (MODE == 0) {
          int bb = row / N1, nn = row - bb * N1;
          o = (((size_t)bb * H + gct) * N1 + nn) * D + lr;
        } else {
          int bb = row / P, pp = row - bb * P;
          o = (((size_t)bb * H + gct) * P + pp) * D + lr;
        }
        outp[o] = acc[rt][ct][reg];
      }
    }
  }
}

// ---------------------------------------------------------------------------
// Attention (round-9 proven): grid B*8 (head pairs). 256 threads = 4 waves.
// wave w: head = h0 + (w>>1); row = (w&1)*64 + lane (1 row/lane).
// K+V in LDS, chunked over keys {52, 49} -> 13.3 KB total.
// exp2-domain online softmax; masks prefetched.
// ---------------------------------------------------------------------------
__device__ __forceinline__ float dot16f(
    const float4& a0, const float4& a1, const float4& a2, const float4& a3,
    const float4& b0, const float4& b1, const float4& b2, const float4& b3) {
  float s = a0.x * b0.x;
  s = fmaf(a0.y, b0.y, s); s = fmaf(a0.z, b0.z, s); s = fmaf(a0.w, b0.w, s);
  s = fmaf(a1.x, b1.x, s); s = fmaf(a1.y, b1.y, s); s = fmaf(a1.z, b1.z, s);
  s = fmaf(a1.w, b1.w, s);
  s = fmaf(a2.x, b2.x, s); s = fmaf(a2.y, b2.y, s); s = fmaf(a2.z, b2.z, s);
  s = fmaf(a2.w, b2.w, s);
  s = fmaf(a3.x, b3.x, s); s = fmaf(a3.y, b3.y, s); s = fmaf(a3.z, b3.z, s);
  s = fmaf(a3.w, b3.w, s);
  return s;
}

__global__ __launch_bounds__(256) void attn_kernel(
    const float* __restrict__ q, const float* __restrict__ k,
    const float* __restrict__ v, const float* __restrict__ ninf,
    float* __restrict__ x) {
  const int b = blockIdx.x >> 3;
  const int h0 = (blockIdx.x & 7) * 2;
  __shared__ float4 kl4[2 * 208];      // 2 heads x 52 keys x 16 floats
  __shared__ float4 vl4[2 * 208];
  const int tid = threadIdx.x;
  const int w = tid >> 6;
  const int lane = tid & 63;
  const int hh = w >> 1;
  const int h = h0 + hh;
  const int prow = (w & 1) * 64 + lane;
  const bool act = (prow < P);
  const int p = act ? prow : (P - 1);
  const float LOG2E = 1.4426950408889634f;
  const float c1 = 0.25f * LOG2E;
  const float* qb = q + (((size_t)b * H + h) * P + p) * D;
  float4 qa0 = *(const float4*)&qb[0];
  float4 qa1 = *(const float4*)&qb[4];
  float4 qa2 = *(const float4*)&qb[8];
  float4 qa3 = *(const float4*)&qb[12];
  qa0.x *= c1; qa0.y *= c1; qa0.z *= c1; qa0.w *= c1;
  qa1.x *= c1; qa1.y *= c1; qa1.z *= c1; qa1.w *= c1;
  qa2.x *= c1; qa2.y *= c1; qa2.z *= c1; qa2.w *= c1;
  qa3.x *= c1; qa3.y *= c1; qa3.z *= c1; qa3.w *= c1;
  const float* mrow = ninf + ((size_t)b * P + p) * N1;
  const float* kw = (const float*)(kl4 + hh * 208);
  const float* vw = (const float*)(vl4 + hh * 208);

  float m2 = -1e30f, l = 0.f;
  float o[16];
#pragma unroll
  for (int d = 0; d < 16; ++d) o[d] = 0.f;

#pragma unroll
  for (int ch = 0; ch < 2; ++ch) {
    const int c0 = ch ? 52 : 0;
    const int len = ch ? 49 : 52;
    const int nf4 = len * 4;           // float4 per head
    __syncthreads();                   // previous chunk fully consumed
    for (int i = tid; i < 2 * nf4; i += 256) {
      int hs = i / nf4, rem = i - hs * nf4;
      const float4* ks =
          (const float4*)(k + (((size_t)b * H + h0 + hs) * N1 + c0) * D);
      const float4* vs =
          (const float4*)(v + (((size_t)b * H + h0 + hs) * N1 + c0) * D);
      kl4[hs * 208 + rem] = ks[rem];
      vl4[hs * 208 + rem] = vs[rem];
    }
    __syncthreads();
    const int nit = len >> 2;          // 13 / 12
    float4 mk = *(const float4*)&mrow[c0];
    for (int it = 0; it < nit; ++it) {
      const int j = it * 4;
      const int nn = (it < nit - 1) ? (c0 + j + 4) : c0;
      float4 nx = *(const float4*)&mrow[nn];
      const float4* kr0 = (const float4*)&kw[(j + 0) * D];
      const float4* kr1 = (const float4*)&kw[(j + 1) * D];
      const float4* kr2 = (const float4*)&kw[(j + 2) * D];
      const float4* kr3 = (const float4*)&kw[(j + 3) * D];
      float4 k00 = kr0[0], k01 = kr0[1], k02 = kr0[2], k03 = kr0[3];
      float4 k10 = kr1[0], k11 = kr1[1], k12 = kr1[2], k13 = kr1[3];
      float4 k20 = kr2[0], k21 = kr2[1], k22 = kr2[2], k23 = kr2[3];
      float4 k30 = kr3[0], k31 = kr3[1], k32 = kr3[2], k33 = kr3[3];
      float s0 = fmaf(mk.x, LOG2E, dot16f(qa0, qa1, qa2, qa3, k00, k01, k02, k03));
      float s1 = fmaf(mk.y, LOG2E, dot16f(qa0, qa1, qa2, qa3, k10, k11, k12, k13));
      float s2 = fmaf(mk.z, LOG2E, dot16f(qa0, qa1, qa2, qa3, k20, k21, k22, k23));
      float s3 = fmaf(mk.w, LOG2E, dot16f(qa0, qa1, qa2, qa3, k30, k31, k32, k33));
      float mn = fmaxf(fmaxf(fmaxf(s0, s1), fmaxf(s2, s3)), m2);
      float sc = exp2f(m2 - mn);
      float p0 = exp2f(s0 - mn), p1 = exp2f(s1 - mn);
      float p2 = exp2f(s2 - mn), p3 = exp2f(s3 - mn);
      l = fmaf(l, sc, (p0 + p1) + (p2 + p3));
      const float4* vr0 = (const float4*)&vw[(j + 0) * D];
      const float4* vr1 = (const float4*)&vw[(j + 1) * D];
      const float4* vr2 = (const float4*)&vw[(j + 2) * D];
      const float4* vr3 = (const float4*)&vw[(j + 3) * D];
#pragma unroll
      for (int dq = 0; dq < 4; ++dq) {
        float4 v0 = vr0[dq], v1 = vr1[dq], v2 = vr2[dq], v3 = vr3[dq];
        o[4 * dq + 0] = fmaf(o[4 * dq + 0], sc,
            fmaf(p0, v0.x, fmaf(p1, v1.x, fmaf(p2, v2.x, p3 * v3.x))));
        o[4 * dq + 1] = fmaf(o[4 * dq + 1], sc,
            fmaf(p0, v0.y, fmaf(p1, v1.y, fmaf(p2, v2.y, p3 * v3.y))));
        o[4 * dq + 2] = fmaf(o[4 * dq + 2], sc,
            fmaf(p0, v0.z, fmaf(p1, v1.z, fmaf(p2, v2.z, p3 * v3.z))));
        o[4 * dq + 3] = fmaf(o[4 * dq + 3], sc,
            fmaf(p0, v0.w, fmaf(p1, v1.w, fmaf(p2, v2.w, p3 * v3.w))));
      }
      m2 = mn;
      mk = nx;
    }
  }
  // tail key 100 = chunk-1 LDS slot 48
  {
    const float tm = mrow[100];
    const float4* kr = (const float4*)&kw[48 * D];
    float4 k0 = kr[0], k1 = kr[1], k2 = kr[2], k3 = kr[3];
    float s = fmaf(tm, LOG2E, dot16f(qa0, qa1, qa2, qa3, k0, k1, k2, k3));
    float mn = fmaxf(m2, s);
    float sc = exp2f(m2 - mn);
    float pp = exp2f(s - mn);
    l = fmaf(l, sc, pp);
    const float4* vr = (const float4*)&vw[48 * D];
#pragma unroll
    for (int dq = 0; dq < 4; ++dq) {
      float4 v0 = vr[dq];
      o[4 * dq + 0] = fmaf(o[4 * dq + 0], sc, pp * v0.x);
      o[4 * dq + 1] = fmaf(o[4 * dq + 1], sc, pp * v0.y);
      o[4 * dq + 2] = fmaf(o[4 * dq + 2], sc, pp * v0.z);
      o[4 * dq + 3] = fmaf(o[4 * dq + 3], sc, pp * v0.w);
    }
  }
  if (act) {
    const float inv = 1.f / l;
    float* xr = &x[((size_t)b * P + p) * HD + h * D];
#pragma unroll
    for (int dq = 0; dq < 4; ++dq) {
      float4 t;
      t.x = o[4 * dq + 0] * inv; t.y = o[4 * dq + 1] * inv;
      t.z = o[4 * dq + 2] * inv; t.w = o[4 * dq + 3] * inv;
      *(float4*)&xr[4 * dq] = t;
    }
  }
}

// ---------------------------------------------------------------------------
// Kernel 4: router logits (fp32) + top2 + gates; emits xsplit (2-plane).
// ---------------------------------------------------------------------------
__global__ __launch_bounds__(256) void logits_top2_kernel(
    const float* __restrict__ x, const float* __restrict__ Wg,
    int* __restrict__ topi, float* __restrict__ topg,
    ushort_t* __restrict__ xsplit) {
  __shared__ float xl[32][260];
  __shared__ float wg[E * NE];
  __shared__ float lg[32][9];
  const int tid = threadIdx.x;
  const int t0 = blockIdx.x * 32;
  for (int r = 0; r < 32; ++r) {
    float val = x[(size_t)(t0 + r) * HD + tid];
    xl[r][tid] = val;
    unsigned short hi = f2bf(val);
    unsigned short lo = f2bf(val - bf2f(hi));
    xsplit[(size_t)(t0 + r) * 512 + tid] = hi;
    xsplit[(size_t)(t0 + r) * 512 + 256 + tid] = lo;
  }
  for (int i = tid; i < E * NE; i += 256) wg[i] = Wg[i];
  __syncthreads();
  const int r = tid >> 3, e = tid & 7;
  float acc = 0.f;
  for (int f = 0; f < E; ++f) acc += xl[r][f] * wg[f * NE + e];
  lg[r][e] = acc;
  __syncthreads();
  if (tid < 32) {
    float v[8];
#pragma unroll
    for (int j = 0; j < 8; ++j) v[j] = lg[tid][j];
    int i1 = 0; float v1 = v[0];
#pragma unroll
    for (int j = 1; j < 8; ++j) if (v[j] > v1) { v1 = v[j]; i1 = j; }
    int i2 = -1; float v2 = -1e30f;
#pragma unroll
    for (int j = 0; j < 8; ++j)
      if (j != i1 && v[j] > v2) { v2 = v[j]; i2 = j; }
    float ex = __expf(v2 - v1);
    float g1 = 1.f / (1.f + ex);
    float g2 = ex / (1.f + ex);
    int t = t0 + tid;
    topi[t * 2 + 0] = i1; topi[t * 2 + 1] = i2;
    topg[t * 2 + 0] = g1; topg[t * 2 + 1] = g2;
  }
}

// ---------------------------------------------------------------------------
// Kernel 5: build per-expert token lists. UNCHANGED.
// ---------------------------------------------------------------------------
__global__ __launch_bounds__(1024) void build_lists_kernel(
    const int* __restrict__ topi, const float* __restrict__ topg,
    int* __restrict__ list_tok, float* __restrict__ list_gate,
    int* __restrict__ counts) {
  const int e = blockIdx.x;
  const int tid = threadIdx.x;
  const int lane = tid & 63, w = tid >> 6;
  __shared__ int wsum[16];
  int running = 0;
  for (int c = 0; c < NTOK; c += 1024) {
    int t = c + tid;
    int ia = topi[t * 2 + 0], ib = topi[t * 2 + 1];
    int slot = (ia == e) ? 0 : ((ib == e) ? 1 : -1);
    int f = (slot >= 0) ? 1 : 0;
    unsigned long long m = __ballot(f);
    if (lane == 0) wsum[w] = __popcll(m);
    __syncthreads();
    int wbase = 0, total = 0;
#pragma unroll
    for (int i = 0; i < 16; ++i) {
      int s = wsum[i];
      if (i < w) wbase += s;
      total += s;
    }
    if (f) {
      int prefix = __popcll(m & ((1ull << lane) - 1ull));
      int pos = running + wbase + prefix;
      list_tok[e * NTOK + pos] = (t << 1) | slot;
      list_gate[e * NTOK + pos] = topg[t * 2 + slot];
    }
    running += total;
    __syncthreads();
  }
  if (tid == 0) counts[e] = running;
}

// ---------------------------------------------------------------------------
// Kernel 5b: expert weight 2-plane prepack (cvt_pk fast path).
// ---------------------------------------------------------------------------
__global__ __launch_bounds__(256) void wsplit_kernel(
    const float* __restrict__ eW, uint4* __restrict__ Wp) {
  const int gid = blockIdx.x * 256 + threadIdx.x;
  const int lane = gid & 63;
  const int rest = gid >> 6;
  const int gct = rest & 15;
  const int kt = (rest >> 4) & 7;
  const int e = rest >> 7;
  const int kbase = kt * 32 + (lane >> 4) * 8;
  const int c = gct * 16 + (lane & 15);
  unsigned int hi[4], lo[4];
#pragma unroll
  for (int jj = 0; jj < 4; ++jj) {
    float v0 = eW[((size_t)e * HD + (kbase + 2 * jj)) * E + c];
    float v1 = eW[((size_t)e * HD + (kbase + 2 * jj + 1)) * E + c];
    unsigned int h = cvtpk(v0, v1);
    float r0 = v0 - lo2f(h), r1 = v1 - hi2f(h);
    unsigned int l = cvtpk(r0, r1);
    hi[jj] = h; lo[jj] = l;
  }
  uint4 uh, ul;
  uh.x = hi[0]; uh.y = hi[1]; uh.z = hi[2]; uh.w = hi[3];
  ul.x = lo[0]; ul.y = lo[1]; ul.z = lo[2]; ul.w = lo[3];
  Wp[(size_t)(rest * 2 + 0) * 64 + lane] = uh;
  Wp[(size_t)(rest * 2 + 1) * 64 + lane] = ul;
}

// ---------------------------------------------------------------------------
// Kernel 6: sparse expert GEMM via split-bf16 MFMA. 48-token tiles (3 rt).
// ---------------------------------------------------------------------------
__global__ __launch_bounds__(256) void expert_gemm_kernel(
    const ushort_t* __restrict__ xsplit, const uint4* __restrict__ Wp,
    const float* __restrict__ eb, const int* __restrict__ list_tok,
    const float* __restrict__ list_gate, const int* __restrict__ counts,
    float* __restrict__ p0, float* __restrict__ p1) {
  int e = 0, t0 = -1;
  {
    int rem = blockIdx.x;
    for (int i = 0; i < NE; ++i) {
      int nt = (counts[i] + 47) / 48;
      if (rem < nt) { e = i; t0 = rem * 48; break; }
      rem -= nt;
    }
  }
  if (t0 < 0) return;
  const int cnt = counts[e];
  const int nr = min(48, cnt - t0);
  __shared__ uint4 xls[48 * 65];       // 49.9 KB
  __shared__ int stok[48];
  __shared__ float sg[48];
  const int tid = threadIdx.x;
  if (tid < 48) {
    int src = e * NTOK + t0 + ((tid < nr) ? tid : 0);
    stok[tid] = list_tok[src];
    sg[tid] = (tid < nr) ? list_gate[e * NTOK + t0 + tid] : 0.f;
  }
  __syncthreads();
  for (int i = tid; i < 48 * 64; i += 256) {
    int r = i >> 6, ch = i & 63;
    const uint4* src = (const uint4*)(xsplit + (size_t)(stok[r] >> 1) * 512);
    xls[r * 65 + ch] = src[ch];
  }
  __syncthreads();
  const int w = tid >> 6;
  const int lane = tid & 63;
  const int lr = lane & 15;
  const int lg4 = lane >> 4;
  f32x4 acc[3][4];
#pragma unroll
  for (int rt = 0; rt < 3; ++rt)
#pragma unroll
    for (int ct = 0; ct < 4; ++ct) acc[rt][ct] = (f32x4){0.f, 0.f, 0.f, 0.f};

  for (int kt = 0; kt < 8; ++kt) {
    short8 afrag[3][2];
#pragma unroll
    for (int rt = 0; rt < 3; ++rt)
#pragma unroll
      for (int pl = 0; pl < 2; ++pl) {
        uint4 u = xls[(rt * 16 + lr) * 65 + pl * 32 + kt * 4 + lg4];
        afrag[rt][pl] = __builtin_bit_cast(short8, u);
      }
#pragma unroll
    for (int ct = 0; ct < 4; ++ct) {
      const int gct = w * 4 + ct;
      const size_t base = (size_t)(((e * 8 + kt) * 16 + gct) * 2) * 64 + lane;
      short8 bh = __builtin_bit_cast(short8, Wp[base]);
      short8 bl = __builtin_bit_cast(short8, Wp[base + 64]);
#pragma unroll
      for (int rt = 0; rt < 3; ++rt) {
        acc[rt][ct] = __builtin_amdgcn_mfma_f32_16x16x32_bf16(
            afrag[rt][0], bh, acc[rt][ct], 0, 0, 0);
        acc[rt][ct] = __builtin_amdgcn_mfma_f32_16x16x32_bf16(
            afrag[rt][0], bl, acc[rt][ct], 0, 0, 0);
        acc[rt][ct] = __builtin_amdgcn_mfma_f32_16x16x32_bf16(
            afrag[rt][1], bh, acc[rt][ct], 0, 0, 0);
      }
    }
  }
#pragma unroll
  for (int rt = 0; rt < 3; ++rt) {
#pragma unroll
    for (int ct = 0; ct < 4; ++ct) {
      const int col = (w * 4 + ct) * 16 + lr;
      const float bias = eb[e * E + col];
#pragma unroll
      for (int reg = 0; reg < 4; ++reg) {
        const int ridx = rt * 16 + lg4 * 4 + reg;
        if (ridx < nr) {
          const int tokw = stok[ridx];
          const float g = sg[ridx];
          float* dst = ((tokw & 1) ? p1 : p0) + (size_t)(tokw >> 1) * E + col;
          *dst = g * (acc[rt][ct][reg] + bias);
        }
      }
    }
  }
}

// ---------------------------------------------------------------------------
// Kernel 7: fused score2 + tanh-clip + softmax -> probs into d_out.
// grid 512 = (b, half); block 256 = 4 waves. 50 rows per block.
// lane owns output cols (lane, lane+64); wave w owns rows w, w+4, ...
// mh = p0+p1 staged in LDS; one LDS broadcast read feeds 8 FMAs.
// ---------------------------------------------------------------------------
__global__ __launch_bounds__(256) void score2_fused_kernel(
    const float* __restrict__ p0, const float* __restrict__ p1,
    const float* __restrict__ enc, const float* __restrict__ ab,
    const float* __restrict__ ab1, const float* __restrict__ ninf,
    float* __restrict__ out) {
  const int b = blockIdx.x >> 1;
  const int half = blockIdx.x & 1;
  const int r0 = half * 50;
  __shared__ float4 mh4[50 * 64];      // 51.2 KB
  const int tid = threadIdx.x;
  for (int i = tid; i < 50 * 64; i += 256) {
    int r = i >> 6, c4 = i & 63;
    size_t idx = (size_t)(b * P + r0 + r) * 64 + c4;
    float4 a = ((const float4*)p0)[idx];
    float4 c = ((const float4*)p1)[idx];
    float4 s;
    s.x = a.x + c.x; s.y = a.y + c.y; s.z = a.z + c.z; s.w = a.w + c.w;
    mh4[i] = s;
  }
  __syncthreads();
  const int w = tid >> 6;
  const int lane = tid & 63;
  const int n0 = lane;
  const int n1v = lane + 64;
  const bool has1 = (n1v < N1);        // lane < 37
  const int n1 = has1 ? n1v : (N1 - 1);
  const float4* er0 = (const float4*)(enc + ((size_t)b * N1 + n0) * E);
  const float4* er1 = (const float4*)(enc + ((size_t)b * N1 + n1) * E);
  float acc0[13], acc1[13];
#pragma unroll
  for (int j = 0; j < 13; ++j) { acc0[j] = 0.f; acc1[j] = 0.f; }
  for (int kk = 0; kk < 64; ++kk) {
    float4 e0 = er0[kk];
    float4 e1 = er1[kk];
#pragma unroll
    for (int j = 0; j < 13; ++j) {
      const int r = w + j * 4;
      if (r < 50) {
        float4 mv = mh4[r * 64 + kk];
        acc0[j] = fmaf(mv.w, e0.w,
                  fmaf(mv.z, e0.z, fmaf(mv.y, e0.y, fmaf(mv.x, e0.x, acc0[j]))));
        acc1[j] = fmaf(mv.w, e1.w,
                  fmaf(mv.z, e1.z, fmaf(mv.y, e1.y, fmaf(mv.x, e1.x, acc1[j]))));
      }
    }
  }
  // Epilogue: bias + tanh clip + ninf + row softmax, write probs.
#pragma unroll
  for (int j = 0; j < 13; ++j) {
    const int r = w + j * 4;
    if (r < 50) {
      const int prow = b * P + r0 + r;
      const float* arow = ab + (size_t)prow * N1;
      const float* a1row = ab1 + (size_t)prow * N1;
      const float* nrow = ninf + (size_t)prow * N1;
      float s0 = acc0[j] + arow[n0] + a1row[n0];
      float e20 = __expf(s0 * 0.125f);
      float v0 = 10.f - 20.f / (e20 + 1.f) + nrow[n0];
      float v1 = -1e30f;
      if (has1) {
        float s1 = acc1[j] + arow[n1v] + a1row[n1v];
        float e21 = __expf(s1 * 0.125f);
        v1 = 10.f - 20.f / (e21 + 1.f) + nrow[n1v];
      }
      float mx = fmaxf(v0, v1);
#pragma unroll
      for (int off = 32; off > 0; off >>= 1)
        mx = fmaxf(mx, __shfl_xor(mx, off, 64));
      float q0 = __expf(v0 - mx);
      float q1 = has1 ? __expf(v1 - mx) : 0.f;
      float sum = q0 + q1;
#pragma unroll
      for (int off = 32; off > 0; off >>= 1)
        sum += __shfl_xor(sum, off, 64);
      float inv = 1.f / sum;
      float* orow = out + (size_t)prow * N1;
      orow[n0] = q0 * inv;
      if (has1) orow[n1v] = q1 * inv;
    }
  }
}

// ---------------------------------------------------------------------------
extern "C" void kernel_launch(void* const* d_in, const int* in_sizes, int n_in,
                              void* d_out, int out_size, void* d_ws,
                              size_t ws_size, hipStream_t stream) {
  const float* eln  = (const float*)d_in[0];
  const float* attr = (const float*)d_in[1];
  const float* enc  = (const float*)d_in[2];
  const float* ninf = (const float*)d_in[3];
  const float* ab   = (const float*)d_in[4];
  const float* ab1  = (const float*)d_in[5];
  const float* Wq   = (const float*)d_in[6];
  const float* Wk   = (const float*)d_in[7];
  const float* Wv   = (const float*)d_in[8];
  const float* Wg   = (const float*)d_in[9];
  const float* eW   = (const float*)d_in[10];
  const float* eb   = (const float*)d_in[11];
  float* out = (float*)d_out;

  char* ws = (char*)d_ws;
  size_t off = 0;
  auto carve = [&](size_t bytes) {
    char* p = ws + off;
    off += (bytes + 255) & ~size_t(255);
    return p;
  };
  float* kbuf = (float*)carve(sizeof(float) * NKV * HD);
  float* vbuf = (float*)carve(sizeof(float) * NKV * HD);
  float* qbuf = (float*)carve(sizeof(float) * NTOK * HD);
  float* xbuf = (float*)carve(sizeof(float) * NTOK * HD);
  int*   topi = (int*)carve(sizeof(int) * NTOK * 2);
  float* topg = (float*)carve(sizeof(float) * NTOK * 2);
  int*   counts = (int*)carve(sizeof(int) * 16);
  int*   list_tok = (int*)carve(sizeof(int) * NE * NTOK);
  float* list_gate = (float*)carve(sizeof(float) * NE * NTOK);
  uint4* Wp  = (uint4*)carve(sizeof(ushort_t) * NE * HD * E * 2);  // 2 MB
  uint4* Wk3 = (uint4*)carve((size_t)8 * 16 * 3 * 64 * 16);        // 393 KB
  uint4* Wv3 = (uint4*)carve((size_t)8 * 16 * 3 * 64 * 16);
  uint4* Wq3 = (uint4*)carve((size_t)9 * 16 * 3 * 64 * 16);        // 442 KB
  float* pp0 = kbuf;
  float* pp1 = vbuf;
  ushort_t* xsplit = (ushort_t*)qbuf;

  wsplit_kernel<<<256, 256, 0, stream>>>(eW, Wp);
  wsplit3_kernel<<<32, 256, 0, stream>>>(Wk, Wk3, 256);
  wsplit3_kernel<<<32, 256, 0, stream>>>(Wv, Wv3, 256);
  wsplit3_kernel<<<36, 256, 0, stream>>>(Wq, Wq3, 260);
  kvproj3_kernel<<<NKV / 32, 256, 0, stream>>>(enc, Wk3, Wv3, kbuf, vbuf);
  proj3_kernel<9, 1><<<NTOK / 32, 256, 0, stream>>>(eln, attr, Wq3, qbuf);
  attn_kernel<<<B * 8, 256, 0, stream>>>(qbuf, kbuf, vbuf, ninf, xbuf);
  logits_top2_kernel<<<NTOK / 32, 256, 0, stream>>>(xbuf, Wg, topi, topg,
                                                    xsplit);
  build_lists_kernel<<<NE, 1024, 0, stream>>>(topi, topg, list_tok, list_gate,
                                              counts);
  // max tiles = ceil(2*NTOK/48) + NE = 1067 + 8
  expert_gemm_kernel<<<1075, 256, 0, stream>>>(xsplit, Wp, eb, list_tok,
                                               list_gate, counts, pp0, pp1);
  score2_fused_kernel<<<512, 256, 0, stream>>>(pp0, pp1, enc, ab, ab1, ninf,
                                               out);
}

// Round 12
// 298.232 us; speedup vs baseline: 1.1008x; 1.0696x over previous
//
#include <hip/hip_runtime.h>
#include <hip/hip_bf16.h>

// Problem constants
#define B   256
#define P   100
#define N1  101
#define E   256
#define HD  256          // H*D
#define H   16
#define D   16
#define NE  8
#define NTOK (B*P)       // 25600
#define NKV  (B*N1)      // 25856
#define NCHK 200         // token chunks for list building
#define CHKSZ 128

typedef __attribute__((ext_vector_type(8))) short short8;
typedef __attribute__((ext_vector_type(4))) float f32x4;
typedef unsigned short ushort_t;

__device__ __forceinline__ unsigned short f2bf(float f) {
  unsigned int u = __float_as_uint(f);
  unsigned int r = (u + 0x7fffu + ((u >> 16) & 1u)) >> 16;
  return (unsigned short)r;
}
__device__ __forceinline__ float bf2f(unsigned short b) {
  return __uint_as_float(((unsigned int)b) << 16);
}
// HW packed f32->bf16 (1 instr for 2 elements); D.lo = bf16(a), D.hi = bf16(b)
__device__ __forceinline__ unsigned int cvtpk(float a, float b) {
  unsigned int r;
  asm("v_cvt_pk_bf16_f32 %0, %1, %2" : "=v"(r) : "v"(a), "v"(b));
  return r;
}
__device__ __forceinline__ float lo2f(unsigned int u) {
  return __uint_as_float(u << 16);
}
__device__ __forceinline__ float hi2f(unsigned int u) {
  return __uint_as_float(u & 0xffff0000u);
}

// ---------------------------------------------------------------------------
// Shared A-split helper: fp32 x8 -> 3-plane packed uint4s (cvt_pk fast path).
// ---------------------------------------------------------------------------
__device__ __forceinline__ void split3_pack(const float* v, uint4& uh,
                                            uint4& um, uint4& ul) {
  unsigned int hw[4], mw[4], lw[4];
#pragma unroll
  for (int jj = 0; jj < 4; ++jj) {
    float va = v[2 * jj], vb = v[2 * jj + 1];
    unsigned int h = cvtpk(va, vb);
    float ra = va - lo2f(h), rb = vb - hi2f(h);
    unsigned int m = cvtpk(ra, rb);
    float sa = ra - lo2f(m), sb = rb - hi2f(m);
    unsigned int l = cvtpk(sa, sb);
    hw[jj] = h; mw[jj] = m; lw[jj] = l;
  }
  uh.x = hw[0]; uh.y = hw[1]; uh.z = hw[2]; uh.w = hw[3];
  um.x = mw[0]; um.y = mw[1]; um.z = mw[2]; um.w = mw[3];
  ul.x = lw[0]; ul.y = lw[1]; ul.z = lw[2]; ul.w = lw[3];
}

// ---------------------------------------------------------------------------
// Device body: 3-plane weight prepack (K x 256 -> fragment order).
// ---------------------------------------------------------------------------
__device__ __forceinline__ void wsplit3_body(const float* __restrict__ W,
                                             uint4* __restrict__ Wp, int Kreal,
                                             int gid) {
  const int lane = gid & 63;
  const int rest = gid >> 6;          // kt*16 + gct
  const int gct = rest & 15;
  const int kt = rest >> 4;
  const int k0 = kt * 32 + (lane >> 4) * 8;
  const int c = gct * 16 + (lane & 15);
  float v[8];
#pragma unroll
  for (int j = 0; j < 8; ++j) {
    int kk = k0 + j;
    v[j] = (kk < Kreal) ? W[(size_t)kk * 256 + c] : 0.f;
  }
  uint4 uh, um, ul;
  split3_pack(v, uh, um, ul);
  Wp[(size_t)(rest * 3 + 0) * 64 + lane] = uh;
  Wp[(size_t)(rest * 3 + 1) * 64 + lane] = um;
  Wp[(size_t)(rest * 3 + 2) * 64 + lane] = ul;
}

// ---------------------------------------------------------------------------
// Merged prepack kernel: blocks [0,256) expert W 2-plane; [256,288) Wk3;
// [288,320) Wv3; [320,356) Wq3.
// ---------------------------------------------------------------------------
__global__ __launch_bounds__(256) void prep_kernel(
    const float* __restrict__ eW, uint4* __restrict__ Wp,
    const float* __restrict__ Wk, uint4* __restrict__ Wk3,
    const float* __restrict__ Wv, uint4* __restrict__ Wv3,
    const float* __restrict__ Wq, uint4* __restrict__ Wq3) {
  const int bx = blockIdx.x;
  const int tid = threadIdx.x;
  if (bx < 256) {
    const int gid = bx * 256 + tid;
    const int lane = gid & 63;
    const int rest = gid >> 6;
    const int gct = rest & 15;
    const int kt = (rest >> 4) & 7;
    const int e = rest >> 7;
    const int kbase = kt * 32 + (lane >> 4) * 8;
    const int c = gct * 16 + (lane & 15);
    unsigned int hi[4], lo[4];
#pragma unroll
    for (int jj = 0; jj < 4; ++jj) {
      float v0 = eW[((size_t)e * HD + (kbase + 2 * jj)) * E + c];
      float v1 = eW[((size_t)e * HD + (kbase + 2 * jj + 1)) * E + c];
      unsigned int h = cvtpk(v0, v1);
      float r0 = v0 - lo2f(h), r1 = v1 - hi2f(h);
      unsigned int l = cvtpk(r0, r1);
      hi[jj] = h; lo[jj] = l;
    }
    uint4 uh, ul;
    uh.x = hi[0]; uh.y = hi[1]; uh.z = hi[2]; uh.w = hi[3];
    ul.x = lo[0]; ul.y = lo[1]; ul.z = lo[2]; ul.w = lo[3];
    Wp[(size_t)(rest * 2 + 0) * 64 + lane] = uh;
    Wp[(size_t)(rest * 2 + 1) * 64 + lane] = ul;
  } else if (bx < 288) {
    wsplit3_body(Wk, Wk3, 256, (bx - 256) * 256 + tid);
  } else if (bx < 320) {
    wsplit3_body(Wv, Wv3, 256, (bx - 288) * 256 + tid);
  } else {
    wsplit3_body(Wq, Wq3, 260, (bx - 320) * 256 + tid);
  }
}

// ---------------------------------------------------------------------------
// Fused K+V projection, 3-plane MFMA. Tile 32 rows x 256 cols, 4 waves.
// ---------------------------------------------------------------------------
__global__ __launch_bounds__(256) void kvproj3_kernel(
    const float* __restrict__ enc, const uint4* __restrict__ Wk3,
    const uint4* __restrict__ Wv3, float* __restrict__ kout,
    float* __restrict__ vout) {
  const int KT = 8;
  const int NKG = KT * 4;              // 32 k-groups of 8
  const int RSTRIDE = KT * 12 + 1;     // 97
  __shared__ uint4 als[32 * 97];       // 49.7 KB
  const int tid = threadIdx.x;
  const int row0 = blockIdx.x * 32;
  for (int i = tid; i < 32 * NKG; i += 256) {
    const int row = i >> 5;
    const int kg = i & 31;
    float v[8];
    const float4* s = (const float4*)(enc + (size_t)(row0 + row) * 256 + kg * 8);
    float4 x0 = s[0], x1 = s[1];
    v[0] = x0.x; v[1] = x0.y; v[2] = x0.z; v[3] = x0.w;
    v[4] = x1.x; v[5] = x1.y; v[6] = x1.z; v[7] = x1.w;
    uint4 uh, um, ul;
    split3_pack(v, uh, um, ul);
    const int slot = row * RSTRIDE + kg;
    als[slot] = uh;
    als[slot + NKG] = um;
    als[slot + 2 * NKG] = ul;
  }
  __syncthreads();
  const int w = tid >> 6;
  const int lane = tid & 63;
  const int lr = lane & 15;
  const int lg4 = lane >> 4;
  f32x4 acck[2][4], accv[2][4];
#pragma unroll
  for (int rt = 0; rt < 2; ++rt)
#pragma unroll
    for (int ct = 0; ct < 4; ++ct) {
      acck[rt][ct] = (f32x4){0.f, 0.f, 0.f, 0.f};
      accv[rt][ct] = (f32x4){0.f, 0.f, 0.f, 0.f};
    }
  for (int kt = 0; kt < KT; ++kt) {
    short8 ah[2], am[2], al[2];
#pragma unroll
    for (int rt = 0; rt < 2; ++rt) {
      const int base = (rt * 16 + lr) * RSTRIDE + kt * 4 + lg4;
      ah[rt] = __builtin_bit_cast(short8, als[base]);
      am[rt] = __builtin_bit_cast(short8, als[base + NKG]);
      al[rt] = __builtin_bit_cast(short8, als[base + 2 * NKG]);
    }
#pragma unroll
    for (int ct = 0; ct < 4; ++ct) {
      const int gct = w * 4 + ct;
      const size_t base = (size_t)((kt * 16 + gct) * 3) * 64 + lane;
      {
        short8 bh = __builtin_bit_cast(short8, Wk3[base]);
        short8 bm = __builtin_bit_cast(short8, Wk3[base + 64]);
        short8 bl = __builtin_bit_cast(short8, Wk3[base + 128]);
#pragma unroll
        for (int rt = 0; rt < 2; ++rt) {
          f32x4 a = acck[rt][ct];
          a = __builtin_amdgcn_mfma_f32_16x16x32_bf16(ah[rt], bh, a, 0, 0, 0);
          a = __builtin_amdgcn_mfma_f32_16x16x32_bf16(ah[rt], bm, a, 0, 0, 0);
          a = __builtin_amdgcn_mfma_f32_16x16x32_bf16(am[rt], bh, a, 0, 0, 0);
          a = __builtin_amdgcn_mfma_f32_16x16x32_bf16(am[rt], bm, a, 0, 0, 0);
          a = __builtin_amdgcn_mfma_f32_16x16x32_bf16(ah[rt], bl, a, 0, 0, 0);
          a = __builtin_amdgcn_mfma_f32_16x16x32_bf16(al[rt], bh, a, 0, 0, 0);
          acck[rt][ct] = a;
        }
      }
      {
        short8 bh = __builtin_bit_cast(short8, Wv3[base]);
        short8 bm = __builtin_bit_cast(short8, Wv3[base + 64]);
        short8 bl = __builtin_bit_cast(short8, Wv3[base + 128]);
#pragma unroll
        for (int rt = 0; rt < 2; ++rt) {
          f32x4 a = accv[rt][ct];
          a = __builtin_amdgcn_mfma_f32_16x16x32_bf16(ah[rt], bh, a, 0, 0, 0);
          a = __builtin_amdgcn_mfma_f32_16x16x32_bf16(ah[rt], bm, a, 0, 0, 0);
          a = __builtin_amdgcn_mfma_f32_16x16x32_bf16(am[rt], bh, a, 0, 0, 0);
          a = __builtin_amdgcn_mfma_f32_16x16x32_bf16(am[rt], bm, a, 0, 0, 0);
          a = __builtin_amdgcn_mfma_f32_16x16x32_bf16(ah[rt], bl, a, 0, 0, 0);
          a = __builtin_amdgcn_mfma_f32_16x16x32_bf16(al[rt], bh, a, 0, 0, 0);
          accv[rt][ct] = a;
        }
      }
    }
  }
#pragma unroll
  for (int rt = 0; rt < 2; ++rt) {
#pragma unroll
    for (int ct = 0; ct < 4; ++ct) {
      const int gct = w * 4 + ct;
#pragma unroll
      for (int reg = 0; reg < 4; ++reg) {
        const int row = row0 + rt * 16 + lg4 * 4 + reg;
        int bb = row / N1, nn = row - bb * N1;
        size_t o = (((size_t)bb * H + gct) * N1 + nn) * D + lr;
        kout[o] = acck[rt][ct][reg];
        vout[o] = accv[rt][ct][reg];
      }
    }
  }
}

// ---------------------------------------------------------------------------
// proj3 (Q only): MODE 1, KT=9.
// ---------------------------------------------------------------------------
template <int KT, int MODE>
__global__ __launch_bounds__(256) void proj3_kernel(
    const float* __restrict__ src, const float* __restrict__ attr,
    const uint4* __restrict__ Wp3, float* __restrict__ outp) {
  const int RSTRIDE = KT * 12 + 1;
  __shared__ uint4 als[32 * (KT * 12 + 1)];
  const int tid = threadIdx.x;
  const int row0 = blockIdx.x * 32;
  const int NKG = KT * 4;
  for (int i = tid; i < 32 * NKG; i += 256) {
    const int row = i / NKG;
    const int kg = i - row * NKG;
    float v[8];
    const int kbase = kg * 8;
    if (MODE == 0 || kbase < 256) {
      const float4* s = (const float4*)(src + (size_t)(row0 + row) * 256 + kbase);
      float4 x0 = s[0], x1 = s[1];
      v[0] = x0.x; v[1] = x0.y; v[2] = x0.z; v[3] = x0.w;
      v[4] = x1.x; v[5] = x1.y; v[6] = x1.z; v[7] = x1.w;
    } else {
#pragma unroll
      for (int j = 0; j < 8; ++j) {
        int k = kbase + j;
        v[j] = (k >= 256 && k < 260) ? attr[(size_t)(row0 + row) * 4 + (k - 256)]
                                     : 0.f;
      }
    }
    uint4 uh, um, ul;
    split3_pack(v, uh, um, ul);
    const int slot = row * RSTRIDE + kg;
    als[slot] = uh;
    als[slot + NKG] = um;
    als[slot + 2 * NKG] = ul;
  }
  __syncthreads();
  const int w = tid >> 6;
  const int lane = tid & 63;
  const int lr = lane & 15;
  const int lg4 = lane >> 4;
  f32x4 acc[2][4];
#pragma unroll
  for (int rt = 0; rt < 2; ++rt)
#pragma unroll
    for (int ct = 0; ct < 4; ++ct) acc[rt][ct] = (f32x4){0.f, 0.f, 0.f, 0.f};
  for (int kt = 0; kt < KT; ++kt) {
    short8 ah[2], am[2], al[2];
#pragma unroll
    for (int rt = 0; rt < 2; ++rt) {
      const int base = (rt * 16 + lr) * RSTRIDE + kt * 4 + lg4;
      ah[rt] = __builtin_bit_cast(short8, als[base]);
      am[rt] = __builtin_bit_cast(short8, als[base + NKG]);
      al[rt] = __builtin_bit_cast(short8, als[base + 2 * NKG]);
    }
#pragma unroll
    for (int ct = 0; ct < 4; ++ct) {
      const int gct = w * 4 + ct;
      const size_t base = (size_t)((kt * 16 + gct) * 3) * 64 + lane;
      short8 bh = __builtin_bit_cast(short8, Wp3[base]);
      short8 bm = __builtin_bit_cast(short8, Wp3[base + 64]);
      short8 bl = __builtin_bit_cast(short8, Wp3[base + 128]);
#pragma unroll
      for (int rt = 0; rt < 2; ++rt) {
        f32x4 a = acc[rt][ct];
        a = __builtin_amdgcn_mfma_f32_16x16x32_bf16(ah[rt], bh, a, 0, 0, 0);
        a = __builtin_amdgcn_mfma_f32_16x16x32_bf16(ah[rt], bm, a, 0, 0, 0);
        a = __builtin_amdgcn_mfma_f32_16x16x32_bf16(am[rt], bh, a, 0, 0, 0);
        a = __builtin_amdgcn_mfma_f32_16x16x32_bf16(am[rt], bm, a, 0, 0, 0);
        a = __builtin_amdgcn_mfma_f32_16x16x32_bf16(ah[rt], bl, a, 0, 0, 0);
        a = __builtin_amdgcn_mfma_f32_16x16x32_bf16(al[rt], bh, a, 0, 0, 0);
        acc[rt][ct] = a;
      }
    }
  }
#pragma unroll
  for (int rt = 0; rt < 2; ++rt) {
#pragma unroll
    for (int ct = 0; ct < 4; ++ct) {
      const int gct = w * 4 + ct;
#pragma unroll
      for (int reg = 0; reg < 4; ++reg) {
        const int row = row0 + rt * 16 + lg4 * 4 + reg;
        size_t o;
        if (MODE == 0) {
          int bb = row / N1, nn = row - bb * N1;
          o = (((size_t)bb * H + gct) * N1 + nn) * D + lr;
        } else {
          int bb = row / P, pp = row - bb * P;
          o = (((size_t)bb * H + gct) * P + pp) * D + lr;
        }
        outp[o] = acc[rt][ct][reg];
      }
    }
  }
}

// ---------------------------------------------------------------------------
// Attention (round-9 structure + T13 defer-max): grid B*8 (head pairs).
// 256 threads = 4 waves; wave w: head = h0 + (w>>1); row = (w&1)*64 + lane.
// K+V in LDS, chunked over keys {52, 49} -> 13.3 KB total.
// ---------------------------------------------------------------------------
__device__ __forceinline__ float dot16f(
    const float4& a0, const float4& a1, const float4& a2, const float4& a3,
    const float4& b0, const float4& b1, const float4& b2, const float4& b3) {
  float s = a0.x * b0.x;
  s = fmaf(a0.y, b0.y, s); s = fmaf(a0.z, b0.z, s); s = fmaf(a0.w, b0.w, s);
  s = fmaf(a1.x, b1.x, s); s = fmaf(a1.y, b1.y, s); s = fmaf(a1.z, b1.z, s);
  s = fmaf(a1.w, b1.w, s);
  s = fmaf(a2.x, b2.x, s); s = fmaf(a2.y, b2.y, s); s = fmaf(a2.z, b2.z, s);
  s = fmaf(a2.w, b2.w, s);
  s = fmaf(a3.x, b3.x, s); s = fmaf(a3.y, b3.y, s); s = fmaf(a3.z, b3.z, s);
  s = fmaf(a3.w, b3.w, s);
  return s;
}

__global__ __launch_bounds__(256) void attn_kernel(
    const float* __restrict__ q, const float* __restrict__ k,
    const float* __restrict__ v, const float* __restrict__ ninf,
    float* __restrict__ x) {
  const int b = blockIdx.x >> 3;
  const int h0 = (blockIdx.x & 7) * 2;
  __shared__ float4 kl4[2 * 208];      // 2 heads x 52 keys x 16 floats
  __shared__ float4 vl4[2 * 208];
  const int tid = threadIdx.x;
  const int w = tid >> 6;
  const int lane = tid & 63;
  const int hh = w >> 1;
  const int h = h0 + hh;
  const int prow = (w & 1) * 64 + lane;
  const bool act = (prow < P);
  const int p = act ? prow : (P - 1);
  const float LOG2E = 1.4426950408889634f;
  const float c1 = 0.25f * LOG2E;
  const float* qb = q + (((size_t)b * H + h) * P + p) * D;
  float4 qa0 = *(const float4*)&qb[0];
  float4 qa1 = *(const float4*)&qb[4];
  float4 qa2 = *(const float4*)&qb[8];
  float4 qa3 = *(const float4*)&qb[12];
  qa0.x *= c1; qa0.y *= c1; qa0.z *= c1; qa0.w *= c1;
  qa1.x *= c1; qa1.y *= c1; qa1.z *= c1; qa1.w *= c1;
  qa2.x *= c1; qa2.y *= c1; qa2.z *= c1; qa2.w *= c1;
  qa3.x *= c1; qa3.y *= c1; qa3.z *= c1; qa3.w *= c1;
  const float* mrow = ninf + ((size_t)b * P + p) * N1;
  const float* kw = (const float*)(kl4 + hh * 208);
  const float* vw = (const float*)(vl4 + hh * 208);

  float m2 = -1e30f, l = 0.f;
  float o[16];
#pragma unroll
  for (int d = 0; d < 16; ++d) o[d] = 0.f;

#pragma unroll
  for (int ch = 0; ch < 2; ++ch) {
    const int c0 = ch ? 52 : 0;
    const int len = ch ? 49 : 52;
    const int nf4 = len * 4;           // float4 per head
    __syncthreads();                   // previous chunk fully consumed
    for (int i = tid; i < 2 * nf4; i += 256) {
      int hs = i / nf4, rem = i - hs * nf4;
      const float4* ks =
          (const float4*)(k + (((size_t)b * H + h0 + hs) * N1 + c0) * D);
      const float4* vs =
          (const float4*)(v + (((size_t)b * H + h0 + hs) * N1 + c0) * D);
      kl4[hs * 208 + rem] = ks[rem];
      vl4[hs * 208 + rem] = vs[rem];
    }
    __syncthreads();
    const int nit = len >> 2;          // 13 / 12
    float4 mk = *(const float4*)&mrow[c0];
    for (int it = 0; it < nit; ++it) {
      const int j = it * 4;
      const int nn = (it < nit - 1) ? (c0 + j + 4) : c0;
      float4 nx = *(const float4*)&mrow[nn];
      const float4* kr0 = (const float4*)&kw[(j + 0) * D];
      const float4* kr1 = (const float4*)&kw[(j + 1) * D];
      const float4* kr2 = (const float4*)&kw[(j + 2) * D];
      const float4* kr3 = (const float4*)&kw[(j + 3) * D];
      float4 k00 = kr0[0], k01 = kr0[1], k02 = kr0[2], k03 = kr0[3];
      float4 k10 = kr1[0], k11 = kr1[1], k12 = kr1[2], k13 = kr1[3];
      float4 k20 = kr2[0], k21 = kr2[1], k22 = kr2[2], k23 = kr2[3];
      float4 k30 = kr3[0], k31 = kr3[1], k32 = kr3[2], k33 = kr3[3];
      float s0 = fmaf(mk.x, LOG2E, dot16f(qa0, qa1, qa2, qa3, k00, k01, k02, k03));
      float s1 = fmaf(mk.y, LOG2E, dot16f(qa0, qa1, qa2, qa3, k10, k11, k12, k13));
      float s2 = fmaf(mk.z, LOG2E, dot16f(qa0, qa1, qa2, qa3, k20, k21, k22, k23));
      float s3 = fmaf(mk.w, LOG2E, dot16f(qa0, qa1, qa2, qa3, k30, k31, k32, k33));
      float gm = fmaxf(fmaxf(s0, s1), fmaxf(s2, s3));
      const float4* vr0 = (const float4*)&vw[(j + 0) * D];
      const float4* vr1 = (const float4*)&vw[(j + 1) * D];
      const float4* vr2 = (const float4*)&vw[(j + 2) * D];
      const float4* vr3 = (const float4*)&vw[(j + 3) * D];
      if (__any(gm > m2 + 8.f)) {
        // rescale path (max grew notably somewhere in the wave)
        float mn = fmaxf(gm, m2);
        float sc = exp2f(m2 - mn);
        float p0 = exp2f(s0 - mn), p1 = exp2f(s1 - mn);
        float p2 = exp2f(s2 - mn), p3 = exp2f(s3 - mn);
        l = fmaf(l, sc, (p0 + p1) + (p2 + p3));
#pragma unroll
        for (int dq = 0; dq < 4; ++dq) {
          float4 v0 = vr0[dq], v1 = vr1[dq], v2 = vr2[dq], v3 = vr3[dq];
          o[4 * dq + 0] = fmaf(o[4 * dq + 0], sc,
              fmaf(p0, v0.x, fmaf(p1, v1.x, fmaf(p2, v2.x, p3 * v3.x))));
          o[4 * dq + 1] = fmaf(o[4 * dq + 1], sc,
              fmaf(p0, v0.y, fmaf(p1, v1.y, fmaf(p2, v2.y, p3 * v3.y))));
          o[4 * dq + 2] = fmaf(o[4 * dq + 2], sc,
              fmaf(p0, v0.z, fmaf(p1, v1.z, fmaf(p2, v2.z, p3 * v3.z))));
          o[4 * dq + 3] = fmaf(o[4 * dq + 3], sc,
              fmaf(p0, v0.w, fmaf(p1, v1.w, fmaf(p2, v2.w, p3 * v3.w))));
        }
        m2 = mn;
      } else {
        // defer path: keep m2; p bounded by 2^8. No O/l rescale.
        float p0 = exp2f(s0 - m2), p1 = exp2f(s1 - m2);
        float p2 = exp2f(s2 - m2), p3 = exp2f(s3 - m2);
        l += (p0 + p1) + (p2 + p3);
#pragma unroll
        for (int dq = 0; dq < 4; ++dq) {
          float4 v0 = vr0[dq], v1 = vr1[dq], v2 = vr2[dq], v3 = vr3[dq];
          o[4 * dq + 0] = fmaf(p0, v0.x,
              fmaf(p1, v1.x, fmaf(p2, v2.x, fmaf(p3, v3.x, o[4 * dq + 0]))));
          o[4 * dq + 1] = fmaf(p0, v0.y,
              fmaf(p1, v1.y, fmaf(p2, v2.y, fmaf(p3, v3.y, o[4 * dq + 1]))));
          o[4 * dq + 2] = fmaf(p0, v0.z,
              fmaf(p1, v1.z, fmaf(p2, v2.z, fmaf(p3, v3.z, o[4 * dq + 2]))));
          o[4 * dq + 3] = fmaf(p0, v0.w,
              fmaf(p1, v1.w, fmaf(p2, v2.w, fmaf(p3, v3.w, o[4 * dq + 3]))));
        }
      }
      mk = nx;
    }
  }
  // tail key 100 = chunk-1 LDS slot 48
  {
    const float tm = mrow[100];
    const float4* kr = (const float4*)&kw[48 * D];
    float4 k0 = kr[0], k1 = kr[1], k2 = kr[2], k3 = kr[3];
    float s = fmaf(tm, LOG2E, dot16f(qa0, qa1, qa2, qa3, k0, k1, k2, k3));
    float mn = fmaxf(m2, s);
    float sc = exp2f(m2 - mn);
    float pp = exp2f(s - mn);
    l = fmaf(l, sc, pp);
    const float4* vr = (const float4*)&vw[48 * D];
#pragma unroll
    for (int dq = 0; dq < 4; ++dq) {
      float4 v0 = vr[dq];
      o[4 * dq + 0] = fmaf(o[4 * dq + 0], sc, pp * v0.x);
      o[4 * dq + 1] = fmaf(o[4 * dq + 1], sc, pp * v0.y);
      o[4 * dq + 2] = fmaf(o[4 * dq + 2], sc, pp * v0.z);
      o[4 * dq + 3] = fmaf(o[4 * dq + 3], sc, pp * v0.w);
    }
  }
  if (act) {
    const float inv = 1.f / l;
    float* xr = &x[((size_t)b * P + p) * HD + h * D];
#pragma unroll
    for (int dq = 0; dq < 4; ++dq) {
      float4 t;
      t.x = o[4 * dq + 0] * inv; t.y = o[4 * dq + 1] * inv;
      t.z = o[4 * dq + 2] * inv; t.w = o[4 * dq + 3] * inv;
      *(float4*)&xr[4 * dq] = t;
    }
  }
}

// ---------------------------------------------------------------------------
// Kernel 4: router logits (fp32, SAME accumulation order as before; loads
// vectorized via transposed+padded Wg) + top2 + gates; emits xsplit.
// ---------------------------------------------------------------------------
__global__ __launch_bounds__(256) void logits_top2_kernel(
    const float* __restrict__ x, const float* __restrict__ Wg,
    int* __restrict__ topi, float* __restrict__ topg,
    ushort_t* __restrict__ xsplit) {
  __shared__ float xl[32][260];
  __shared__ float wgt[8 * 260];       // transposed, stride 260 (bank-spread)
  __shared__ float lg[32][9];
  const int tid = threadIdx.x;
  const int t0 = blockIdx.x * 32;
  for (int r = 0; r < 32; ++r) {
    float val = x[(size_t)(t0 + r) * HD + tid];
    xl[r][tid] = val;
    unsigned short hi = f2bf(val);
    unsigned short lo = f2bf(val - bf2f(hi));
    xsplit[(size_t)(t0 + r) * 512 + tid] = hi;
    xsplit[(size_t)(t0 + r) * 512 + 256 + tid] = lo;
  }
  for (int i = tid; i < E * NE; i += 256) {
    // Wg layout [f][e] -> wgt[e][f]
    wgt[(i & 7) * 260 + (i >> 3)] = Wg[i];
  }
  __syncthreads();
  const int r = tid >> 3, e = tid & 7;
  float acc = 0.f;
  const float* xr = &xl[r][0];
  const float* wr = &wgt[e * 260];
  for (int f = 0; f < E; f += 4) {
    float4 xv = *(const float4*)&xr[f];
    float4 wv = *(const float4*)&wr[f];
    acc += xv.x * wv.x;
    acc += xv.y * wv.y;
    acc += xv.z * wv.z;
    acc += xv.w * wv.w;
  }
  lg[r][e] = acc;
  __syncthreads();
  if (tid < 32) {
    float v[8];
#pragma unroll
    for (int j = 0; j < 8; ++j) v[j] = lg[tid][j];
    int i1 = 0; float v1 = v[0];
#pragma unroll
    for (int j = 1; j < 8; ++j) if (v[j] > v1) { v1 = v[j]; i1 = j; }
    int i2 = -1; float v2 = -1e30f;
#pragma unroll
    for (int j = 0; j < 8; ++j)
      if (j != i1 && v[j] > v2) { v2 = v[j]; i2 = j; }
    float ex = __expf(v2 - v1);
    float g1 = 1.f / (1.f + ex);
    float g2 = ex / (1.f + ex);
    int t = t0 + tid;
    topi[t * 2 + 0] = i1; topi[t * 2 + 1] = i2;
    topg[t * 2 + 0] = g1; topg[t * 2 + 1] = g2;
  }
}

// ---------------------------------------------------------------------------
// Parallel list building: count -> scan -> scatter. Deterministic
// (token-ascending within expert, same as the old single-kernel version).
// ---------------------------------------------------------------------------
__global__ __launch_bounds__(CHKSZ) void moe_count_kernel(
    const int* __restrict__ topi, int* __restrict__ chunk_cnt) {
  __shared__ int cnt[NE];
  const int tid = threadIdx.x;
  if (tid < NE) cnt[tid] = 0;
  __syncthreads();
  const int t = blockIdx.x * CHKSZ + tid;
  atomicAdd(&cnt[topi[t * 2 + 0]], 1);
  atomicAdd(&cnt[topi[t * 2 + 1]], 1);
  __syncthreads();
  if (tid < NE) chunk_cnt[blockIdx.x * NE + tid] = cnt[tid];
}

__global__ __launch_bounds__(64) void moe_scan_kernel(
    const int* __restrict__ chunk_cnt, int* __restrict__ chunk_base,
    int* __restrict__ counts) {
  const int e = threadIdx.x;
  if (e < NE) {
    int run = 0;
    for (int c = 0; c < NCHK; ++c) {
      chunk_base[c * NE + e] = run;
      run += chunk_cnt[c * NE + e];
    }
    counts[e] = run;
  }
}

__global__ __launch_bounds__(CHKSZ) void moe_scatter_kernel(
    const int* __restrict__ topi, const float* __restrict__ topg,
    const int* __restrict__ chunk_base, int* __restrict__ list_tok,
    float* __restrict__ list_gate) {
  __shared__ int w0cnt[NE];
  const int tid = threadIdx.x;
  const int wv = tid >> 6, lane = tid & 63;
  const int t = blockIdx.x * CHKSZ + tid;
  const int ia = topi[t * 2 + 0], ib = topi[t * 2 + 1];
  const float ga = topg[t * 2 + 0], gb = topg[t * 2 + 1];
  const unsigned long long lmask = (lane == 0) ? 0ull : ((~0ull) >> (64 - lane));
  int prefA = 0, prefB = 0;
#pragma unroll
  for (int e = 0; e < NE; ++e) {
    unsigned long long mc = __ballot(ia == e) | __ballot(ib == e);
    if (wv == 0 && lane == 0) w0cnt[e] = __popcll(mc);
    int pref = __popcll(mc & lmask);
    if (ia == e) prefA = pref;
    if (ib == e) prefB = pref;
  }
  __syncthreads();
  const int baseA =
      chunk_base[blockIdx.x * NE + ia] + (wv ? w0cnt[ia] : 0) + prefA;
  const int baseB =
      chunk_base[blockIdx.x * NE + ib] + (wv ? w0cnt[ib] : 0) + prefB;
  list_tok[ia * NTOK + baseA] = (t << 1) | 0;
  list_gate[ia * NTOK + baseA] = ga;
  list_tok[ib * NTOK + baseB] = (t << 1) | 1;
  list_gate[ib * NTOK + baseB] = gb;
}

// ---------------------------------------------------------------------------
// Kernel 6: sparse expert GEMM via split-bf16 MFMA. 48-token tiles (3 rt).
// ---------------------------------------------------------------------------
__global__ __launch_bounds__(256) void expert_gemm_kernel(
    const ushort_t* __restrict__ xsplit, const uint4* __restrict__ Wp,
    const float* __restrict__ eb, const int* __restrict__ list_tok,
    const float* __restrict__ list_gate, const int* __restrict__ counts,
    float* __restrict__ p0, float* __restrict__ p1) {
  int e = 0, t0 = -1;
  {
    int rem = blockIdx.x;
    for (int i = 0; i < NE; ++i) {
      int nt = (counts[i] + 47) / 48;
      if (rem < nt) { e = i; t0 = rem * 48; break; }
      rem -= nt;
    }
  }
  if (t0 < 0) return;
  const int cnt = counts[e];
  const int nr = min(48, cnt - t0);
  __shared__ uint4 xls[48 * 65];       // 49.9 KB
  __shared__ int stok[48];
  __shared__ float sg[48];
  const int tid = threadIdx.x;
  if (tid < 48) {
    int src = e * NTOK + t0 + ((tid < nr) ? tid : 0);
    stok[tid] = list_tok[src];
    sg[tid] = (tid < nr) ? list_gate[e * NTOK + t0 + tid] : 0.f;
  }
  __syncthreads();
  for (int i = tid; i < 48 * 64; i += 256) {
    int r = i >> 6, ch = i & 63;
    const uint4* src = (const uint4*)(xsplit + (size_t)(stok[r] >> 1) * 512);
    xls[r * 65 + ch] = src[ch];
  }
  __syncthreads();
  const int w = tid >> 6;
  const int lane = tid & 63;
  const int lr = lane & 15;
  const int lg4 = lane >> 4;
  f32x4 acc[3][4];
#pragma unroll
  for (int rt = 0; rt < 3; ++rt)
#pragma unroll
    for (int ct = 0; ct < 4; ++ct) acc[rt][ct] = (f32x4){0.f, 0.f, 0.f, 0.f};

  for (int kt = 0; kt < 8; ++kt) {
    short8 afrag[3][2];
#pragma unroll
    for (int rt = 0; rt < 3; ++rt)
#pragma unroll
      for (int pl = 0; pl < 2; ++pl) {
        uint4 u = xls[(rt * 16 + lr) * 65 + pl * 32 + kt * 4 + lg4];
        afrag[rt][pl] = __builtin_bit_cast(short8, u);
      }
#pragma unroll
    for (int ct = 0; ct < 4; ++ct) {
      const int gct = w * 4 + ct;
      const size_t base = (size_t)(((e * 8 + kt) * 16 + gct) * 2) * 64 + lane;
      short8 bh = __builtin_bit_cast(short8, Wp[base]);
      short8 bl = __builtin_bit_cast(short8, Wp[base + 64]);
#pragma unroll
      for (int rt = 0; rt < 3; ++rt) {
        acc[rt][ct] = __builtin_amdgcn_mfma_f32_16x16x32_bf16(
            afrag[rt][0], bh, acc[rt][ct], 0, 0, 0);
        acc[rt][ct] = __builtin_amdgcn_mfma_f32_16x16x32_bf16(
            afrag[rt][0], bl, acc[rt][ct], 0, 0, 0);
        acc[rt][ct] = __builtin_amdgcn_mfma_f32_16x16x32_bf16(
            afrag[rt][1], bh, acc[rt][ct], 0, 0, 0);
      }
    }
  }
#pragma unroll
  for (int rt = 0; rt < 3; ++rt) {
#pragma unroll
    for (int ct = 0; ct < 4; ++ct) {
      const int col = (w * 4 + ct) * 16 + lr;
      const float bias = eb[e * E + col];
#pragma unroll
      for (int reg = 0; reg < 4; ++reg) {
        const int ridx = rt * 16 + lg4 * 4 + reg;
        if (ridx < nr) {
          const int tokw = stok[ridx];
          const float g = sg[ridx];
          float* dst = ((tokw & 1) ? p1 : p0) + (size_t)(tokw >> 1) * E + col;
          *dst = g * (acc[rt][ct][reg] + bias);
        }
      }
    }
  }
}

// ---------------------------------------------------------------------------
// Kernel 7: fused score2 + tanh-clip + softmax -> probs into d_out.
// ---------------------------------------------------------------------------
__global__ __launch_bounds__(256) void score2_fused_kernel(
    const float* __restrict__ p0, const float* __restrict__ p1,
    const float* __restrict__ enc, const float* __restrict__ ab,
    const float* __restrict__ ab1, const float* __restrict__ ninf,
    float* __restrict__ out) {
  const int b = blockIdx.x >> 1;
  const int half = blockIdx.x & 1;
  const int r0 = half * 50;
  __shared__ float4 mh4[50 * 64];      // 51.2 KB
  const int tid = threadIdx.x;
  for (int i = tid; i < 50 * 64; i += 256) {
    int r = i >> 6, c4 = i & 63;
    size_t idx = (size_t)(b * P + r0 + r) * 64 + c4;
    float4 a = ((const float4*)p0)[idx];
    float4 c = ((const float4*)p1)[idx];
    float4 s;
    s.x = a.x + c.x; s.y = a.y + c.y; s.z = a.z + c.z; s.w = a.w + c.w;
    mh4[i] = s;
  }
  __syncthreads();
  const int w = tid >> 6;
  const int lane = tid & 63;
  const int n0 = lane;
  const int n1v = lane + 64;
  const bool has1 = (n1v < N1);        // lane < 37
  const int n1 = has1 ? n1v : (N1 - 1);
  const float4* er0 = (const float4*)(enc + ((size_t)b * N1 + n0) * E);
  const float4* er1 = (const float4*)(enc + ((size_t)b * N1 + n1) * E);
  float acc0[13], acc1[13];
#pragma unroll
  for (int j = 0; j < 13; ++j) { acc0[j] = 0.f; acc1[j] = 0.f; }
  for (int kk = 0; kk < 64; ++kk) {
    float4 e0 = er0[kk];
    float4 e1 = er1[kk];
#pragma unroll
    for (int j = 0; j < 13; ++j) {
      const int r = w + j * 4;
      if (r < 50) {
        float4 mv = mh4[r * 64 + kk];
        acc0[j] = fmaf(mv.w, e0.w,
                  fmaf(mv.z, e0.z, fmaf(mv.y, e0.y, fmaf(mv.x, e0.x, acc0[j]))));
        acc1[j] = fmaf(mv.w, e1.w,
                  fmaf(mv.z, e1.z, fmaf(mv.y, e1.y, fmaf(mv.x, e1.x, acc1[j]))));
      }
    }
  }
#pragma unroll
  for (int j = 0; j < 13; ++j) {
    const int r = w + j * 4;
    if (r < 50) {
      const int prow = b * P + r0 + r;
      const float* arow = ab + (size_t)prow * N1;
      const float* a1row = ab1 + (size_t)prow * N1;
      const float* nrow = ninf + (size_t)prow * N1;
      float s0 = acc0[j] + arow[n0] + a1row[n0];
      float e20 = __expf(s0 * 0.125f);
      float v0 = 10.f - 20.f / (e20 + 1.f) + nrow[n0];
      float v1 = -1e30f;
      if (has1) {
        float s1 = acc1[j] + arow[n1v] + a1row[n1v];
        float e21 = __expf(s1 * 0.125f);
        v1 = 10.f - 20.f / (e21 + 1.f) + nrow[n1v];
      }
      float mx = fmaxf(v0, v1);
#pragma unroll
      for (int off = 32; off > 0; off >>= 1)
        mx = fmaxf(mx, __shfl_xor(mx, off, 64));
      float q0 = __expf(v0 - mx);
      float q1 = has1 ? __expf(v1 - mx) : 0.f;
      float sum = q0 + q1;
#pragma unroll
      for (int off = 32; off > 0; off >>= 1)
        sum += __shfl_xor(sum, off, 64);
      float inv = 1.f / sum;
      float* orow = out + (size_t)prow * N1;
      orow[n0] = q0 * inv;
      if (has1) orow[n1v] = q1 * inv;
    }
  }
}

// ---------------------------------------------------------------------------
extern "C" void kernel_launch(void* const* d_in, const int* in_sizes, int n_in,
                              void* d_out, int out_size, void* d_ws,
                              size_t ws_size, hipStream_t stream) {
  const float* eln  = (const float*)d_in[0];
  const float* attr = (const float*)d_in[1];
  const float* enc  = (const float*)d_in[2];
  const float* ninf = (const float*)d_in[3];
  const float* ab   = (const float*)d_in[4];
  const float* ab1  = (const float*)d_in[5];
  const float* Wq   = (const float*)d_in[6];
  const float* Wk   = (const float*)d_in[7];
  const float* Wv   = (const float*)d_in[8];
  const float* Wg   = (const float*)d_in[9];
  const float* eW   = (const float*)d_in[10];
  const float* eb   = (const float*)d_in[11];
  float* out = (float*)d_out;

  char* ws = (char*)d_ws;
  size_t off = 0;
  auto carve = [&](size_t bytes) {
    char* p = ws + off;
    off += (bytes + 255) & ~size_t(255);
    return p;
  };
  float* kbuf = (float*)carve(sizeof(float) * NKV * HD);
  float* vbuf = (float*)carve(sizeof(float) * NKV * HD);
  float* qbuf = (float*)carve(sizeof(float) * NTOK * HD);
  float* xbuf = (float*)carve(sizeof(float) * NTOK * HD);
  int*   topi = (int*)carve(sizeof(int) * NTOK * 2);
  float* topg = (float*)carve(sizeof(float) * NTOK * 2);
  int*   counts = (int*)carve(sizeof(int) * 16);
  int*   chunk_cnt = (int*)carve(sizeof(int) * NCHK * NE);
  int*   chunk_base = (int*)carve(sizeof(int) * NCHK * NE);
  int*   list_tok = (int*)carve(sizeof(int) * NE * NTOK);
  float* list_gate = (float*)carve(sizeof(float) * NE * NTOK);
  uint4* Wp  = (uint4*)carve(sizeof(ushort_t) * NE * HD * E * 2);  // 2 MB
  uint4* Wk3 = (uint4*)carve((size_t)8 * 16 * 3 * 64 * 16);        // 393 KB
  uint4* Wv3 = (uint4*)carve((size_t)8 * 16 * 3 * 64 * 16);
  uint4* Wq3 = (uint4*)carve((size_t)9 * 16 * 3 * 64 * 16);        // 442 KB
  float* pp0 = kbuf;
  float* pp1 = vbuf;
  ushort_t* xsplit = (ushort_t*)qbuf;

  prep_kernel<<<356, 256, 0, stream>>>(eW, Wp, Wk, Wk3, Wv, Wv3, Wq, Wq3);
  kvproj3_kernel<<<NKV / 32, 256, 0, stream>>>(enc, Wk3, Wv3, kbuf, vbuf);
  proj3_kernel<9, 1><<<NTOK / 32, 256, 0, stream>>>(eln, attr, Wq3, qbuf);
  attn_kernel<<<B * 8, 256, 0, stream>>>(qbuf, kbuf, vbuf, ninf, xbuf);
  logits_top2_kernel<<<NTOK / 32, 256, 0, stream>>>(xbuf, Wg, topi, topg,
                                                    xsplit);
  moe_count_kernel<<<NCHK, CHKSZ, 0, stream>>>(topi, chunk_cnt);
  moe_scan_kernel<<<1, 64, 0, stream>>>(chunk_cnt, chunk_base, counts);
  moe_scatter_kernel<<<NCHK, CHKSZ, 0, stream>>>(topi, topg, chunk_base,
                                                 list_tok, list_gate);
  // max tiles = ceil(2*NTOK/48) + NE = 1067 + 8
  expert_gemm_kernel<<<1075, 256, 0, stream>>>(xsplit, Wp, eb, list_tok,
                                               list_gate, counts, pp0, pp1);
  score2_fused_kernel<<<512, 256, 0, stream>>>(pp0, pp1, enc, ab, ab1, ninf,
                                               out);
}

// Round 13
// 297.601 us; speedup vs baseline: 1.1032x; 1.0021x over previous
//
#include <hip/hip_runtime.h>
#include <hip/hip_bf16.h>

// Problem constants
#define B   256
#define P   100
#define N1  101
#define E   256
#define HD  256          // H*D
#define H   16
#define D   16
#define NE  8
#define NTOK (B*P)       // 25600
#define NKV  (B*N1)      // 25856
#define NCHK 200         // token chunks for list building
#define CHKSZ 128

typedef __attribute__((ext_vector_type(8))) short short8;
typedef __attribute__((ext_vector_type(4))) float f32x4;
typedef unsigned short ushort_t;

__device__ __forceinline__ unsigned short f2bf(float f) {
  unsigned int u = __float_as_uint(f);
  unsigned int r = (u + 0x7fffu + ((u >> 16) & 1u)) >> 16;
  return (unsigned short)r;
}
__device__ __forceinline__ float bf2f(unsigned short b) {
  return __uint_as_float(((unsigned int)b) << 16);
}
// HW packed f32->bf16 (1 instr for 2 elements); D.lo = bf16(a), D.hi = bf16(b)
__device__ __forceinline__ unsigned int cvtpk(float a, float b) {
  unsigned int r;
  asm("v_cvt_pk_bf16_f32 %0, %1, %2" : "=v"(r) : "v"(a), "v"(b));
  return r;
}
__device__ __forceinline__ float lo2f(unsigned int u) {
  return __uint_as_float(u << 16);
}
__device__ __forceinline__ float hi2f(unsigned int u) {
  return __uint_as_float(u & 0xffff0000u);
}

// ---------------------------------------------------------------------------
// Shared A-split helper: fp32 x8 -> 3-plane packed uint4s (cvt_pk fast path).
// ---------------------------------------------------------------------------
__device__ __forceinline__ void split3_pack(const float* v, uint4& uh,
                                            uint4& um, uint4& ul) {
  unsigned int hw[4], mw[4], lw[4];
#pragma unroll
  for (int jj = 0; jj < 4; ++jj) {
    float va = v[2 * jj], vb = v[2 * jj + 1];
    unsigned int h = cvtpk(va, vb);
    float ra = va - lo2f(h), rb = vb - hi2f(h);
    unsigned int m = cvtpk(ra, rb);
    float sa = ra - lo2f(m), sb = rb - hi2f(m);
    unsigned int l = cvtpk(sa, sb);
    hw[jj] = h; mw[jj] = m; lw[jj] = l;
  }
  uh.x = hw[0]; uh.y = hw[1]; uh.z = hw[2]; uh.w = hw[3];
  um.x = mw[0]; um.y = mw[1]; um.z = mw[2]; um.w = mw[3];
  ul.x = lw[0]; ul.y = lw[1]; ul.z = lw[2]; ul.w = lw[3];
}

// ---------------------------------------------------------------------------
// Device body: 3-plane weight prepack (K x 256 -> fragment order).
// ---------------------------------------------------------------------------
__device__ __forceinline__ void wsplit3_body(const float* __restrict__ W,
                                             uint4* __restrict__ Wp, int Kreal,
                                             int gid) {
  const int lane = gid & 63;
  const int rest = gid >> 6;          // kt*16 + gct
  const int gct = rest & 15;
  const int kt = rest >> 4;
  const int k0 = kt * 32 + (lane >> 4) * 8;
  const int c = gct * 16 + (lane & 15);
  float v[8];
#pragma unroll
  for (int j = 0; j < 8; ++j) {
    int kk = k0 + j;
    v[j] = (kk < Kreal) ? W[(size_t)kk * 256 + c] : 0.f;
  }
  uint4 uh, um, ul;
  split3_pack(v, uh, um, ul);
  Wp[(size_t)(rest * 3 + 0) * 64 + lane] = uh;
  Wp[(size_t)(rest * 3 + 1) * 64 + lane] = um;
  Wp[(size_t)(rest * 3 + 2) * 64 + lane] = ul;
}

// ---------------------------------------------------------------------------
// Merged prepack kernel: blocks [0,256) expert W 2-plane; [256,288) Wk3;
// [288,320) Wv3; [320,356) Wq3.
// ---------------------------------------------------------------------------
__global__ __launch_bounds__(256) void prep_kernel(
    const float* __restrict__ eW, uint4* __restrict__ Wp,
    const float* __restrict__ Wk, uint4* __restrict__ Wk3,
    const float* __restrict__ Wv, uint4* __restrict__ Wv3,
    const float* __restrict__ Wq, uint4* __restrict__ Wq3) {
  const int bx = blockIdx.x;
  const int tid = threadIdx.x;
  if (bx < 256) {
    const int gid = bx * 256 + tid;
    const int lane = gid & 63;
    const int rest = gid >> 6;
    const int gct = rest & 15;
    const int kt = (rest >> 4) & 7;
    const int e = rest >> 7;
    const int kbase = kt * 32 + (lane >> 4) * 8;
    const int c = gct * 16 + (lane & 15);
    unsigned int hi[4], lo[4];
#pragma unroll
    for (int jj = 0; jj < 4; ++jj) {
      float v0 = eW[((size_t)e * HD + (kbase + 2 * jj)) * E + c];
      float v1 = eW[((size_t)e * HD + (kbase + 2 * jj + 1)) * E + c];
      unsigned int h = cvtpk(v0, v1);
      float r0 = v0 - lo2f(h), r1 = v1 - hi2f(h);
      unsigned int l = cvtpk(r0, r1);
      hi[jj] = h; lo[jj] = l;
    }
    uint4 uh, ul;
    uh.x = hi[0]; uh.y = hi[1]; uh.z = hi[2]; uh.w = hi[3];
    ul.x = lo[0]; ul.y = lo[1]; ul.z = lo[2]; ul.w = lo[3];
    Wp[(size_t)(rest * 2 + 0) * 64 + lane] = uh;
    Wp[(size_t)(rest * 2 + 1) * 64 + lane] = ul;
  } else if (bx < 288) {
    wsplit3_body(Wk, Wk3, 256, (bx - 256) * 256 + tid);
  } else if (bx < 320) {
    wsplit3_body(Wv, Wv3, 256, (bx - 288) * 256 + tid);
  } else {
    wsplit3_body(Wq, Wq3, 260, (bx - 320) * 256 + tid);
  }
}

// ---------------------------------------------------------------------------
// Fused K+V projection, 3-plane MFMA. Tile 32 rows x 256 cols, 4 waves.
// ---------------------------------------------------------------------------
__global__ __launch_bounds__(256) void kvproj3_kernel(
    const float* __restrict__ enc, const uint4* __restrict__ Wk3,
    const uint4* __restrict__ Wv3, float* __restrict__ kout,
    float* __restrict__ vout) {
  const int KT = 8;
  const int NKG = KT * 4;              // 32 k-groups of 8
  const int RSTRIDE = KT * 12 + 1;     // 97
  __shared__ uint4 als[32 * 97];       // 49.7 KB
  const int tid = threadIdx.x;
  const int row0 = blockIdx.x * 32;
  for (int i = tid; i < 32 * NKG; i += 256) {
    const int row = i >> 5;
    const int kg = i & 31;
    float v[8];
    const float4* s = (const float4*)(enc + (size_t)(row0 + row) * 256 + kg * 8);
    float4 x0 = s[0], x1 = s[1];
    v[0] = x0.x; v[1] = x0.y; v[2] = x0.z; v[3] = x0.w;
    v[4] = x1.x; v[5] = x1.y; v[6] = x1.z; v[7] = x1.w;
    uint4 uh, um, ul;
    split3_pack(v, uh, um, ul);
    const int slot = row * RSTRIDE + kg;
    als[slot] = uh;
    als[slot + NKG] = um;
    als[slot + 2 * NKG] = ul;
  }
  __syncthreads();
  const int w = tid >> 6;
  const int lane = tid & 63;
  const int lr = lane & 15;
  const int lg4 = lane >> 4;
  f32x4 acck[2][4], accv[2][4];
#pragma unroll
  for (int rt = 0; rt < 2; ++rt)
#pragma unroll
    for (int ct = 0; ct < 4; ++ct) {
      acck[rt][ct] = (f32x4){0.f, 0.f, 0.f, 0.f};
      accv[rt][ct] = (f32x4){0.f, 0.f, 0.f, 0.f};
    }
  for (int kt = 0; kt < KT; ++kt) {
    short8 ah[2], am[2], al[2];
#pragma unroll
    for (int rt = 0; rt < 2; ++rt) {
      const int base = (rt * 16 + lr) * RSTRIDE + kt * 4 + lg4;
      ah[rt] = __builtin_bit_cast(short8, als[base]);
      am[rt] = __builtin_bit_cast(short8, als[base + NKG]);
      al[rt] = __builtin_bit_cast(short8, als[base + 2 * NKG]);
    }
#pragma unroll
    for (int ct = 0; ct < 4; ++ct) {
      const int gct = w * 4 + ct;
      const size_t base = (size_t)((kt * 16 + gct) * 3) * 64 + lane;
      {
        short8 bh = __builtin_bit_cast(short8, Wk3[base]);
        short8 bm = __builtin_bit_cast(short8, Wk3[base + 64]);
        short8 bl = __builtin_bit_cast(short8, Wk3[base + 128]);
#pragma unroll
        for (int rt = 0; rt < 2; ++rt) {
          f32x4 a = acck[rt][ct];
          a = __builtin_amdgcn_mfma_f32_16x16x32_bf16(ah[rt], bh, a, 0, 0, 0);
          a = __builtin_amdgcn_mfma_f32_16x16x32_bf16(ah[rt], bm, a, 0, 0, 0);
          a = __builtin_amdgcn_mfma_f32_16x16x32_bf16(am[rt], bh, a, 0, 0, 0);
          a = __builtin_amdgcn_mfma_f32_16x16x32_bf16(am[rt], bm, a, 0, 0, 0);
          a = __builtin_amdgcn_mfma_f32_16x16x32_bf16(ah[rt], bl, a, 0, 0, 0);
          a = __builtin_amdgcn_mfma_f32_16x16x32_bf16(al[rt], bh, a, 0, 0, 0);
          acck[rt][ct] = a;
        }
      }
      {
        short8 bh = __builtin_bit_cast(short8, Wv3[base]);
        short8 bm = __builtin_bit_cast(short8, Wv3[base + 64]);
        short8 bl = __builtin_bit_cast(short8, Wv3[base + 128]);
#pragma unroll
        for (int rt = 0; rt < 2; ++rt) {
          f32x4 a = accv[rt][ct];
          a = __builtin_amdgcn_mfma_f32_16x16x32_bf16(ah[rt], bh, a, 0, 0, 0);
          a = __builtin_amdgcn_mfma_f32_16x16x32_bf16(ah[rt], bm, a, 0, 0, 0);
          a = __builtin_amdgcn_mfma_f32_16x16x32_bf16(am[rt], bh, a, 0, 0, 0);
          a = __builtin_amdgcn_mfma_f32_16x16x32_bf16(am[rt], bm, a, 0, 0, 0);
          a = __builtin_amdgcn_mfma_f32_16x16x32_bf16(ah[rt], bl, a, 0, 0, 0);
          a = __builtin_amdgcn_mfma_f32_16x16x32_bf16(al[rt], bh, a, 0, 0, 0);
          accv[rt][ct] = a;
        }
      }
    }
  }
#pragma unroll
  for (int rt = 0; rt < 2; ++rt) {
#pragma unroll
    for (int ct = 0; ct < 4; ++ct) {
      const int gct = w * 4 + ct;
#pragma unroll
      for (int reg = 0; reg < 4; ++reg) {
        const int row = row0 + rt * 16 + lg4 * 4 + reg;
        int bb = row / N1, nn = row - bb * N1;
        size_t o = (((size_t)bb * H + gct) * N1 + nn) * D + lr;
        kout[o] = acck[rt][ct][reg];
        vout[o] = accv[rt][ct][reg];
      }
    }
  }
}

// ---------------------------------------------------------------------------
// proj3 (Q only): MODE 1, KT=9.
// ---------------------------------------------------------------------------
template <int KT, int MODE>
__global__ __launch_bounds__(256) void proj3_kernel(
    const float* __restrict__ src, const float* __restrict__ attr,
    const uint4* __restrict__ Wp3, float* __restrict__ outp) {
  const int RSTRIDE = KT * 12 + 1;
  __shared__ uint4 als[32 * (KT * 12 + 1)];
  const int tid = threadIdx.x;
  const int row0 = blockIdx.x * 32;
  const int NKG = KT * 4;
  for (int i = tid; i < 32 * NKG; i += 256) {
    const int row = i / NKG;
    const int kg = i - row * NKG;
    float v[8];
    const int kbase = kg * 8;
    if (MODE == 0 || kbase < 256) {
      const float4* s = (const float4*)(src + (size_t)(row0 + row) * 256 + kbase);
      float4 x0 = s[0], x1 = s[1];
      v[0] = x0.x; v[1] = x0.y; v[2] = x0.z; v[3] = x0.w;
      v[4] = x1.x; v[5] = x1.y; v[6] = x1.z; v[7] = x1.w;
    } else {
#pragma unroll
      for (int j = 0; j < 8; ++j) {
        int k = kbase + j;
        v[j] = (k >= 256 && k < 260) ? attr[(size_t)(row0 + row) * 4 + (k - 256)]
                                     : 0.f;
      }
    }
    uint4 uh, um, ul;
    split3_pack(v, uh, um, ul);
    const int slot = row * RSTRIDE + kg;
    als[slot] = uh;
    als[slot + NKG] = um;
    als[slot + 2 * NKG] = ul;
  }
  __syncthreads();
  const int w = tid >> 6;
  const int lane = tid & 63;
  const int lr = lane & 15;
  const int lg4 = lane >> 4;
  f32x4 acc[2][4];
#pragma unroll
  for (int rt = 0; rt < 2; ++rt)
#pragma unroll
    for (int ct = 0; ct < 4; ++ct) acc[rt][ct] = (f32x4){0.f, 0.f, 0.f, 0.f};
  for (int kt = 0; kt < KT; ++kt) {
    short8 ah[2], am[2], al[2];
#pragma unroll
    for (int rt = 0; rt < 2; ++rt) {
      const int base = (rt * 16 + lr) * RSTRIDE + kt * 4 + lg4;
      ah[rt] = __builtin_bit_cast(short8, als[base]);
      am[rt] = __builtin_bit_cast(short8, als[base + NKG]);
      al[rt] = __builtin_bit_cast(short8, als[base + 2 * NKG]);
    }
#pragma unroll
    for (int ct = 0; ct < 4; ++ct) {
      const int gct = w * 4 + ct;
      const size_t base = (size_t)((kt * 16 + gct) * 3) * 64 + lane;
      short8 bh = __builtin_bit_cast(short8, Wp3[base]);
      short8 bm = __builtin_bit_cast(short8, Wp3[base + 64]);
      short8 bl = __builtin_bit_cast(short8, Wp3[base + 128]);
#pragma unroll
      for (int rt = 0; rt < 2; ++rt) {
        f32x4 a = acc[rt][ct];
        a = __builtin_amdgcn_mfma_f32_16x16x32_bf16(ah[rt], bh, a, 0, 0, 0);
        a = __builtin_amdgcn_mfma_f32_16x16x32_bf16(ah[rt], bm, a, 0, 0, 0);
        a = __builtin_amdgcn_mfma_f32_16x16x32_bf16(am[rt], bh, a, 0, 0, 0);
        a = __builtin_amdgcn_mfma_f32_16x16x32_bf16(am[rt], bm, a, 0, 0, 0);
        a = __builtin_amdgcn_mfma_f32_16x16x32_bf16(ah[rt], bl, a, 0, 0, 0);
        a = __builtin_amdgcn_mfma_f32_16x16x32_bf16(al[rt], bh, a, 0, 0, 0);
        acc[rt][ct] = a;
      }
    }
  }
#pragma unroll
  for (int rt = 0; rt < 2; ++rt) {
#pragma unroll
    for (int ct = 0; ct < 4; ++ct) {
      const int gct = w * 4 + ct;
#pragma unroll
      for (int reg = 0; reg < 4; ++reg) {
        const int row = row0 + rt * 16 + lg4 * 4 + reg;
        size_t o;
        if (MODE == 0) {
          int bb = row / N1, nn = row - bb * N1;
          o = (((size_t)bb * H + gct) * N1 + nn) * D + lr;
        } else {
          int bb = row / P, pp = row - bb * P;
          o = (((size_t)bb * H + gct) * P + pp) * D + lr;
        }
        outp[o] = acc[rt][ct][reg];
      }
    }
  }
}

// ---------------------------------------------------------------------------
// Attention v5: grid B*4; block 256 = 4 waves = 4 heads; 2 q-rows per lane
// (rows lane, lane+64) so each K/V LDS read feeds 2 dot/PV rows.
// K+V in LDS, chunked over keys {52, 49} -> 26.6 KB.
// exp2-domain online softmax; masks prefetched. No defer-max.
// ---------------------------------------------------------------------------
__device__ __forceinline__ float dot16f(
    const float4& a0, const float4& a1, const float4& a2, const float4& a3,
    const float4& b0, const float4& b1, const float4& b2, const float4& b3) {
  float s = a0.x * b0.x;
  s = fmaf(a0.y, b0.y, s); s = fmaf(a0.z, b0.z, s); s = fmaf(a0.w, b0.w, s);
  s = fmaf(a1.x, b1.x, s); s = fmaf(a1.y, b1.y, s); s = fmaf(a1.z, b1.z, s);
  s = fmaf(a1.w, b1.w, s);
  s = fmaf(a2.x, b2.x, s); s = fmaf(a2.y, b2.y, s); s = fmaf(a2.z, b2.z, s);
  s = fmaf(a2.w, b2.w, s);
  s = fmaf(a3.x, b3.x, s); s = fmaf(a3.y, b3.y, s); s = fmaf(a3.z, b3.z, s);
  s = fmaf(a3.w, b3.w, s);
  return s;
}

__global__ __launch_bounds__(256) void attn_kernel(
    const float* __restrict__ q, const float* __restrict__ k,
    const float* __restrict__ v, const float* __restrict__ ninf,
    float* __restrict__ x) {
  const int b = blockIdx.x >> 2;
  const int h0 = (blockIdx.x & 3) * 4;
  __shared__ float4 kl4[4 * 208];      // 4 heads x 52 keys x 4 float4
  __shared__ float4 vl4[4 * 208];      // total 26.6 KB
  const int tid = threadIdx.x;
  const int w = tid >> 6;
  const int lane = tid & 63;
  const int h = h0 + w;
  const int p0 = lane;                 // < 100 always
  const bool r1 = (lane + 64 < P);
  const int p1 = r1 ? (lane + 64) : (P - 1);
  const float LOG2E = 1.4426950408889634f;
  const float c1 = 0.25f * LOG2E;
  const float* qbase = q + (((size_t)b * H + h) * P) * D;
  float4 qa0 = *(const float4*)&qbase[p0 * D + 0];
  float4 qa1 = *(const float4*)&qbase[p0 * D + 4];
  float4 qa2 = *(const float4*)&qbase[p0 * D + 8];
  float4 qa3 = *(const float4*)&qbase[p0 * D + 12];
  float4 qb0 = *(const float4*)&qbase[p1 * D + 0];
  float4 qb1 = *(const float4*)&qbase[p1 * D + 4];
  float4 qb2 = *(const float4*)&qbase[p1 * D + 8];
  float4 qb3 = *(const float4*)&qbase[p1 * D + 12];
  qa0.x *= c1; qa0.y *= c1; qa0.z *= c1; qa0.w *= c1;
  qa1.x *= c1; qa1.y *= c1; qa1.z *= c1; qa1.w *= c1;
  qa2.x *= c1; qa2.y *= c1; qa2.z *= c1; qa2.w *= c1;
  qa3.x *= c1; qa3.y *= c1; qa3.z *= c1; qa3.w *= c1;
  qb0.x *= c1; qb0.y *= c1; qb0.z *= c1; qb0.w *= c1;
  qb1.x *= c1; qb1.y *= c1; qb1.z *= c1; qb1.w *= c1;
  qb2.x *= c1; qb2.y *= c1; qb2.z *= c1; qb2.w *= c1;
  qb3.x *= c1; qb3.y *= c1; qb3.z *= c1; qb3.w *= c1;
  const float* m0 = ninf + ((size_t)b * P + p0) * N1;
  const float* m1 = ninf + ((size_t)b * P + p1) * N1;
  const float* kw = (const float*)(kl4 + w * 208);
  const float* vw = (const float*)(vl4 + w * 208);

  float mA = -1e30f, mB = -1e30f, lA = 0.f, lB = 0.f;
  float oA[16], oB[16];
#pragma unroll
  for (int d = 0; d < 16; ++d) { oA[d] = 0.f; oB[d] = 0.f; }

#pragma unroll
  for (int ch = 0; ch < 2; ++ch) {
    const int c0 = ch ? 52 : 0;
    const int len = ch ? 49 : 52;
    const int nf4 = len * 4;           // float4 per head
    __syncthreads();                   // previous chunk fully consumed
    for (int i = tid; i < 4 * nf4; i += 256) {
      int hs = i / nf4, rem = i - hs * nf4;
      const float4* ks =
          (const float4*)(k + (((size_t)b * H + h0 + hs) * N1 + c0) * D);
      const float4* vs =
          (const float4*)(v + (((size_t)b * H + h0 + hs) * N1 + c0) * D);
      kl4[hs * 208 + rem] = ks[rem];
      vl4[hs * 208 + rem] = vs[rem];
    }
    __syncthreads();
    const int nit = len >> 2;          // 13 / 12
    float4 mk0 = *(const float4*)&m0[c0];
    float4 mk1 = *(const float4*)&m1[c0];
    for (int it = 0; it < nit; ++it) {
      const int j = it * 4;
      const int nn = (it < nit - 1) ? (c0 + j + 4) : c0;
      float4 nx0 = *(const float4*)&m0[nn];
      float4 nx1 = *(const float4*)&m1[nn];
      const float4* kr0 = (const float4*)&kw[(j + 0) * D];
      const float4* kr1 = (const float4*)&kw[(j + 1) * D];
      const float4* kr2 = (const float4*)&kw[(j + 2) * D];
      const float4* kr3 = (const float4*)&kw[(j + 3) * D];
      float4 k00 = kr0[0], k01 = kr0[1], k02 = kr0[2], k03 = kr0[3];
      float4 k10 = kr1[0], k11 = kr1[1], k12 = kr1[2], k13 = kr1[3];
      float4 k20 = kr2[0], k21 = kr2[1], k22 = kr2[2], k23 = kr2[3];
      float4 k30 = kr3[0], k31 = kr3[1], k32 = kr3[2], k33 = kr3[3];
      float sA0 = fmaf(mk0.x, LOG2E, dot16f(qa0, qa1, qa2, qa3, k00, k01, k02, k03));
      float sA1 = fmaf(mk0.y, LOG2E, dot16f(qa0, qa1, qa2, qa3, k10, k11, k12, k13));
      float sA2 = fmaf(mk0.z, LOG2E, dot16f(qa0, qa1, qa2, qa3, k20, k21, k22, k23));
      float sA3 = fmaf(mk0.w, LOG2E, dot16f(qa0, qa1, qa2, qa3, k30, k31, k32, k33));
      float sB0 = fmaf(mk1.x, LOG2E, dot16f(qb0, qb1, qb2, qb3, k00, k01, k02, k03));
      float sB1 = fmaf(mk1.y, LOG2E, dot16f(qb0, qb1, qb2, qb3, k10, k11, k12, k13));
      float sB2 = fmaf(mk1.z, LOG2E, dot16f(qb0, qb1, qb2, qb3, k20, k21, k22, k23));
      float sB3 = fmaf(mk1.w, LOG2E, dot16f(qb0, qb1, qb2, qb3, k30, k31, k32, k33));
      float mnA = fmaxf(fmaxf(fmaxf(sA0, sA1), fmaxf(sA2, sA3)), mA);
      float mnB = fmaxf(fmaxf(fmaxf(sB0, sB1), fmaxf(sB2, sB3)), mB);
      float scA = exp2f(mA - mnA);
      float scB = exp2f(mB - mnB);
      float pA0 = exp2f(sA0 - mnA), pA1 = exp2f(sA1 - mnA);
      float pA2 = exp2f(sA2 - mnA), pA3 = exp2f(sA3 - mnA);
      float pB0 = exp2f(sB0 - mnB), pB1 = exp2f(sB1 - mnB);
      float pB2 = exp2f(sB2 - mnB), pB3 = exp2f(sB3 - mnB);
      lA = fmaf(lA, scA, (pA0 + pA1) + (pA2 + pA3));
      lB = fmaf(lB, scB, (pB0 + pB1) + (pB2 + pB3));
      const float4* vr0 = (const float4*)&vw[(j + 0) * D];
      const float4* vr1 = (const float4*)&vw[(j + 1) * D];
      const float4* vr2 = (const float4*)&vw[(j + 2) * D];
      const float4* vr3 = (const float4*)&vw[(j + 3) * D];
#pragma unroll
      for (int dq = 0; dq < 4; ++dq) {
        float4 v0 = vr0[dq], v1 = vr1[dq], v2 = vr2[dq], v3 = vr3[dq];
        oA[4 * dq + 0] = fmaf(oA[4 * dq + 0], scA,
            fmaf(pA0, v0.x, fmaf(pA1, v1.x, fmaf(pA2, v2.x, pA3 * v3.x))));
        oA[4 * dq + 1] = fmaf(oA[4 * dq + 1], scA,
            fmaf(pA0, v0.y, fmaf(pA1, v1.y, fmaf(pA2, v2.y, pA3 * v3.y))));
        oA[4 * dq + 2] = fmaf(oA[4 * dq + 2], scA,
            fmaf(pA0, v0.z, fmaf(pA1, v1.z, fmaf(pA2, v2.z, pA3 * v3.z))));
        oA[4 * dq + 3] = fmaf(oA[4 * dq + 3], scA,
            fmaf(pA0, v0.w, fmaf(pA1, v1.w, fmaf(pA2, v2.w, pA3 * v3.w))));
        oB[4 * dq + 0] = fmaf(oB[4 * dq + 0], scB,
            fmaf(pB0, v0.x, fmaf(pB1, v1.x, fmaf(pB2, v2.x, pB3 * v3.x))));
        oB[4 * dq + 1] = fmaf(oB[4 * dq + 1], scB,
            fmaf(pB0, v0.y, fmaf(pB1, v1.y, fmaf(pB2, v2.y, pB3 * v3.y))));
        oB[4 * dq + 2] = fmaf(oB[4 * dq + 2], scB,
            fmaf(pB0, v0.z, fmaf(pB1, v1.z, fmaf(pB2, v2.z, pB3 * v3.z))));
        oB[4 * dq + 3] = fmaf(oB[4 * dq + 3], scB,
            fmaf(pB0, v0.w, fmaf(pB1, v1.w, fmaf(pB2, v2.w, pB3 * v3.w))));
      }
      mA = mnA; mB = mnB;
      mk0 = nx0; mk1 = nx1;
    }
  }
  // tail key 100 = chunk-1 LDS slot 48
  {
    const float tm0 = m0[100], tm1 = m1[100];
    const float4* kr = (const float4*)&kw[48 * D];
    float4 k0 = kr[0], k1 = kr[1], k2 = kr[2], k3 = kr[3];
    float sA = fmaf(tm0, LOG2E, dot16f(qa0, qa1, qa2, qa3, k0, k1, k2, k3));
    float sB = fmaf(tm1, LOG2E, dot16f(qb0, qb1, qb2, qb3, k0, k1, k2, k3));
    float mnA = fmaxf(mA, sA), mnB = fmaxf(mB, sB);
    float scA = exp2f(mA - mnA), scB = exp2f(mB - mnB);
    float pA = exp2f(sA - mnA), pB = exp2f(sB - mnB);
    lA = fmaf(lA, scA, pA);
    lB = fmaf(lB, scB, pB);
    const float4* vr = (const float4*)&vw[48 * D];
#pragma unroll
    for (int dq = 0; dq < 4; ++dq) {
      float4 v0 = vr[dq];
      oA[4 * dq + 0] = fmaf(oA[4 * dq + 0], scA, pA * v0.x);
      oA[4 * dq + 1] = fmaf(oA[4 * dq + 1], scA, pA * v0.y);
      oA[4 * dq + 2] = fmaf(oA[4 * dq + 2], scA, pA * v0.z);
      oA[4 * dq + 3] = fmaf(oA[4 * dq + 3], scA, pA * v0.w);
      oB[4 * dq + 0] = fmaf(oB[4 * dq + 0], scB, pB * v0.x);
      oB[4 * dq + 1] = fmaf(oB[4 * dq + 1], scB, pB * v0.y);
      oB[4 * dq + 2] = fmaf(oB[4 * dq + 2], scB, pB * v0.z);
      oB[4 * dq + 3] = fmaf(oB[4 * dq + 3], scB, pB * v0.w);
    }
  }
  {
    const float invA = 1.f / lA;
    float* xr0 = &x[((size_t)b * P + p0) * HD + h * D];
#pragma unroll
    for (int dq = 0; dq < 4; ++dq) {
      float4 t;
      t.x = oA[4 * dq + 0] * invA; t.y = oA[4 * dq + 1] * invA;
      t.z = oA[4 * dq + 2] * invA; t.w = oA[4 * dq + 3] * invA;
      *(float4*)&xr0[4 * dq] = t;
    }
  }
  if (r1) {
    const float invB = 1.f / lB;
    float* xr1 = &x[((size_t)b * P + p1) * HD + h * D];
#pragma unroll
    for (int dq = 0; dq < 4; ++dq) {
      float4 t;
      t.x = oB[4 * dq + 0] * invB; t.y = oB[4 * dq + 1] * invB;
      t.z = oB[4 * dq + 2] * invB; t.w = oB[4 * dq + 3] * invB;
      *(float4*)&xr1[4 * dq] = t;
    }
  }
}

// ---------------------------------------------------------------------------
// Kernel 4: router logits (fp32, SAME accumulation order; vectorized loads
// via transposed Wg) + top2 + gates; emits xsplit (2-plane).
// ---------------------------------------------------------------------------
__global__ __launch_bounds__(256) void logits_top2_kernel(
    const float* __restrict__ x, const float* __restrict__ Wg,
    int* __restrict__ topi, float* __restrict__ topg,
    ushort_t* __restrict__ xsplit) {
  __shared__ float xl[32][260];
  __shared__ float wgt[8 * 260];       // transposed, stride 260 (bank-spread)
  __shared__ float lg[32][9];
  const int tid = threadIdx.x;
  const int t0 = blockIdx.x * 32;
  for (int r = 0; r < 32; ++r) {
    float val = x[(size_t)(t0 + r) * HD + tid];
    xl[r][tid] = val;
    unsigned short hi = f2bf(val);
    unsigned short lo = f2bf(val - bf2f(hi));
    xsplit[(size_t)(t0 + r) * 512 + tid] = hi;
    xsplit[(size_t)(t0 + r) * 512 + 256 + tid] = lo;
  }
  for (int i = tid; i < E * NE; i += 256) {
    wgt[(i & 7) * 260 + (i >> 3)] = Wg[i];
  }
  __syncthreads();
  const int r = tid >> 3, e = tid & 7;
  float acc = 0.f;
  const float* xr = &xl[r][0];
  const float* wr = &wgt[e * 260];
  for (int f = 0; f < E; f += 4) {
    float4 xv = *(const float4*)&xr[f];
    float4 wv = *(const float4*)&wr[f];
    acc += xv.x * wv.x;
    acc += xv.y * wv.y;
    acc += xv.z * wv.z;
    acc += xv.w * wv.w;
  }
  lg[r][e] = acc;
  __syncthreads();
  if (tid < 32) {
    float v[8];
#pragma unroll
    for (int j = 0; j < 8; ++j) v[j] = lg[tid][j];
    int i1 = 0; float v1 = v[0];
#pragma unroll
    for (int j = 1; j < 8; ++j) if (v[j] > v1) { v1 = v[j]; i1 = j; }
    int i2 = -1; float v2 = -1e30f;
#pragma unroll
    for (int j = 0; j < 8; ++j)
      if (j != i1 && v[j] > v2) { v2 = v[j]; i2 = j; }
    float ex = __expf(v2 - v1);
    float g1 = 1.f / (1.f + ex);
    float g2 = ex / (1.f + ex);
    int t = t0 + tid;
    topi[t * 2 + 0] = i1; topi[t * 2 + 1] = i2;
    topg[t * 2 + 0] = g1; topg[t * 2 + 1] = g2;
  }
}

// ---------------------------------------------------------------------------
// Parallel list building: count -> scan -> scatter. Deterministic.
// ---------------------------------------------------------------------------
__global__ __launch_bounds__(CHKSZ) void moe_count_kernel(
    const int* __restrict__ topi, int* __restrict__ chunk_cnt) {
  __shared__ int cnt[NE];
  const int tid = threadIdx.x;
  if (tid < NE) cnt[tid] = 0;
  __syncthreads();
  const int t = blockIdx.x * CHKSZ + tid;
  atomicAdd(&cnt[topi[t * 2 + 0]], 1);
  atomicAdd(&cnt[topi[t * 2 + 1]], 1);
  __syncthreads();
  if (tid < NE) chunk_cnt[blockIdx.x * NE + tid] = cnt[tid];
}

__global__ __launch_bounds__(64) void moe_scan_kernel(
    const int* __restrict__ chunk_cnt, int* __restrict__ chunk_base,
    int* __restrict__ counts) {
  const int e = threadIdx.x;
  if (e < NE) {
    int run = 0;
    for (int c = 0; c < NCHK; ++c) {
      chunk_base[c * NE + e] = run;
      run += chunk_cnt[c * NE + e];
    }
    counts[e] = run;
  }
}

__global__ __launch_bounds__(CHKSZ) void moe_scatter_kernel(
    const int* __restrict__ topi, const float* __restrict__ topg,
    const int* __restrict__ chunk_base, int* __restrict__ list_tok,
    float* __restrict__ list_gate) {
  __shared__ int w0cnt[NE];
  const int tid = threadIdx.x;
  const int wv = tid >> 6, lane = tid & 63;
  const int t = blockIdx.x * CHKSZ + tid;
  const int ia = topi[t * 2 + 0], ib = topi[t * 2 + 1];
  const float ga = topg[t * 2 + 0], gb = topg[t * 2 + 1];
  const unsigned long long lmask = (lane == 0) ? 0ull : ((~0ull) >> (64 - lane));
  int prefA = 0, prefB = 0;
#pragma unroll
  for (int e = 0; e < NE; ++e) {
    unsigned long long mc = __ballot(ia == e) | __ballot(ib == e);
    if (wv == 0 && lane == 0) w0cnt[e] = __popcll(mc);
    int pref = __popcll(mc & lmask);
    if (ia == e) prefA = pref;
    if (ib == e) prefB = pref;
  }
  __syncthreads();
  const int baseA =
      chunk_base[blockIdx.x * NE + ia] + (wv ? w0cnt[ia] : 0) + prefA;
  const int baseB =
      chunk_base[blockIdx.x * NE + ib] + (wv ? w0cnt[ib] : 0) + prefB;
  list_tok[ia * NTOK + baseA] = (t << 1) | 0;
  list_gate[ia * NTOK + baseA] = ga;
  list_tok[ib * NTOK + baseB] = (t << 1) | 1;
  list_gate[ib * NTOK + baseB] = gb;
}

// ---------------------------------------------------------------------------
// Kernel 6: sparse expert GEMM via split-bf16 MFMA. 48-token tiles (3 rt).
// ---------------------------------------------------------------------------
__global__ __launch_bounds__(256) void expert_gemm_kernel(
    const ushort_t* __restrict__ xsplit, const uint4* __restrict__ Wp,
    const float* __restrict__ eb, const int* __restrict__ list_tok,
    const float* __restrict__ list_gate, const int* __restrict__ counts,
    float* __restrict__ p0, float* __restrict__ p1) {
  int e = 0, t0 = -1;
  {
    int rem = blockIdx.x;
    for (int i = 0; i < NE; ++i) {
      int nt = (counts[i] + 47) / 48;
      if (rem < nt) { e = i; t0 = rem * 48; break; }
      rem -= nt;
    }
  }
  if (t0 < 0) return;
  const int cnt = counts[e];
  const int nr = min(48, cnt - t0);
  __shared__ uint4 xls[48 * 65];       // 49.9 KB
  __shared__ int stok[48];
  __shared__ float sg[48];
  const int tid = threadIdx.x;
  if (tid < 48) {
    int src = e * NTOK + t0 + ((tid < nr) ? tid : 0);
    stok[tid] = list_tok[src];
    sg[tid] = (tid < nr) ? list_gate[e * NTOK + t0 + tid] : 0.f;
  }
  __syncthreads();
  for (int i = tid; i < 48 * 64; i += 256) {
    int r = i >> 6, ch = i & 63;
    const uint4* src = (const uint4*)(xsplit + (size_t)(stok[r] >> 1) * 512);
    xls[r * 65 + ch] = src[ch];
  }
  __syncthreads();
  const int w = tid >> 6;
  const int lane = tid & 63;
  const int lr = lane & 15;
  const int lg4 = lane >> 4;
  f32x4 acc[3][4];
#pragma unroll
  for (int rt = 0; rt < 3; ++rt)
#pragma unroll
    for (int ct = 0; ct < 4; ++ct) acc[rt][ct] = (f32x4){0.f, 0.f, 0.f, 0.f};

  for (int kt = 0; kt < 8; ++kt) {
    short8 afrag[3][2];
#pragma unroll
    for (int rt = 0; rt < 3; ++rt)
#pragma unroll
      for (int pl = 0; pl < 2; ++pl) {
        uint4 u = xls[(rt * 16 + lr) * 65 + pl * 32 + kt * 4 + lg4];
        afrag[rt][pl] = __builtin_bit_cast(short8, u);
      }
#pragma unroll
    for (int ct = 0; ct < 4; ++ct) {
      const int gct = w * 4 + ct;
      const size_t base = (size_t)(((e * 8 + kt) * 16 + gct) * 2) * 64 + lane;
      short8 bh = __builtin_bit_cast(short8, Wp[base]);
      short8 bl = __builtin_bit_cast(short8, Wp[base + 64]);
#pragma unroll
      for (int rt = 0; rt < 3; ++rt) {
        acc[rt][ct] = __builtin_amdgcn_mfma_f32_16x16x32_bf16(
            afrag[rt][0], bh, acc[rt][ct], 0, 0, 0);
        acc[rt][ct] = __builtin_amdgcn_mfma_f32_16x16x32_bf16(
            afrag[rt][0], bl, acc[rt][ct], 0, 0, 0);
        acc[rt][ct] = __builtin_amdgcn_mfma_f32_16x16x32_bf16(
            afrag[rt][1], bh, acc[rt][ct], 0, 0, 0);
      }
    }
  }
#pragma unroll
  for (int rt = 0; rt < 3; ++rt) {
#pragma unroll
    for (int ct = 0; ct < 4; ++ct) {
      const int col = (w * 4 + ct) * 16 + lr;
      const float bias = eb[e * E + col];
#pragma unroll
      for (int reg = 0; reg < 4; ++reg) {
        const int ridx = rt * 16 + lg4 * 4 + reg;
        if (ridx < nr) {
          const int tokw = stok[ridx];
          const float g = sg[ridx];
          float* dst = ((tokw & 1) ? p1 : p0) + (size_t)(tokw >> 1) * E + col;
          *dst = g * (acc[rt][ct][reg] + bias);
        }
      }
    }
  }
}

// ---------------------------------------------------------------------------
// Kernel 7: fused score2 + tanh-clip + softmax -> probs into d_out.
// ---------------------------------------------------------------------------
__global__ __launch_bounds__(256) void score2_fused_kernel(
    const float* __restrict__ p0, const float* __restrict__ p1,
    const float* __restrict__ enc, const float* __restrict__ ab,
    const float* __restrict__ ab1, const float* __restrict__ ninf,
    float* __restrict__ out) {
  const int b = blockIdx.x >> 1;
  const int half = blockIdx.x & 1;
  const int r0 = half * 50;
  __shared__ float4 mh4[50 * 64];      // 51.2 KB
  const int tid = threadIdx.x;
  for (int i = tid; i < 50 * 64; i += 256) {
    int r = i >> 6, c4 = i & 63;
    size_t idx = (size_t)(b * P + r0 + r) * 64 + c4;
    float4 a = ((const float4*)p0)[idx];
    float4 c = ((const float4*)p1)[idx];
    float4 s;
    s.x = a.x + c.x; s.y = a.y + c.y; s.z = a.z + c.z; s.w = a.w + c.w;
    mh4[i] = s;
  }
  __syncthreads();
  const int w = tid >> 6;
  const int lane = tid & 63;
  const int n0 = lane;
  const int n1v = lane + 64;
  const bool has1 = (n1v < N1);        // lane < 37
  const int n1 = has1 ? n1v : (N1 - 1);
  const float4* er0 = (const float4*)(enc + ((size_t)b * N1 + n0) * E);
  const float4* er1 = (const float4*)(enc + ((size_t)b * N1 + n1) * E);
  float acc0[13], acc1[13];
#pragma unroll
  for (int j = 0; j < 13; ++j) { acc0[j] = 0.f; acc1[j] = 0.f; }
  for (int kk = 0; kk < 64; ++kk) {
    float4 e0 = er0[kk];
    float4 e1 = er1[kk];
#pragma unroll
    for (int j = 0; j < 13; ++j) {
      const int r = w + j * 4;
      if (r < 50) {
        float4 mv = mh4[r * 64 + kk];
        acc0[j] = fmaf(mv.w, e0.w,
                  fmaf(mv.z, e0.z, fmaf(mv.y, e0.y, fmaf(mv.x, e0.x, acc0[j]))));
        acc1[j] = fmaf(mv.w, e1.w,
                  fmaf(mv.z, e1.z, fmaf(mv.y, e1.y, fmaf(mv.x, e1.x, acc1[j]))));
      }
    }
  }
#pragma unroll
  for (int j = 0; j < 13; ++j) {
    const int r = w + j * 4;
    if (r < 50) {
      const int prow = b * P + r0 + r;
      const float* arow = ab + (size_t)prow * N1;
      const float* a1row = ab1 + (size_t)prow * N1;
      const float* nrow = ninf + (size_t)prow * N1;
      float s0 = acc0[j] + arow[n0] + a1row[n0];
      float e20 = __expf(s0 * 0.125f);
      float v0 = 10.f - 20.f / (e20 + 1.f) + nrow[n0];
      float v1 = -1e30f;
      if (has1) {
        float s1 = acc1[j] + arow[n1v] + a1row[n1v];
        float e21 = __expf(s1 * 0.125f);
        v1 = 10.f - 20.f / (e21 + 1.f) + nrow[n1v];
      }
      float mx = fmaxf(v0, v1);
#pragma unroll
      for (int off = 32; off > 0; off >>= 1)
        mx = fmaxf(mx, __shfl_xor(mx, off, 64));
      float q0 = __expf(v0 - mx);
      float q1 = has1 ? __expf(v1 - mx) : 0.f;
      float sum = q0 + q1;
#pragma unroll
      for (int off = 32; off > 0; off >>= 1)
        sum += __shfl_xor(sum, off, 64);
      float inv = 1.f / sum;
      float* orow = out + (size_t)prow * N1;
      orow[n0] = q0 * inv;
      if (has1) orow[n1v] = q1 * inv;
    }
  }
}

// ---------------------------------------------------------------------------
extern "C" void kernel_launch(void* const* d_in, const int* in_sizes, int n_in,
                              void* d_out, int out_size, void* d_ws,
                              size_t ws_size, hipStream_t stream) {
  const float* eln  = (const float*)d_in[0];
  const float* attr = (const float*)d_in[1];
  const float* enc  = (const float*)d_in[2];
  const float* ninf = (const float*)d_in[3];
  const float* ab   = (const float*)d_in[4];
  const float* ab1  = (const float*)d_in[5];
  const float* Wq   = (const float*)d_in[6];
  const float* Wk   = (const float*)d_in[7];
  const float* Wv   = (const float*)d_in[8];
  const float* Wg   = (const float*)d_in[9];
  const float* eW   = (const float*)d_in[10];
  const float* eb   = (const float*)d_in[11];
  float* out = (float*)d_out;

  char* ws = (char*)d_ws;
  size_t off = 0;
  auto carve = [&](size_t bytes) {
    char* p = ws + off;
    off += (bytes + 255) & ~size_t(255);
    return p;
  };
  float* kbuf = (float*)carve(sizeof(float) * NKV * HD);
  float* vbuf = (float*)carve(sizeof(float) * NKV * HD);
  float* qbuf = (float*)carve(sizeof(float) * NTOK * HD);
  float* xbuf = (float*)carve(sizeof(float) * NTOK * HD);
  int*   topi = (int*)carve(sizeof(int) * NTOK * 2);
  float* topg = (float*)carve(sizeof(float) * NTOK * 2);
  int*   counts = (int*)carve(sizeof(int) * 16);
  int*   chunk_cnt = (int*)carve(sizeof(int) * NCHK * NE);
  int*   chunk_base = (int*)carve(sizeof(int) * NCHK * NE);
  int*   list_tok = (int*)carve(sizeof(int) * NE * NTOK);
  float* list_gate = (float*)carve(sizeof(float) * NE * NTOK);
  uint4* Wp  = (uint4*)carve(sizeof(ushort_t) * NE * HD * E * 2);  // 2 MB
  uint4* Wk3 = (uint4*)carve((size_t)8 * 16 * 3 * 64 * 16);        // 393 KB
  uint4* Wv3 = (uint4*)carve((size_t)8 * 16 * 3 * 64 * 16);
  uint4* Wq3 = (uint4*)carve((size_t)9 * 16 * 3 * 64 * 16);        // 442 KB
  float* pp0 = kbuf;
  float* pp1 = vbuf;
  ushort_t* xsplit = (ushort_t*)qbuf;

  prep_kernel<<<356, 256, 0, stream>>>(eW, Wp, Wk, Wk3, Wv, Wv3, Wq, Wq3);
  kvproj3_kernel<<<NKV / 32, 256, 0, stream>>>(enc, Wk3, Wv3, kbuf, vbuf);
  proj3_kernel<9, 1><<<NTOK / 32, 256, 0, stream>>>(eln, attr, Wq3, qbuf);
  attn_kernel<<<B * 4, 256, 0, stream>>>(qbuf, kbuf, vbuf, ninf, xbuf);
  logits_top2_kernel<<<NTOK / 32, 256, 0, stream>>>(xbuf, Wg, topi, topg,
                                                    xsplit);
  moe_count_kernel<<<NCHK, CHKSZ, 0, stream>>>(topi, chunk_cnt);
  moe_scan_kernel<<<1, 64, 0, stream>>>(chunk_cnt, chunk_base, counts);
  moe_scatter_kernel<<<NCHK, CHKSZ, 0, stream>>>(topi, topg, chunk_base,
                                                 list_tok, list_gate);
  // max tiles = ceil(2*NTOK/48) + NE = 1067 + 8
  expert_gemm_kernel<<<1075, 256, 0, stream>>>(xsplit, Wp, eb, list_tok,
                                               list_gate, counts, pp0, pp1);
  score2_fused_kernel<<<512, 256, 0, stream>>>(pp0, pp1, enc, ab, ab1, ninf,
                                               out);
}

// Round 14
// 295.358 us; speedup vs baseline: 1.1115x; 1.0076x over previous
//
#include <hip/hip_runtime.h>
#include <hip/hip_bf16.h>

// Problem constants
#define B   256
#define P   100
#define N1  101
#define E   256
#define HD  256          // H*D
#define H   16
#define D   16
#define NE  8
#define NTOK (B*P)       // 25600
#define NKV  (B*N1)      // 25856
#define NCHK 200         // token chunks for list building
#define CHKSZ 128

typedef __attribute__((ext_vector_type(8))) short short8;
typedef __attribute__((ext_vector_type(4))) float f32x4;
typedef unsigned short ushort_t;

__device__ __forceinline__ unsigned short f2bf(float f) {
  unsigned int u = __float_as_uint(f);
  unsigned int r = (u + 0x7fffu + ((u >> 16) & 1u)) >> 16;
  return (unsigned short)r;
}
__device__ __forceinline__ float bf2f(unsigned short b) {
  return __uint_as_float(((unsigned int)b) << 16);
}
// HW packed f32->bf16 (1 instr for 2 elements); D.lo = bf16(a), D.hi = bf16(b)
__device__ __forceinline__ unsigned int cvtpk(float a, float b) {
  unsigned int r;
  asm("v_cvt_pk_bf16_f32 %0, %1, %2" : "=v"(r) : "v"(a), "v"(b));
  return r;
}
__device__ __forceinline__ float lo2f(unsigned int u) {
  return __uint_as_float(u << 16);
}
__device__ __forceinline__ float hi2f(unsigned int u) {
  return __uint_as_float(u & 0xffff0000u);
}

// ---------------------------------------------------------------------------
// Shared A-split helper: fp32 x8 -> 3-plane packed uint4s (cvt_pk fast path).
// ---------------------------------------------------------------------------
__device__ __forceinline__ void split3_pack(const float* v, uint4& uh,
                                            uint4& um, uint4& ul) {
  unsigned int hw[4], mw[4], lw[4];
#pragma unroll
  for (int jj = 0; jj < 4; ++jj) {
    float va = v[2 * jj], vb = v[2 * jj + 1];
    unsigned int h = cvtpk(va, vb);
    float ra = va - lo2f(h), rb = vb - hi2f(h);
    unsigned int m = cvtpk(ra, rb);
    float sa = ra - lo2f(m), sb = rb - hi2f(m);
    unsigned int l = cvtpk(sa, sb);
    hw[jj] = h; mw[jj] = m; lw[jj] = l;
  }
  uh.x = hw[0]; uh.y = hw[1]; uh.z = hw[2]; uh.w = hw[3];
  um.x = mw[0]; um.y = mw[1]; um.z = mw[2]; um.w = mw[3];
  ul.x = lw[0]; ul.y = lw[1]; ul.z = lw[2]; ul.w = lw[3];
}

// ---------------------------------------------------------------------------
// Device body: 3-plane weight prepack (K x 256 -> fragment order).
// ---------------------------------------------------------------------------
__device__ __forceinline__ void wsplit3_body(const float* __restrict__ W,
                                             uint4* __restrict__ Wp, int Kreal,
                                             int gid) {
  const int lane = gid & 63;
  const int rest = gid >> 6;          // kt*16 + gct
  const int gct = rest & 15;
  const int kt = rest >> 4;
  const int k0 = kt * 32 + (lane >> 4) * 8;
  const int c = gct * 16 + (lane & 15);
  float v[8];
#pragma unroll
  for (int j = 0; j < 8; ++j) {
    int kk = k0 + j;
    v[j] = (kk < Kreal) ? W[(size_t)kk * 256 + c] : 0.f;
  }
  uint4 uh, um, ul;
  split3_pack(v, uh, um, ul);
  Wp[(size_t)(rest * 3 + 0) * 64 + lane] = uh;
  Wp[(size_t)(rest * 3 + 1) * 64 + lane] = um;
  Wp[(size_t)(rest * 3 + 2) * 64 + lane] = ul;
}

// ---------------------------------------------------------------------------
// Merged prepack kernel: blocks [0,256) expert W 2-plane; [256,288) Wk3;
// [288,320) Wv3; [320,356) Wq3.
// ---------------------------------------------------------------------------
__global__ __launch_bounds__(256) void prep_kernel(
    const float* __restrict__ eW, uint4* __restrict__ Wp,
    const float* __restrict__ Wk, uint4* __restrict__ Wk3,
    const float* __restrict__ Wv, uint4* __restrict__ Wv3,
    const float* __restrict__ Wq, uint4* __restrict__ Wq3) {
  const int bx = blockIdx.x;
  const int tid = threadIdx.x;
  if (bx < 256) {
    const int gid = bx * 256 + tid;
    const int lane = gid & 63;
    const int rest = gid >> 6;
    const int gct = rest & 15;
    const int kt = (rest >> 4) & 7;
    const int e = rest >> 7;
    const int kbase = kt * 32 + (lane >> 4) * 8;
    const int c = gct * 16 + (lane & 15);
    unsigned int hi[4], lo[4];
#pragma unroll
    for (int jj = 0; jj < 4; ++jj) {
      float v0 = eW[((size_t)e * HD + (kbase + 2 * jj)) * E + c];
      float v1 = eW[((size_t)e * HD + (kbase + 2 * jj + 1)) * E + c];
      unsigned int h = cvtpk(v0, v1);
      float r0 = v0 - lo2f(h), r1 = v1 - hi2f(h);
      unsigned int l = cvtpk(r0, r1);
      hi[jj] = h; lo[jj] = l;
    }
    uint4 uh, ul;
    uh.x = hi[0]; uh.y = hi[1]; uh.z = hi[2]; uh.w = hi[3];
    ul.x = lo[0]; ul.y = lo[1]; ul.z = lo[2]; ul.w = lo[3];
    Wp[(size_t)(rest * 2 + 0) * 64 + lane] = uh;
    Wp[(size_t)(rest * 2 + 1) * 64 + lane] = ul;
  } else if (bx < 288) {
    wsplit3_body(Wk, Wk3, 256, (bx - 256) * 256 + tid);
  } else if (bx < 320) {
    wsplit3_body(Wv, Wv3, 256, (bx - 288) * 256 + tid);
  } else {
    wsplit3_body(Wq, Wq3, 260, (bx - 320) * 256 + tid);
  }
}

// ---------------------------------------------------------------------------
// Fused K+V projection, 3-plane MFMA. Tile 32 rows x 256 cols, 4 waves.
// ---------------------------------------------------------------------------
__global__ __launch_bounds__(256) void kvproj3_kernel(
    const float* __restrict__ enc, const uint4* __restrict__ Wk3,
    const uint4* __restrict__ Wv3, float* __restrict__ kout,
    float* __restrict__ vout) {
  const int KT = 8;
  const int NKG = KT * 4;              // 32 k-groups of 8
  const int RSTRIDE = KT * 12 + 1;     // 97
  __shared__ uint4 als[32 * 97];       // 49.7 KB
  const int tid = threadIdx.x;
  const int row0 = blockIdx.x * 32;
  for (int i = tid; i < 32 * NKG; i += 256) {
    const int row = i >> 5;
    const int kg = i & 31;
    float v[8];
    const float4* s = (const float4*)(enc + (size_t)(row0 + row) * 256 + kg * 8);
    float4 x0 = s[0], x1 = s[1];
    v[0] = x0.x; v[1] = x0.y; v[2] = x0.z; v[3] = x0.w;
    v[4] = x1.x; v[5] = x1.y; v[6] = x1.z; v[7] = x1.w;
    uint4 uh, um, ul;
    split3_pack(v, uh, um, ul);
    const int slot = row * RSTRIDE + kg;
    als[slot] = uh;
    als[slot + NKG] = um;
    als[slot + 2 * NKG] = ul;
  }
  __syncthreads();
  const int w = tid >> 6;
  const int lane = tid & 63;
  const int lr = lane & 15;
  const int lg4 = lane >> 4;
  f32x4 acck[2][4], accv[2][4];
#pragma unroll
  for (int rt = 0; rt < 2; ++rt)
#pragma unroll
    for (int ct = 0; ct < 4; ++ct) {
      acck[rt][ct] = (f32x4){0.f, 0.f, 0.f, 0.f};
      accv[rt][ct] = (f32x4){0.f, 0.f, 0.f, 0.f};
    }
  for (int kt = 0; kt < KT; ++kt) {
    short8 ah[2], am[2], al[2];
#pragma unroll
    for (int rt = 0; rt < 2; ++rt) {
      const int base = (rt * 16 + lr) * RSTRIDE + kt * 4 + lg4;
      ah[rt] = __builtin_bit_cast(short8, als[base]);
      am[rt] = __builtin_bit_cast(short8, als[base + NKG]);
      al[rt] = __builtin_bit_cast(short8, als[base + 2 * NKG]);
    }
#pragma unroll
    for (int ct = 0; ct < 4; ++ct) {
      const int gct = w * 4 + ct;
      const size_t base = (size_t)((kt * 16 + gct) * 3) * 64 + lane;
      {
        short8 bh = __builtin_bit_cast(short8, Wk3[base]);
        short8 bm = __builtin_bit_cast(short8, Wk3[base + 64]);
        short8 bl = __builtin_bit_cast(short8, Wk3[base + 128]);
#pragma unroll
        for (int rt = 0; rt < 2; ++rt) {
          f32x4 a = acck[rt][ct];
          a = __builtin_amdgcn_mfma_f32_16x16x32_bf16(ah[rt], bh, a, 0, 0, 0);
          a = __builtin_amdgcn_mfma_f32_16x16x32_bf16(ah[rt], bm, a, 0, 0, 0);
          a = __builtin_amdgcn_mfma_f32_16x16x32_bf16(am[rt], bh, a, 0, 0, 0);
          a = __builtin_amdgcn_mfma_f32_16x16x32_bf16(am[rt], bm, a, 0, 0, 0);
          a = __builtin_amdgcn_mfma_f32_16x16x32_bf16(ah[rt], bl, a, 0, 0, 0);
          a = __builtin_amdgcn_mfma_f32_16x16x32_bf16(al[rt], bh, a, 0, 0, 0);
          acck[rt][ct] = a;
        }
      }
      {
        short8 bh = __builtin_bit_cast(short8, Wv3[base]);
        short8 bm = __builtin_bit_cast(short8, Wv3[base + 64]);
        short8 bl = __builtin_bit_cast(short8, Wv3[base + 128]);
#pragma unroll
        for (int rt = 0; rt < 2; ++rt) {
          f32x4 a = accv[rt][ct];
          a = __builtin_amdgcn_mfma_f32_16x16x32_bf16(ah[rt], bh, a, 0, 0, 0);
          a = __builtin_amdgcn_mfma_f32_16x16x32_bf16(ah[rt], bm, a, 0, 0, 0);
          a = __builtin_amdgcn_mfma_f32_16x16x32_bf16(am[rt], bh, a, 0, 0, 0);
          a = __builtin_amdgcn_mfma_f32_16x16x32_bf16(am[rt], bm, a, 0, 0, 0);
          a = __builtin_amdgcn_mfma_f32_16x16x32_bf16(ah[rt], bl, a, 0, 0, 0);
          a = __builtin_amdgcn_mfma_f32_16x16x32_bf16(al[rt], bh, a, 0, 0, 0);
          accv[rt][ct] = a;
        }
      }
    }
  }
#pragma unroll
  for (int rt = 0; rt < 2; ++rt) {
#pragma unroll
    for (int ct = 0; ct < 4; ++ct) {
      const int gct = w * 4 + ct;
#pragma unroll
      for (int reg = 0; reg < 4; ++reg) {
        const int row = row0 + rt * 16 + lg4 * 4 + reg;
        int bb = row / N1, nn = row - bb * N1;
        size_t o = (((size_t)bb * H + gct) * N1 + nn) * D + lr;
        kout[o] = acck[rt][ct][reg];
        vout[o] = accv[rt][ct][reg];
      }
    }
  }
}

// ---------------------------------------------------------------------------
// proj3 (Q only): MODE 1, KT=9.
// ---------------------------------------------------------------------------
template <int KT, int MODE>
__global__ __launch_bounds__(256) void proj3_kernel(
    const float* __restrict__ src, const float* __restrict__ attr,
    const uint4* __restrict__ Wp3, float* __restrict__ outp) {
  const int RSTRIDE = KT * 12 + 1;
  __shared__ uint4 als[32 * (KT * 12 + 1)];
  const int tid = threadIdx.x;
  const int row0 = blockIdx.x * 32;
  const int NKG = KT * 4;
  for (int i = tid; i < 32 * NKG; i += 256) {
    const int row = i / NKG;
    const int kg = i - row * NKG;
    float v[8];
    const int kbase = kg * 8;
    if (MODE == 0 || kbase < 256) {
      const float4* s = (const float4*)(src + (size_t)(row0 + row) * 256 + kbase);
      float4 x0 = s[0], x1 = s[1];
      v[0] = x0.x; v[1] = x0.y; v[2] = x0.z; v[3] = x0.w;
      v[4] = x1.x; v[5] = x1.y; v[6] = x1.z; v[7] = x1.w;
    } else {
#pragma unroll
      for (int j = 0; j < 8; ++j) {
        int k = kbase + j;
        v[j] = (k >= 256 && k < 260) ? attr[(size_t)(row0 + row) * 4 + (k - 256)]
                                     : 0.f;
      }
    }
    uint4 uh, um, ul;
    split3_pack(v, uh, um, ul);
    const int slot = row * RSTRIDE + kg;
    als[slot] = uh;
    als[slot + NKG] = um;
    als[slot + 2 * NKG] = ul;
  }
  __syncthreads();
  const int w = tid >> 6;
  const int lane = tid & 63;
  const int lr = lane & 15;
  const int lg4 = lane >> 4;
  f32x4 acc[2][4];
#pragma unroll
  for (int rt = 0; rt < 2; ++rt)
#pragma unroll
    for (int ct = 0; ct < 4; ++ct) acc[rt][ct] = (f32x4){0.f, 0.f, 0.f, 0.f};
  for (int kt = 0; kt < KT; ++kt) {
    short8 ah[2], am[2], al[2];
#pragma unroll
    for (int rt = 0; rt < 2; ++rt) {
      const int base = (rt * 16 + lr) * RSTRIDE + kt * 4 + lg4;
      ah[rt] = __builtin_bit_cast(short8, als[base]);
      am[rt] = __builtin_bit_cast(short8, als[base + NKG]);
      al[rt] = __builtin_bit_cast(short8, als[base + 2 * NKG]);
    }
#pragma unroll
    for (int ct = 0; ct < 4; ++ct) {
      const int gct = w * 4 + ct;
      const size_t base = (size_t)((kt * 16 + gct) * 3) * 64 + lane;
      short8 bh = __builtin_bit_cast(short8, Wp3[base]);
      short8 bm = __builtin_bit_cast(short8, Wp3[base + 64]);
      short8 bl = __builtin_bit_cast(short8, Wp3[base + 128]);
#pragma unroll
      for (int rt = 0; rt < 2; ++rt) {
        f32x4 a = acc[rt][ct];
        a = __builtin_amdgcn_mfma_f32_16x16x32_bf16(ah[rt], bh, a, 0, 0, 0);
        a = __builtin_amdgcn_mfma_f32_16x16x32_bf16(ah[rt], bm, a, 0, 0, 0);
        a = __builtin_amdgcn_mfma_f32_16x16x32_bf16(am[rt], bh, a, 0, 0, 0);
        a = __builtin_amdgcn_mfma_f32_16x16x32_bf16(am[rt], bm, a, 0, 0, 0);
        a = __builtin_amdgcn_mfma_f32_16x16x32_bf16(ah[rt], bl, a, 0, 0, 0);
        a = __builtin_amdgcn_mfma_f32_16x16x32_bf16(al[rt], bh, a, 0, 0, 0);
        acc[rt][ct] = a;
      }
    }
  }
#pragma unroll
  for (int rt = 0; rt < 2; ++rt) {
#pragma unroll
    for (int ct = 0; ct < 4; ++ct) {
      const int gct = w * 4 + ct;
#pragma unroll
      for (int reg = 0; reg < 4; ++reg) {
        const int row = row0 + rt * 16 + lg4 * 4 + reg;
        size_t o;
        if (MODE == 0) {
          int bb = row / N1, nn = row - bb * N1;
          o = (((size_t)bb * H + gct) * N1 + nn) * D + lr;
        } else {
          int bb = row / P, pp = row - bb * P;
          o = (((size_t)bb * H + gct) * P + pp) * D + lr;
        }
        outp[o] = acc[rt][ct][reg];
      }
    }
  }
}

// ---------------------------------------------------------------------------
// Attention (round-11 proven best): grid B*8 (head pairs). 256 threads =
// 4 waves; wave w: head = h0 + (w>>1); row = (w&1)*64 + lane (1 row/lane).
// K+V in LDS, chunked over keys {52, 49} -> 13.3 KB total.
// exp2-domain online softmax; masks prefetched.
// ---------------------------------------------------------------------------
__device__ __forceinline__ float dot16f(
    const float4& a0, const float4& a1, const float4& a2, const float4& a3,
    const float4& b0, const float4& b1, const float4& b2, const float4& b3) {
  float s = a0.x * b0.x;
  s = fmaf(a0.y, b0.y, s); s = fmaf(a0.z, b0.z, s); s = fmaf(a0.w, b0.w, s);
  s = fmaf(a1.x, b1.x, s); s = fmaf(a1.y, b1.y, s); s = fmaf(a1.z, b1.z, s);
  s = fmaf(a1.w, b1.w, s);
  s = fmaf(a2.x, b2.x, s); s = fmaf(a2.y, b2.y, s); s = fmaf(a2.z, b2.z, s);
  s = fmaf(a2.w, b2.w, s);
  s = fmaf(a3.x, b3.x, s); s = fmaf(a3.y, b3.y, s); s = fmaf(a3.z, b3.z, s);
  s = fmaf(a3.w, b3.w, s);
  return s;
}

__global__ __launch_bounds__(256) void attn_kernel(
    const float* __restrict__ q, const float* __restrict__ k,
    const float* __restrict__ v, const float* __restrict__ ninf,
    float* __restrict__ x) {
  const int b = blockIdx.x >> 3;
  const int h0 = (blockIdx.x & 7) * 2;
  __shared__ float4 kl4[2 * 208];      // 2 heads x 52 keys x 16 floats
  __shared__ float4 vl4[2 * 208];
  const int tid = threadIdx.x;
  const int w = tid >> 6;
  const int lane = tid & 63;
  const int hh = w >> 1;
  const int h = h0 + hh;
  const int prow = (w & 1) * 64 + lane;
  const bool act = (prow < P);
  const int p = act ? prow : (P - 1);
  const float LOG2E = 1.4426950408889634f;
  const float c1 = 0.25f * LOG2E;
  const float* qb = q + (((size_t)b * H + h) * P + p) * D;
  float4 qa0 = *(const float4*)&qb[0];
  float4 qa1 = *(const float4*)&qb[4];
  float4 qa2 = *(const float4*)&qb[8];
  float4 qa3 = *(const float4*)&qb[12];
  qa0.x *= c1; qa0.y *= c1; qa0.z *= c1; qa0.w *= c1;
  qa1.x *= c1; qa1.y *= c1; qa1.z *= c1; qa1.w *= c1;
  qa2.x *= c1; qa2.y *= c1; qa2.z *= c1; qa2.w *= c1;
  qa3.x *= c1; qa3.y *= c1; qa3.z *= c1; qa3.w *= c1;
  const float* mrow = ninf + ((size_t)b * P + p) * N1;
  const float* kw = (const float*)(kl4 + hh * 208);
  const float* vw = (const float*)(vl4 + hh * 208);

  float m2 = -1e30f, l = 0.f;
  float o[16];
#pragma unroll
  for (int d = 0; d < 16; ++d) o[d] = 0.f;

#pragma unroll
  for (int ch = 0; ch < 2; ++ch) {
    const int c0 = ch ? 52 : 0;
    const int len = ch ? 49 : 52;
    const int nf4 = len * 4;           // float4 per head
    __syncthreads();                   // previous chunk fully consumed
    for (int i = tid; i < 2 * nf4; i += 256) {
      int hs = i / nf4, rem = i - hs * nf4;
      const float4* ks =
          (const float4*)(k + (((size_t)b * H + h0 + hs) * N1 + c0) * D);
      const float4* vs =
          (const float4*)(v + (((size_t)b * H + h0 + hs) * N1 + c0) * D);
      kl4[hs * 208 + rem] = ks[rem];
      vl4[hs * 208 + rem] = vs[rem];
    }
    __syncthreads();
    const int nit = len >> 2;          // 13 / 12
    float4 mk = *(const float4*)&mrow[c0];
    for (int it = 0; it < nit; ++it) {
      const int j = it * 4;
      const int nn = (it < nit - 1) ? (c0 + j + 4) : c0;
      float4 nx = *(const float4*)&mrow[nn];
      const float4* kr0 = (const float4*)&kw[(j + 0) * D];
      const float4* kr1 = (const float4*)&kw[(j + 1) * D];
      const float4* kr2 = (const float4*)&kw[(j + 2) * D];
      const float4* kr3 = (const float4*)&kw[(j + 3) * D];
      float4 k00 = kr0[0], k01 = kr0[1], k02 = kr0[2], k03 = kr0[3];
      float4 k10 = kr1[0], k11 = kr1[1], k12 = kr1[2], k13 = kr1[3];
      float4 k20 = kr2[0], k21 = kr2[1], k22 = kr2[2], k23 = kr2[3];
      float4 k30 = kr3[0], k31 = kr3[1], k32 = kr3[2], k33 = kr3[3];
      float s0 = fmaf(mk.x, LOG2E, dot16f(qa0, qa1, qa2, qa3, k00, k01, k02, k03));
      float s1 = fmaf(mk.y, LOG2E, dot16f(qa0, qa1, qa2, qa3, k10, k11, k12, k13));
      float s2 = fmaf(mk.z, LOG2E, dot16f(qa0, qa1, qa2, qa3, k20, k21, k22, k23));
      float s3 = fmaf(mk.w, LOG2E, dot16f(qa0, qa1, qa2, qa3, k30, k31, k32, k33));
      float mn = fmaxf(fmaxf(fmaxf(s0, s1), fmaxf(s2, s3)), m2);
      float sc = exp2f(m2 - mn);
      float p0 = exp2f(s0 - mn), p1 = exp2f(s1 - mn);
      float p2 = exp2f(s2 - mn), p3 = exp2f(s3 - mn);
      l = fmaf(l, sc, (p0 + p1) + (p2 + p3));
      const float4* vr0 = (const float4*)&vw[(j + 0) * D];
      const float4* vr1 = (const float4*)&vw[(j + 1) * D];
      const float4* vr2 = (const float4*)&vw[(j + 2) * D];
      const float4* vr3 = (const float4*)&vw[(j + 3) * D];
#pragma unroll
      for (int dq = 0; dq < 4; ++dq) {
        float4 v0 = vr0[dq], v1 = vr1[dq], v2 = vr2[dq], v3 = vr3[dq];
        o[4 * dq + 0] = fmaf(o[4 * dq + 0], sc,
            fmaf(p0, v0.x, fmaf(p1, v1.x, fmaf(p2, v2.x, p3 * v3.x))));
        o[4 * dq + 1] = fmaf(o[4 * dq + 1], sc,
            fmaf(p0, v0.y, fmaf(p1, v1.y, fmaf(p2, v2.y, p3 * v3.y))));
        o[4 * dq + 2] = fmaf(o[4 * dq + 2], sc,
            fmaf(p0, v0.z, fmaf(p1, v1.z, fmaf(p2, v2.z, p3 * v3.z))));
        o[4 * dq + 3] = fmaf(o[4 * dq + 3], sc,
            fmaf(p0, v0.w, fmaf(p1, v1.w, fmaf(p2, v2.w, p3 * v3.w))));
      }
      m2 = mn;
      mk = nx;
    }
  }
  // tail key 100 = chunk-1 LDS slot 48
  {
    const float tm = mrow[100];
    const float4* kr = (const float4*)&kw[48 * D];
    float4 k0 = kr[0], k1 = kr[1], k2 = kr[2], k3 = kr[3];
    float s = fmaf(tm, LOG2E, dot16f(qa0, qa1, qa2, qa3, k0, k1, k2, k3));
    float mn = fmaxf(m2, s);
    float sc = exp2f(m2 - mn);
    float pp = exp2f(s - mn);
    l = fmaf(l, sc, pp);
    const float4* vr = (const float4*)&vw[48 * D];
#pragma unroll
    for (int dq = 0; dq < 4; ++dq) {
      float4 v0 = vr[dq];
      o[4 * dq + 0] = fmaf(o[4 * dq + 0], sc, pp * v0.x);
      o[4 * dq + 1] = fmaf(o[4 * dq + 1], sc, pp * v0.y);
      o[4 * dq + 2] = fmaf(o[4 * dq + 2], sc, pp * v0.z);
      o[4 * dq + 3] = fmaf(o[4 * dq + 3], sc, pp * v0.w);
    }
  }
  if (act) {
    const float inv = 1.f / l;
    float* xr = &x[((size_t)b * P + p) * HD + h * D];
#pragma unroll
    for (int dq = 0; dq < 4; ++dq) {
      float4 t;
      t.x = o[4 * dq + 0] * inv; t.y = o[4 * dq + 1] * inv;
      t.z = o[4 * dq + 2] * inv; t.w = o[4 * dq + 3] * inv;
      *(float4*)&xr[4 * dq] = t;
    }
  }
}

// ---------------------------------------------------------------------------
// Kernel 4: router logits (fp32, SAME accumulation order; vectorized loads
// via transposed Wg) + top2 + gates; emits xsplit (2-plane).
// ---------------------------------------------------------------------------
__global__ __launch_bounds__(256) void logits_top2_kernel(
    const float* __restrict__ x, const float* __restrict__ Wg,
    int* __restrict__ topi, float* __restrict__ topg,
    ushort_t* __restrict__ xsplit) {
  __shared__ float xl[32][260];
  __shared__ float wgt[8 * 260];       // transposed, stride 260 (bank-spread)
  __shared__ float lg[32][9];
  const int tid = threadIdx.x;
  const int t0 = blockIdx.x * 32;
  for (int r = 0; r < 32; ++r) {
    float val = x[(size_t)(t0 + r) * HD + tid];
    xl[r][tid] = val;
    unsigned short hi = f2bf(val);
    unsigned short lo = f2bf(val - bf2f(hi));
    xsplit[(size_t)(t0 + r) * 512 + tid] = hi;
    xsplit[(size_t)(t0 + r) * 512 + 256 + tid] = lo;
  }
  for (int i = tid; i < E * NE; i += 256) {
    wgt[(i & 7) * 260 + (i >> 3)] = Wg[i];
  }
  __syncthreads();
  const int r = tid >> 3, e = tid & 7;
  float acc = 0.f;
  const float* xr = &xl[r][0];
  const float* wr = &wgt[e * 260];
  for (int f = 0; f < E; f += 4) {
    float4 xv = *(const float4*)&xr[f];
    float4 wv = *(const float4*)&wr[f];
    acc += xv.x * wv.x;
    acc += xv.y * wv.y;
    acc += xv.z * wv.z;
    acc += xv.w * wv.w;
  }
  lg[r][e] = acc;
  __syncthreads();
  if (tid < 32) {
    float v[8];
#pragma unroll
    for (int j = 0; j < 8; ++j) v[j] = lg[tid][j];
    int i1 = 0; float v1 = v[0];
#pragma unroll
    for (int j = 1; j < 8; ++j) if (v[j] > v1) { v1 = v[j]; i1 = j; }
    int i2 = -1; float v2 = -1e30f;
#pragma unroll
    for (int j = 0; j < 8; ++j)
      if (j != i1 && v[j] > v2) { v2 = v[j]; i2 = j; }
    float ex = __expf(v2 - v1);
    float g1 = 1.f / (1.f + ex);
    float g2 = ex / (1.f + ex);
    int t = t0 + tid;
    topi[t * 2 + 0] = i1; topi[t * 2 + 1] = i2;
    topg[t * 2 + 0] = g1; topg[t * 2 + 1] = g2;
  }
}

// ---------------------------------------------------------------------------
// Parallel list building: count -> scan -> scatter. Deterministic.
// ---------------------------------------------------------------------------
__global__ __launch_bounds__(CHKSZ) void moe_count_kernel(
    const int* __restrict__ topi, int* __restrict__ chunk_cnt) {
  __shared__ int cnt[NE];
  const int tid = threadIdx.x;
  if (tid < NE) cnt[tid] = 0;
  __syncthreads();
  const int t = blockIdx.x * CHKSZ + tid;
  atomicAdd(&cnt[topi[t * 2 + 0]], 1);
  atomicAdd(&cnt[topi[t * 2 + 1]], 1);
  __syncthreads();
  if (tid < NE) chunk_cnt[blockIdx.x * NE + tid] = cnt[tid];
}

__global__ __launch_bounds__(64) void moe_scan_kernel(
    const int* __restrict__ chunk_cnt, int* __restrict__ chunk_base,
    int* __restrict__ counts) {
  const int e = threadIdx.x;
  if (e < NE) {
    int run = 0;
    for (int c = 0; c < NCHK; ++c) {
      chunk_base[c * NE + e] = run;
      run += chunk_cnt[c * NE + e];
    }
    counts[e] = run;
  }
}

__global__ __launch_bounds__(CHKSZ) void moe_scatter_kernel(
    const int* __restrict__ topi, const float* __restrict__ topg,
    const int* __restrict__ chunk_base, int* __restrict__ list_tok,
    float* __restrict__ list_gate) {
  __shared__ int w0cnt[NE];
  const int tid = threadIdx.x;
  const int wv = tid >> 6, lane = tid & 63;
  const int t = blockIdx.x * CHKSZ + tid;
  const int ia = topi[t * 2 + 0], ib = topi[t * 2 + 1];
  const float ga = topg[t * 2 + 0], gb = topg[t * 2 + 1];
  const unsigned long long lmask = (lane == 0) ? 0ull : ((~0ull) >> (64 - lane));
  int prefA = 0, prefB = 0;
#pragma unroll
  for (int e = 0; e < NE; ++e) {
    unsigned long long mc = __ballot(ia == e) | __ballot(ib == e);
    if (wv == 0 && lane == 0) w0cnt[e] = __popcll(mc);
    int pref = __popcll(mc & lmask);
    if (ia == e) prefA = pref;
    if (ib == e) prefB = pref;
  }
  __syncthreads();
  const int baseA =
      chunk_base[blockIdx.x * NE + ia] + (wv ? w0cnt[ia] : 0) + prefA;
  const int baseB =
      chunk_base[blockIdx.x * NE + ib] + (wv ? w0cnt[ib] : 0) + prefB;
  list_tok[ia * NTOK + baseA] = (t << 1) | 0;
  list_gate[ia * NTOK + baseA] = ga;
  list_tok[ib * NTOK + baseB] = (t << 1) | 1;
  list_gate[ib * NTOK + baseB] = gb;
}

// ---------------------------------------------------------------------------
// Kernel 6: sparse expert GEMM via split-bf16 MFMA. 48-token tiles (3 rt).
// ---------------------------------------------------------------------------
__global__ __launch_bounds__(256) void expert_gemm_kernel(
    const ushort_t* __restrict__ xsplit, const uint4* __restrict__ Wp,
    const float* __restrict__ eb, const int* __restrict__ list_tok,
    const float* __restrict__ list_gate, const int* __restrict__ counts,
    float* __restrict__ p0, float* __restrict__ p1) {
  int e = 0, t0 = -1;
  {
    int rem = blockIdx.x;
    for (int i = 0; i < NE; ++i) {
      int nt = (counts[i] + 47) / 48;
      if (rem < nt) { e = i; t0 = rem * 48; break; }
      rem -= nt;
    }
  }
  if (t0 < 0) return;
  const int cnt = counts[e];
  const int nr = min(48, cnt - t0);
  __shared__ uint4 xls[48 * 65];       // 49.9 KB
  __shared__ int stok[48];
  __shared__ float sg[48];
  const int tid = threadIdx.x;
  if (tid < 48) {
    int src = e * NTOK + t0 + ((tid < nr) ? tid : 0);
    stok[tid] = list_tok[src];
    sg[tid] = (tid < nr) ? list_gate[e * NTOK + t0 + tid] : 0.f;
  }
  __syncthreads();
  for (int i = tid; i < 48 * 64; i += 256) {
    int r = i >> 6, ch = i & 63;
    const uint4* src = (const uint4*)(xsplit + (size_t)(stok[r] >> 1) * 512);
    xls[r * 65 + ch] = src[ch];
  }
  __syncthreads();
  const int w = tid >> 6;
  const int lane = tid & 63;
  const int lr = lane & 15;
  const int lg4 = lane >> 4;
  f32x4 acc[3][4];
#pragma unroll
  for (int rt = 0; rt < 3; ++rt)
#pragma unroll
    for (int ct = 0; ct < 4; ++ct) acc[rt][ct] = (f32x4){0.f, 0.f, 0.f, 0.f};

  for (int kt = 0; kt < 8; ++kt) {
    short8 afrag[3][2];
#pragma unroll
    for (int rt = 0; rt < 3; ++rt)
#pragma unroll
      for (int pl = 0; pl < 2; ++pl) {
        uint4 u = xls[(rt * 16 + lr) * 65 + pl * 32 + kt * 4 + lg4];
        afrag[rt][pl] = __builtin_bit_cast(short8, u);
      }
#pragma unroll
    for (int ct = 0; ct < 4; ++ct) {
      const int gct = w * 4 + ct;
      const size_t base = (size_t)(((e * 8 + kt) * 16 + gct) * 2) * 64 + lane;
      short8 bh = __builtin_bit_cast(short8, Wp[base]);
      short8 bl = __builtin_bit_cast(short8, Wp[base + 64]);
#pragma unroll
      for (int rt = 0; rt < 3; ++rt) {
        acc[rt][ct] = __builtin_amdgcn_mfma_f32_16x16x32_bf16(
            afrag[rt][0], bh, acc[rt][ct], 0, 0, 0);
        acc[rt][ct] = __builtin_amdgcn_mfma_f32_16x16x32_bf16(
            afrag[rt][0], bl, acc[rt][ct], 0, 0, 0);
        acc[rt][ct] = __builtin_amdgcn_mfma_f32_16x16x32_bf16(
            afrag[rt][1], bh, acc[rt][ct], 0, 0, 0);
      }
    }
  }
#pragma unroll
  for (int rt = 0; rt < 3; ++rt) {
#pragma unroll
    for (int ct = 0; ct < 4; ++ct) {
      const int col = (w * 4 + ct) * 16 + lr;
      const float bias = eb[e * E + col];
#pragma unroll
      for (int reg = 0; reg < 4; ++reg) {
        const int ridx = rt * 16 + lg4 * 4 + reg;
        if (ridx < nr) {
          const int tokw = stok[ridx];
          const float g = sg[ridx];
          float* dst = ((tokw & 1) ? p1 : p0) + (size_t)(tokw >> 1) * E + col;
          *dst = g * (acc[rt][ct][reg] + bias);
        }
      }
    }
  }
}

// ---------------------------------------------------------------------------
// Kernel 7: fused score2 + tanh-clip + softmax -> probs into d_out.
// ---------------------------------------------------------------------------
__global__ __launch_bounds__(256) void score2_fused_kernel(
    const float* __restrict__ p0, const float* __restrict__ p1,
    const float* __restrict__ enc, const float* __restrict__ ab,
    const float* __restrict__ ab1, const float* __restrict__ ninf,
    float* __restrict__ out) {
  const int b = blockIdx.x >> 1;
  const int half = blockIdx.x & 1;
  const int r0 = half * 50;
  __shared__ float4 mh4[50 * 64];      // 51.2 KB
  const int tid = threadIdx.x;
  for (int i = tid; i < 50 * 64; i += 256) {
    int r = i >> 6, c4 = i & 63;
    size_t idx = (size_t)(b * P + r0 + r) * 64 + c4;
    float4 a = ((const float4*)p0)[idx];
    float4 c = ((const float4*)p1)[idx];
    float4 s;
    s.x = a.x + c.x; s.y = a.y + c.y; s.z = a.z + c.z; s.w = a.w + c.w;
    mh4[i] = s;
  }
  __syncthreads();
  const int w = tid >> 6;
  const int lane = tid & 63;
  const int n0 = lane;
  const int n1v = lane + 64;
  const bool has1 = (n1v < N1);        // lane < 37
  const int n1 = has1 ? n1v : (N1 - 1);
  const float4* er0 = (const float4*)(enc + ((size_t)b * N1 + n0) * E);
  const float4* er1 = (const float4*)(enc + ((size_t)b * N1 + n1) * E);
  float acc0[13], acc1[13];
#pragma unroll
  for (int j = 0; j < 13; ++j) { acc0[j] = 0.f; acc1[j] = 0.f; }
  for (int kk = 0; kk < 64; ++kk) {
    float4 e0 = er0[kk];
    float4 e1 = er1[kk];
#pragma unroll
    for (int j = 0; j < 13; ++j) {
      const int r = w + j * 4;
      if (r < 50) {
        float4 mv = mh4[r * 64 + kk];
        acc0[j] = fmaf(mv.w, e0.w,
                  fmaf(mv.z, e0.z, fmaf(mv.y, e0.y, fmaf(mv.x, e0.x, acc0[j]))));
        acc1[j] = fmaf(mv.w, e1.w,
                  fmaf(mv.z, e1.z, fmaf(mv.y, e1.y, fmaf(mv.x, e1.x, acc1[j]))));
      }
    }
  }
#pragma unroll
  for (int j = 0; j < 13; ++j) {
    const int r = w + j * 4;
    if (r < 50) {
      const int prow = b * P + r0 + r;
      const float* arow = ab + (size_t)prow * N1;
      const float* a1row = ab1 + (size_t)prow * N1;
      const float* nrow = ninf + (size_t)prow * N1;
      float s0 = acc0[j] + arow[n0] + a1row[n0];
      float e20 = __expf(s0 * 0.125f);
      float v0 = 10.f - 20.f / (e20 + 1.f) + nrow[n0];
      float v1 = -1e30f;
      if (has1) {
        float s1 = acc1[j] + arow[n1v] + a1row[n1v];
        float e21 = __expf(s1 * 0.125f);
        v1 = 10.f - 20.f / (e21 + 1.f) + nrow[n1v];
      }
      float mx = fmaxf(v0, v1);
#pragma unroll
      for (int off = 32; off > 0; off >>= 1)
        mx = fmaxf(mx, __shfl_xor(mx, off, 64));
      float q0 = __expf(v0 - mx);
      float q1 = has1 ? __expf(v1 - mx) : 0.f;
      float sum = q0 + q1;
#pragma unroll
      for (int off = 32; off > 0; off >>= 1)
        sum += __shfl_xor(sum, off, 64);
      float inv = 1.f / sum;
      float* orow = out + (size_t)prow * N1;
      orow[n0] = q0 * inv;
      if (has1) orow[n1v] = q1 * inv;
    }
  }
}

// ---------------------------------------------------------------------------
extern "C" void kernel_launch(void* const* d_in, const int* in_sizes, int n_in,
                              void* d_out, int out_size, void* d_ws,
                              size_t ws_size, hipStream_t stream) {
  const float* eln  = (const float*)d_in[0];
  const float* attr = (const float*)d_in[1];
  const float* enc  = (const float*)d_in[2];
  const float* ninf = (const float*)d_in[3];
  const float* ab   = (const float*)d_in[4];
  const float* ab1  = (const float*)d_in[5];
  const float* Wq   = (const float*)d_in[6];
  const float* Wk   = (const float*)d_in[7];
  const float* Wv   = (const float*)d_in[8];
  const float* Wg   = (const float*)d_in[9];
  const float* eW   = (const float*)d_in[10];
  const float* eb   = (const float*)d_in[11];
  float* out = (float*)d_out;

  char* ws = (char*)d_ws;
  size_t off = 0;
  auto carve = [&](size_t bytes) {
    char* p = ws + off;
    off += (bytes + 255) & ~size_t(255);
    return p;
  };
  float* kbuf = (float*)carve(sizeof(float) * NKV * HD);
  float* vbuf = (float*)carve(sizeof(float) * NKV * HD);
  float* qbuf = (float*)carve(sizeof(float) * NTOK * HD);
  float* xbuf = (float*)carve(sizeof(float) * NTOK * HD);
  int*   topi = (int*)carve(sizeof(int) * NTOK * 2);
  float* topg = (float*)carve(sizeof(float) * NTOK * 2);
  int*   counts = (int*)carve(sizeof(int) * 16);
  int*   chunk_cnt = (int*)carve(sizeof(int) * NCHK * NE);
  int*   chunk_base = (int*)carve(sizeof(int) * NCHK * NE);
  int*   list_tok = (int*)carve(sizeof(int) * NE * NTOK);
  float* list_gate = (float*)carve(sizeof(float) * NE * NTOK);
  uint4* Wp  = (uint4*)carve(sizeof(ushort_t) * NE * HD * E * 2);  // 2 MB
  uint4* Wk3 = (uint4*)carve((size_t)8 * 16 * 3 * 64 * 16);        // 393 KB
  uint4* Wv3 = (uint4*)carve((size_t)8 * 16 * 3 * 64 * 16);
  uint4* Wq3 = (uint4*)carve((size_t)9 * 16 * 3 * 64 * 16);        // 442 KB
  float* pp0 = kbuf;
  float* pp1 = vbuf;
  ushort_t* xsplit = (ushort_t*)qbuf;

  prep_kernel<<<356, 256, 0, stream>>>(eW, Wp, Wk, Wk3, Wv, Wv3, Wq, Wq3);
  kvproj3_kernel<<<NKV / 32, 256, 0, stream>>>(enc, Wk3, Wv3, kbuf, vbuf);
  proj3_kernel<9, 1><<<NTOK / 32, 256, 0, stream>>>(eln, attr, Wq3, qbuf);
  attn_kernel<<<B * 8, 256, 0, stream>>>(qbuf, kbuf, vbuf, ninf, xbuf);
  logits_top2_kernel<<<NTOK / 32, 256, 0, stream>>>(xbuf, Wg, topi, topg,
                                                    xsplit);
  moe_count_kernel<<<NCHK, CHKSZ, 0, stream>>>(topi, chunk_cnt);
  moe_scan_kernel<<<1, 64, 0, stream>>>(chunk_cnt, chunk_base, counts);
  moe_scatter_kernel<<<NCHK, CHKSZ, 0, stream>>>(topi, topg, chunk_base,
                                                 list_tok, list_gate);
  // max tiles = ceil(2*NTOK/48) + NE = 1067 + 8
  expert_gemm_kernel<<<1075, 256, 0, stream>>>(xsplit, Wp, eb, list_tok,
                                               list_gate, counts, pp0, pp1);
  score2_fused_kernel<<<512, 256, 0, stream>>>(pp0, pp1, enc, ab, ab1, ninf,
                                               out);
}